// Round 2
// baseline (1493.761 us; speedup 1.0000x reference)
//
#include <hip/hip_runtime.h>
#include <cstdint>
#include <cstddef>

// ============================================================================
// HierarchicalTransformerBlock: B=1, S=4096 (64x64 grid), D=256, NH=8, dh=32,
// DFF=1024, local windows w = 4,8,16 (stride w/2).
// Round 1: correctness-first scalar/fp32 pipeline (bf16 only for LDS-staged
// attention operands). No MFMA yet — baseline for profiling.
// Workspace use: ~31 MB of d_ws (hbuf aliased onto q/k/v region).
// ============================================================================

#define DEVFN __device__ __forceinline__

constexpr int S    = 4096;
constexpr int D    = 256;
constexpr int GRID = 64;
constexpr int NH   = 8;
constexpr int DH   = 32;

DEVFN float asf(unsigned u) { return __uint_as_float(u); }

DEVFN unsigned short f2bf(float f) {  // round-to-nearest-even bf16
  unsigned u = __float_as_uint(f);
  u += 0x7fffu + ((u >> 16) & 1u);
  return (unsigned short)(u >> 16);
}
DEVFN float bf2f(unsigned short s) { return __uint_as_float(((unsigned)s) << 16); }

DEVFN float hmax4(float4 v) { return fmaxf(fmaxf(v.x, v.y), fmaxf(v.z, v.w)); }

// packed-bf16 dot: rowreg[128] = 256 elems (pairs), krow = bf16 row in LDS
DEVFN float dot_row(const unsigned* rowreg, const unsigned short* krow) {
  float acc = 0.f;
#pragma unroll
  for (int e = 0; e < 64; ++e) {
    uint2 kw = *(const uint2*)(krow + 4 * e);
    unsigned r0 = rowreg[2 * e], r1 = rowreg[2 * e + 1];
    acc = fmaf(asf(r0 << 16),        asf(kw.x << 16),        acc);
    acc = fmaf(asf(r0 & 0xffff0000u), asf(kw.x & 0xffff0000u), acc);
    acc = fmaf(asf(r1 << 16),        asf(kw.y << 16),        acc);
    acc = fmaf(asf(r1 & 0xffff0000u), asf(kw.y & 0xffff0000u), acc);
  }
  return acc;
}

// ---------------------------------------------------------------------------
// Local windowed attention, one (window, q-chunk) per block.
// pooled[l][d] = (1/NT) * sum_q sum_k softmax(win win^T /16)[q,k] * win[k][d]
// ---------------------------------------------------------------------------
template <int W, int QC, int NCH>
__global__ __launch_bounds__(256) void k_local(const float* __restrict__ x,
                                               float* __restrict__ pooled, int nS) {
  constexpr int NT  = W * W;
  constexpr int LDE = 260;           // padded bf16 row (breaks bank aliasing)
  constexpr int TPQ = 256 / QC;
  constexpr int REPS = 256 / NT;
  __shared__ unsigned short win[NT][LDE];
  __shared__ float mq[QC], zq[QC], a[NT];
  const int tid = threadIdx.x;
  const int l = blockIdx.x / NCH, ch = blockIdx.x % NCH;
  const int row0 = (l / nS) * (W / 2), col0 = (l % nS) * (W / 2);

  for (int e4 = tid; e4 < NT * (D / 4); e4 += 256) {
    int t = e4 / (D / 4);
    int d = (e4 % (D / 4)) * 4;
    const float4 v = *(const float4*)(x + ((size_t)((row0 + t / W) * GRID + col0 + (t % W))) * D + d);
    unsigned* p = (unsigned*)&win[t][d];
    p[0] = ((unsigned)f2bf(v.y) << 16) | (unsigned)f2bf(v.x);
    p[1] = ((unsigned)f2bf(v.w) << 16) | (unsigned)f2bf(v.z);
  }
  if (tid < NT) a[tid] = 0.f;
  __syncthreads();

  unsigned rowreg[128];
  {  // phase 1: per-q softmax stats (m, Z), TPQ lanes per q
    const int qi = tid / TPQ, lk = tid % TPQ;
    const unsigned short* qr = win[ch * QC + qi];
#pragma unroll
    for (int e = 0; e < 128; ++e) rowreg[e] = *(const unsigned*)(qr + 2 * e);
    float m = -INFINITY, Z = 0.f;
    for (int k = lk; k < NT; k += TPQ) {
      float s = dot_row(rowreg, win[k]) * 0.0625f;
      float nm = fmaxf(m, s);
      Z = Z * __expf(m - nm) + __expf(s - nm);
      m = nm;
    }
#pragma unroll
    for (int msk = 1; msk < TPQ; msk <<= 1) {
      float om = __shfl_xor(m, msk);
      float oz = __shfl_xor(Z, msk);
      float nm = fmaxf(m, om);
      Z = Z * __expf(m - nm) + oz * __expf(om - nm);
      m = nm;
    }
    if (lk == 0) { mq[qi] = m; zq[qi] = Z; }
  }
  __syncthreads();
  {  // phase 2: a[k] = sum_q p[q][k] (thread owns key k, k-row in regs)
    const int k = tid % NT;
    const unsigned short* kr = win[k];
#pragma unroll
    for (int e = 0; e < 128; ++e) rowreg[e] = *(const unsigned*)(kr + 2 * e);
    float partial = 0.f;
    for (int qi = tid / NT; qi < QC; qi += REPS) {
      float s = dot_row(rowreg, win[ch * QC + qi]) * 0.0625f;  // symmetric dot
      partial += __expf(s - mq[qi]) / zq[qi];
    }
    if constexpr (REPS == 1) a[k] = partial;
    else atomicAdd(&a[k], partial);
  }
  __syncthreads();
  {  // phase 3: pooled[d] += (1/NT) sum_k a[k] * win[k][d]
    const int d = tid;
    float acc = 0.f;
#pragma unroll 8
    for (int k = 0; k < NT; ++k) acc += a[k] * bf2f(win[k][d]);
    acc *= (1.f / NT);
    if constexpr (NCH == 1) pooled[(size_t)l * D + d] = acc;
    else atomicAdd(&pooled[(size_t)l * D + d], acc);
  }
}

// ---------------------------------------------------------------------------
// Overlap-average scatter of pooled windows -> cat[t][3*256]
// ---------------------------------------------------------------------------
DEVFN float gatherp(const float* __restrict__ pooled, int r, int c, int W, int s, int nS, int d) {
  int amin = max(0, (r - W + s) / s), amax = min(nS - 1, r / s);
  int bmin = max(0, (c - W + s) / s), bmax = min(nS - 1, c / s);
  float acc = 0.f;
  int cnt = 0;
  for (int a = amin; a <= amax; ++a)
    for (int b = bmin; b <= bmax; ++b) { acc += pooled[(size_t)(a * nS + b) * D + d]; ++cnt; }
  return acc / (float)cnt;
}

__global__ void k_combine(const float* __restrict__ p0, const float* __restrict__ p1,
                          const float* __restrict__ p2, float* __restrict__ cat) {
  const int t = blockIdx.x, d = threadIdx.x;
  const int r = t >> 6, c = t & 63;
  float* o = cat + (size_t)t * 768;
  o[d]       = gatherp(p0, r, c, 4, 2, 31, d);
  o[256 + d] = gatherp(p1, r, c, 8, 4, 15, d);
  o[512 + d] = gatherp(p2, r, c, 16, 8, 7, d);
}

// ---------------------------------------------------------------------------
// Generic GEMM C[S][N] = A[S][K] @ W[K][N] + bias (ACT=1: exact GELU)
// 16-token tiles; thread owns N/256 output columns.
// ---------------------------------------------------------------------------
template <int K, int N, int ACT>
__global__ __launch_bounds__(256) void k_gemm(const float* __restrict__ A,
                                              const float* __restrict__ Wm,
                                              const float* __restrict__ bias,
                                              float* __restrict__ C) {
  constexpr int NC = N / 256;
  __shared__ float As[16][K];
  const int tid = threadIdx.x;
  const size_t t0 = (size_t)blockIdx.x * 16;
  for (int e = tid; e < 16 * (K / 4); e += 256) {
    int row = e / (K / 4), col = (e % (K / 4)) * 4;
    *(float4*)&As[row][col] = *(const float4*)(A + (t0 + row) * K + col);
  }
  __syncthreads();
  float acc[16][NC];
#pragma unroll
  for (int t = 0; t < 16; ++t)
#pragma unroll
    for (int c = 0; c < NC; ++c) acc[t][c] = 0.f;
  for (int k = 0; k < K; k += 4) {
    float w[4][NC];
#pragma unroll
    for (int kk = 0; kk < 4; ++kk)
#pragma unroll
      for (int c = 0; c < NC; ++c) w[kk][c] = Wm[(size_t)(k + kk) * N + tid + c * 256];
#pragma unroll
    for (int t = 0; t < 16; ++t) {
      float4 a4 = *(const float4*)&As[t][k];
#pragma unroll
      for (int c = 0; c < NC; ++c)
        acc[t][c] = fmaf(a4.x, w[0][c],
                    fmaf(a4.y, w[1][c], fmaf(a4.z, w[2][c], fmaf(a4.w, w[3][c], acc[t][c]))));
    }
  }
#pragma unroll
  for (int t = 0; t < 16; ++t)
#pragma unroll
    for (int c = 0; c < NC; ++c) {
      float v = acc[t][c] + bias[tid + c * 256];
      if (ACT == 1) v = 0.5f * v * (1.f + erff(v * 0.70710678118654752f));
      C[(t0 + t) * N + tid + c * 256] = v;
    }
}

// ---------------------------------------------------------------------------
// Block-wide sum of (a, b) over 256 threads
// ---------------------------------------------------------------------------
DEVFN float2 block_sum2(float a, float b) {
  __shared__ float sb[8];
#pragma unroll
  for (int m = 32; m; m >>= 1) { a += __shfl_xor(a, m); b += __shfl_xor(b, m); }
  const int w = threadIdx.x >> 6;
  __syncthreads();
  if ((threadIdx.x & 63) == 0) { sb[w] = a; sb[4 + w] = b; }
  __syncthreads();
  return make_float2(sb[0] + sb[1] + sb[2] + sb[3], sb[4] + sb[5] + sb[6] + sb[7]);
}

// out = LN(a (+ b), g, be); in-place safe (out==a) since reads precede writes
__global__ __launch_bounds__(256) void k_ln(float* __restrict__ out, const float* __restrict__ a,
                                            const float* __restrict__ b, const float* __restrict__ g,
                                            const float* __restrict__ be) {
  const size_t i = (size_t)blockIdx.x * D + threadIdx.x;
  float v = a[i] + (b ? b[i] : 0.f);
  float2 s = block_sum2(v, v * v);
  float mean = s.x * (1.f / D);
  float var = s.y * (1.f / D) - mean * mean;
  out[i] = (v - mean) * rsqrtf(var + 1e-5f) * g[threadIdx.x] + be[threadIdx.x];
}

// ---------------------------------------------------------------------------
// Flash attention: dh=32, 8 heads, 128 queries/block, RQ=2 rows per lane-slot,
// K/V staged transposed in LDS as bf16.
// ---------------------------------------------------------------------------
__global__ __launch_bounds__(256) void k_flash(const float* __restrict__ Qg,
                                               const float* __restrict__ Kg,
                                               const float* __restrict__ Vg,
                                               float* __restrict__ Og) {
  const int h = blockIdx.y;
  const int q0 = blockIdx.x * 128;
  const int tid = threadIdx.x;
  const int qs = tid >> 2, kq = tid & 3;
  __shared__ unsigned short KsT[DH][64];
  __shared__ unsigned short VsT[DH][64];
  float qreg[2][DH], o0[DH], o1[DH];
  const float scale = 0.17677669529663687f;  // 1/sqrt(32)
#pragma unroll
  for (int rq = 0; rq < 2; ++rq) {
    const float4* qp = (const float4*)(Qg + (size_t)(q0 + qs * 2 + rq) * D + h * DH);
#pragma unroll
    for (int d4 = 0; d4 < DH / 4; ++d4) {
      float4 v = qp[d4];
      qreg[rq][4 * d4 + 0] = v.x * scale;
      qreg[rq][4 * d4 + 1] = v.y * scale;
      qreg[rq][4 * d4 + 2] = v.z * scale;
      qreg[rq][4 * d4 + 3] = v.w * scale;
    }
  }
#pragma unroll
  for (int d = 0; d < DH; ++d) { o0[d] = 0.f; o1[d] = 0.f; }
  float m0 = -INFINITY, m1 = -INFINITY, l0 = 0.f, l1 = 0.f;

  for (int kt = 0; kt < S / 64; ++kt) {
    {  // stage K,V tile transposed (bf16)
      const int e = tid * 8, r = e >> 5, c = e & 31;
      const float* kp = Kg + (size_t)(kt * 64 + r) * D + h * DH + c;
      const float* vp = Vg + (size_t)(kt * 64 + r) * D + h * DH + c;
      float4 ka = *(const float4*)kp, kb = *(const float4*)(kp + 4);
      float4 va = *(const float4*)vp, vb = *(const float4*)(vp + 4);
      KsT[c + 0][r] = f2bf(ka.x); KsT[c + 1][r] = f2bf(ka.y);
      KsT[c + 2][r] = f2bf(ka.z); KsT[c + 3][r] = f2bf(ka.w);
      KsT[c + 4][r] = f2bf(kb.x); KsT[c + 5][r] = f2bf(kb.y);
      KsT[c + 6][r] = f2bf(kb.z); KsT[c + 7][r] = f2bf(kb.w);
      VsT[c + 0][r] = f2bf(va.x); VsT[c + 1][r] = f2bf(va.y);
      VsT[c + 2][r] = f2bf(va.z); VsT[c + 3][r] = f2bf(va.w);
      VsT[c + 4][r] = f2bf(vb.x); VsT[c + 5][r] = f2bf(vb.y);
      VsT[c + 6][r] = f2bf(vb.z); VsT[c + 7][r] = f2bf(vb.w);
    }
    __syncthreads();

    float4 p0[4], p1[4];
#pragma unroll
    for (int j = 0; j < 4; ++j) {
      p0[j] = make_float4(0.f, 0.f, 0.f, 0.f);
      p1[j] = make_float4(0.f, 0.f, 0.f, 0.f);
    }
#pragma unroll
    for (int d = 0; d < DH; ++d) {
      const float qa = qreg[0][d], qb = qreg[1][d];
#pragma unroll
      for (int j = 0; j < 4; ++j) {
        uint2 w = *(const uint2*)&KsT[d][kq * 16 + j * 4];
        float k0 = asf(w.x << 16), k1 = asf(w.x & 0xffff0000u);
        float k2 = asf(w.y << 16), k3 = asf(w.y & 0xffff0000u);
        p0[j].x = fmaf(qa, k0, p0[j].x); p0[j].y = fmaf(qa, k1, p0[j].y);
        p0[j].z = fmaf(qa, k2, p0[j].z); p0[j].w = fmaf(qa, k3, p0[j].w);
        p1[j].x = fmaf(qb, k0, p1[j].x); p1[j].y = fmaf(qb, k1, p1[j].y);
        p1[j].z = fmaf(qb, k2, p1[j].z); p1[j].w = fmaf(qb, k3, p1[j].w);
      }
    }
    float tm0 = fmaxf(fmaxf(hmax4(p0[0]), hmax4(p0[1])), fmaxf(hmax4(p0[2]), hmax4(p0[3])));
    float tm1 = fmaxf(fmaxf(hmax4(p1[0]), hmax4(p1[1])), fmaxf(hmax4(p1[2]), hmax4(p1[3])));
    tm0 = fmaxf(tm0, __shfl_xor(tm0, 1)); tm0 = fmaxf(tm0, __shfl_xor(tm0, 2));
    tm1 = fmaxf(tm1, __shfl_xor(tm1, 1)); tm1 = fmaxf(tm1, __shfl_xor(tm1, 2));
    const float nm0 = fmaxf(m0, tm0), nm1 = fmaxf(m1, tm1);
    const float c0 = __expf(m0 - nm0), c1 = __expf(m1 - nm1);
    float ls0 = 0.f, ls1 = 0.f;
#pragma unroll
    for (int j = 0; j < 4; ++j) {
      p0[j].x = __expf(p0[j].x - nm0); p0[j].y = __expf(p0[j].y - nm0);
      p0[j].z = __expf(p0[j].z - nm0); p0[j].w = __expf(p0[j].w - nm0);
      ls0 += p0[j].x + p0[j].y + p0[j].z + p0[j].w;
      p1[j].x = __expf(p1[j].x - nm1); p1[j].y = __expf(p1[j].y - nm1);
      p1[j].z = __expf(p1[j].z - nm1); p1[j].w = __expf(p1[j].w - nm1);
      ls1 += p1[j].x + p1[j].y + p1[j].z + p1[j].w;
    }
    ls0 += __shfl_xor(ls0, 1); ls0 += __shfl_xor(ls0, 2);
    ls1 += __shfl_xor(ls1, 1); ls1 += __shfl_xor(ls1, 2);
    l0 = l0 * c0 + ls0; l1 = l1 * c1 + ls1;
    m0 = nm0; m1 = nm1;
#pragma unroll
    for (int d = 0; d < DH; ++d) { o0[d] *= c0; o1[d] *= c1; }
#pragma unroll
    for (int d = 0; d < DH; ++d) {
      float a0 = 0.f, a1 = 0.f;
#pragma unroll
      for (int j = 0; j < 4; ++j) {
        uint2 w = *(const uint2*)&VsT[d][kq * 16 + j * 4];
        float v0 = asf(w.x << 16), v1 = asf(w.x & 0xffff0000u);
        float v2 = asf(w.y << 16), v3 = asf(w.y & 0xffff0000u);
        a0 += p0[j].x * v0 + p0[j].y * v1 + p0[j].z * v2 + p0[j].w * v3;
        a1 += p1[j].x * v0 + p1[j].y * v1 + p1[j].z * v2 + p1[j].w * v3;
      }
      o0[d] += a0; o1[d] += a1;
    }
    __syncthreads();
  }
  // sum partial outputs over the 4 kq lanes (each held a 16-key subset)
#pragma unroll
  for (int d = 0; d < DH; ++d) {
    o0[d] += __shfl_xor(o0[d], 1); o0[d] += __shfl_xor(o0[d], 2);
    o1[d] += __shfl_xor(o1[d], 1); o1[d] += __shfl_xor(o1[d], 2);
  }
  const float i0 = 1.f / l0, i1 = 1.f / l1;
  float w0[8], w1[8];
#pragma unroll
  for (int dd = 0; dd < 8; ++dd) {  // lane kq extracts dims [kq*8, kq*8+8)
    float a0 = o0[dd], a1 = o0[8 + dd], a2 = o0[16 + dd], a3 = o0[24 + dd];
    w0[dd] = (kq == 0 ? a0 : kq == 1 ? a1 : kq == 2 ? a2 : a3) * i0;
    float b0 = o1[dd], b1 = o1[8 + dd], b2 = o1[16 + dd], b3 = o1[24 + dd];
    w1[dd] = (kq == 0 ? b0 : kq == 1 ? b1 : kq == 2 ? b2 : b3) * i1;
  }
  float* op0 = Og + (size_t)(q0 + qs * 2 + 0) * D + h * DH + kq * 8;
  float* op1 = Og + (size_t)(q0 + qs * 2 + 1) * D + h * DH + kq * 8;
  *(float4*)op0       = make_float4(w0[0], w0[1], w0[2], w0[3]);
  *(float4*)(op0 + 4) = make_float4(w0[4], w0[5], w0[6], w0[7]);
  *(float4*)op1       = make_float4(w1[0], w1[1], w1[2], w1[3]);
  *(float4*)(op1 + 4) = make_float4(w1[4], w1[5], w1[6], w1[7]);
}

// ---------------------------------------------------------------------------
// Gate helpers
// ---------------------------------------------------------------------------
__global__ __launch_bounds__(256) void k_colmean(const float* __restrict__ xl,
                                                 const float* __restrict__ xg,
                                                 float* __restrict__ gbuf) {
  const int j = threadIdx.x;
  const int t0 = blockIdx.x * 64;
  float s = 0.f;
  for (int t = 0; t < 64; ++t) {
    size_t i = (size_t)(t0 + t) * D + j;
    s += xl[i] + xg[i];
  }
  atomicAdd(&gbuf[j], s * 0.5f);
}

__global__ __launch_bounds__(256) void k_gate(float* __restrict__ gbuf,
                                              const float* __restrict__ gw,
                                              const float* __restrict__ gb) {
  const int j = threadIdx.x;
  const float gm = gbuf[j] * (1.f / (float)S);
  float2 s = block_sum2(gm * gw[2 * j], gm * gw[2 * j + 1]);
  if (j == 0) {
    float g0 = s.x + gb[0], g1 = s.y + gb[1];
    float mx = fmaxf(g0, g1);
    float e0 = __expf(g0 - mx), e1 = __expf(g1 - mx);
    gbuf[256] = e0 / (e0 + e1);
    gbuf[257] = e1 / (e0 + e1);
  }
}

__global__ __launch_bounds__(256) void k_xf(const float* __restrict__ xl,
                                            const float* __restrict__ xg,
                                            const float* __restrict__ gbuf,
                                            float* __restrict__ xf) {
  const float alpha = gbuf[256], beta = gbuf[257];
  const size_t i = ((size_t)blockIdx.x * 256 + threadIdx.x) * 4;
  float4 a = *(const float4*)(xg + i);
  float4 b = *(const float4*)(xl + i);
  float4 r;
  r.x = alpha * a.x + beta * b.x;
  r.y = alpha * a.y + beta * b.y;
  r.z = alpha * a.z + beta * b.z;
  r.w = alpha * a.w + beta * b.w;
  *(float4*)(xf + i) = r;
}

// ===========================================================================
extern "C" void kernel_launch(void* const* d_in, const int* in_sizes, int n_in,
                              void* d_out, int out_size, void* d_ws, size_t ws_size,
                              hipStream_t stream) {
  const float* x   = (const float*)d_in[0];
  const float* fw  = (const float*)d_in[2];
  const float* fb  = (const float*)d_in[3];
  const float* fg  = (const float*)d_in[4];
  const float* fbb = (const float*)d_in[5];
  const float* wq  = (const float*)d_in[6];
  const float* wk  = (const float*)d_in[7];
  const float* wv  = (const float*)d_in[8];
  const float* bq  = (const float*)d_in[9];
  const float* bk  = (const float*)d_in[10];
  const float* bv  = (const float*)d_in[11];
  const float* wo  = (const float*)d_in[12];
  const float* bo  = (const float*)d_in[13];
  const float* gw  = (const float*)d_in[14];
  const float* gb  = (const float*)d_in[15];
  const float* w1  = (const float*)d_in[16];
  const float* b1  = (const float*)d_in[17];
  const float* w2  = (const float*)d_in[18];
  const float* b2  = (const float*)d_in[19];
  const float* n1g = (const float*)d_in[20];
  const float* n1b = (const float*)d_in[21];
  const float* n2g = (const float*)d_in[22];
  const float* n2b = (const float*)d_in[23];
  const float* n3g = (const float*)d_in[24];
  const float* n3b = (const float*)d_in[25];
  float* out = (float*)d_out;
  float* ws = (float*)d_ws;

  // workspace layout (floats)
  float* p0   = ws;                         // 961*256
  float* p1   = p0 + 961 * 256;             // 225*256
  float* p2   = p1 + 225 * 256;             // 49*256
  float* cat  = ws + 316160;                // S*768 ; reused as q,k,v, then hbuf
  float* qb   = cat;
  float* kb   = cat + (size_t)S * D;
  float* vb   = cat + 2 * (size_t)S * D;
  float* t1   = cat + (size_t)S * 768;      // S*D ; attn pre-proj out
  float* hbuf = cat;                        // S*1024 (cat..t1 dead by FFN time)
  float* xl   = t1 + (size_t)S * D;         // S*D ; reused as ff out
  float* xg   = xl + (size_t)S * D;         // S*D
  float* xf   = xg + (size_t)S * D;         // S*D ; first holds attn proj out
  float* gbuf = xf + (size_t)S * D;         // 264 (gmean[256] + gate[2])

  hipMemsetAsync(p2, 0, 49 * 256 * sizeof(float), stream);
  hipMemsetAsync(gbuf, 0, 264 * sizeof(float), stream);

  // local multi-scale window attention -> pooled per window
  k_local<4, 16, 1><<<dim3(961), dim3(256), 0, stream>>>(x, p0, 31);
  k_local<8, 64, 1><<<dim3(225), dim3(256), 0, stream>>>(x, p1, 15);
  k_local<16, 32, 8><<<dim3(392), dim3(256), 0, stream>>>(x, p2, 7);
  // scatter/avg -> cat[S][768]
  k_combine<<<dim3(S), dim3(256), 0, stream>>>(p0, p1, p2, cat);
  // fuse: LN(cat@fw+fb) ; xl = LN(x + .)
  k_gemm<768, 256, 0><<<dim3(S / 16), dim3(256), 0, stream>>>(cat, fw, fb, t1);
  k_ln<<<dim3(S), dim3(256), 0, stream>>>(t1, t1, nullptr, fg, fbb);
  k_ln<<<dim3(S), dim3(256), 0, stream>>>(xl, x, t1, n1g, n1b);
  // global MHA
  k_gemm<256, 256, 0><<<dim3(S / 16), dim3(256), 0, stream>>>(xl, wq, bq, qb);
  k_gemm<256, 256, 0><<<dim3(S / 16), dim3(256), 0, stream>>>(xl, wk, bk, kb);
  k_gemm<256, 256, 0><<<dim3(S / 16), dim3(256), 0, stream>>>(xl, wv, bv, vb);
  k_flash<<<dim3(32, NH), dim3(256), 0, stream>>>(qb, kb, vb, t1);
  k_gemm<256, 256, 0><<<dim3(S / 16), dim3(256), 0, stream>>>(t1, wo, bo, xf);
  k_ln<<<dim3(S), dim3(256), 0, stream>>>(xg, xl, xf, n2g, n2b);
  // gate
  k_colmean<<<dim3(64), dim3(256), 0, stream>>>(xl, xg, gbuf);
  k_gate<<<dim3(1), dim3(256), 0, stream>>>(gbuf, gw, gb);
  k_xf<<<dim3(S * D / 1024), dim3(256), 0, stream>>>(xl, xg, gbuf, xf);
  // FFN + final LN  (hbuf aliases cat/q/k/v/t1 region — all dead here)
  k_gemm<256, 1024, 1><<<dim3(S / 16), dim3(256), 0, stream>>>(xf, w1, b1, hbuf);
  k_gemm<1024, 256, 0><<<dim3(S / 16), dim3(256), 0, stream>>>(hbuf, w2, b2, xl);
  k_ln<<<dim3(S), dim3(256), 0, stream>>>(out, xf, xl, n3g, n3b);
}

// Round 3
// 918.105 us; speedup vs baseline: 1.6270x; 1.6270x over previous
//
#include <hip/hip_runtime.h>
#include <cstdint>
#include <cstddef>

// ============================================================================
// HierarchicalTransformerBlock: B=1, S=4096 (64x64 grid), D=256, NH=8, dh=32,
// DFF=1024, local windows w = 4,8,16 (stride w/2).
// Round 3: global MHA moved to MFMA (bf16, 16x16x32). Rest unchanged from the
// round-2 baseline (scalar GEMMs/local attention — next targets).
// ============================================================================

#define DEVFN __device__ __forceinline__

constexpr int S    = 4096;
constexpr int D    = 256;
constexpr int GRID = 64;
constexpr int NH   = 8;
constexpr int DH   = 32;

typedef __attribute__((ext_vector_type(8))) short bf16x8;
typedef __attribute__((ext_vector_type(4))) float f32x4;

DEVFN float asf(unsigned u) { return __uint_as_float(u); }

DEVFN unsigned short f2bf(float f) {  // round-to-nearest-even bf16
  unsigned u = __float_as_uint(f);
  u += 0x7fffu + ((u >> 16) & 1u);
  return (unsigned short)(u >> 16);
}
DEVFN float bf2f(unsigned short s) { return __uint_as_float(((unsigned)s) << 16); }

// packed-bf16 dot: rowreg[128] = 256 elems (pairs), krow = bf16 row in LDS
DEVFN float dot_row(const unsigned* rowreg, const unsigned short* krow) {
  float acc = 0.f;
#pragma unroll
  for (int e = 0; e < 64; ++e) {
    uint2 kw = *(const uint2*)(krow + 4 * e);
    unsigned r0 = rowreg[2 * e], r1 = rowreg[2 * e + 1];
    acc = fmaf(asf(r0 << 16),        asf(kw.x << 16),        acc);
    acc = fmaf(asf(r0 & 0xffff0000u), asf(kw.x & 0xffff0000u), acc);
    acc = fmaf(asf(r1 << 16),        asf(kw.y << 16),        acc);
    acc = fmaf(asf(r1 & 0xffff0000u), asf(kw.y & 0xffff0000u), acc);
  }
  return acc;
}

// ---------------------------------------------------------------------------
// Local windowed attention, one (window, q-chunk) per block.
// pooled[l][d] = (1/NT) * sum_q sum_k softmax(win win^T /16)[q,k] * win[k][d]
// ---------------------------------------------------------------------------
template <int W, int QC, int NCH>
__global__ __launch_bounds__(256) void k_local(const float* __restrict__ x,
                                               float* __restrict__ pooled, int nS) {
  constexpr int NT  = W * W;
  constexpr int LDE = 260;           // padded bf16 row (breaks bank aliasing)
  constexpr int TPQ = 256 / QC;
  constexpr int REPS = 256 / NT;
  __shared__ unsigned short win[NT][LDE];
  __shared__ float mq[QC], zq[QC], a[NT];
  const int tid = threadIdx.x;
  const int l = blockIdx.x / NCH, ch = blockIdx.x % NCH;
  const int row0 = (l / nS) * (W / 2), col0 = (l % nS) * (W / 2);

  for (int e4 = tid; e4 < NT * (D / 4); e4 += 256) {
    int t = e4 / (D / 4);
    int d = (e4 % (D / 4)) * 4;
    const float4 v = *(const float4*)(x + ((size_t)((row0 + t / W) * GRID + col0 + (t % W))) * D + d);
    unsigned* p = (unsigned*)&win[t][d];
    p[0] = ((unsigned)f2bf(v.y) << 16) | (unsigned)f2bf(v.x);
    p[1] = ((unsigned)f2bf(v.w) << 16) | (unsigned)f2bf(v.z);
  }
  if (tid < NT) a[tid] = 0.f;
  __syncthreads();

  unsigned rowreg[128];
  {  // phase 1: per-q softmax stats (m, Z), TPQ lanes per q
    const int qi = tid / TPQ, lk = tid % TPQ;
    const unsigned short* qr = win[ch * QC + qi];
#pragma unroll
    for (int e = 0; e < 128; ++e) rowreg[e] = *(const unsigned*)(qr + 2 * e);
    float m = -INFINITY, Z = 0.f;
    for (int k = lk; k < NT; k += TPQ) {
      float s = dot_row(rowreg, win[k]) * 0.0625f;
      float nm = fmaxf(m, s);
      Z = Z * __expf(m - nm) + __expf(s - nm);
      m = nm;
    }
#pragma unroll
    for (int msk = 1; msk < TPQ; msk <<= 1) {
      float om = __shfl_xor(m, msk);
      float oz = __shfl_xor(Z, msk);
      float nm = fmaxf(m, om);
      Z = Z * __expf(m - nm) + oz * __expf(om - nm);
      m = nm;
    }
    if (lk == 0) { mq[qi] = m; zq[qi] = Z; }
  }
  __syncthreads();
  {  // phase 2: a[k] = sum_q p[q][k] (thread owns key k, k-row in regs)
    const int k = tid % NT;
    const unsigned short* kr = win[k];
#pragma unroll
    for (int e = 0; e < 128; ++e) rowreg[e] = *(const unsigned*)(kr + 2 * e);
    float partial = 0.f;
    for (int qi = tid / NT; qi < QC; qi += REPS) {
      float s = dot_row(rowreg, win[ch * QC + qi]) * 0.0625f;  // symmetric dot
      partial += __expf(s - mq[qi]) / zq[qi];
    }
    if constexpr (REPS == 1) a[k] = partial;
    else atomicAdd(&a[k], partial);
  }
  __syncthreads();
  {  // phase 3: pooled[d] += (1/NT) sum_k a[k] * win[k][d]
    const int d = tid;
    float acc = 0.f;
#pragma unroll 8
    for (int k = 0; k < NT; ++k) acc += a[k] * bf2f(win[k][d]);
    acc *= (1.f / NT);
    if constexpr (NCH == 1) pooled[(size_t)l * D + d] = acc;
    else atomicAdd(&pooled[(size_t)l * D + d], acc);
  }
}

// ---------------------------------------------------------------------------
// Overlap-average scatter of pooled windows -> cat[t][3*256]
// ---------------------------------------------------------------------------
DEVFN float gatherp(const float* __restrict__ pooled, int r, int c, int W, int s, int nS, int d) {
  int amin = max(0, (r - W + s) / s), amax = min(nS - 1, r / s);
  int bmin = max(0, (c - W + s) / s), bmax = min(nS - 1, c / s);
  float acc = 0.f;
  int cnt = 0;
  for (int a = amin; a <= amax; ++a)
    for (int b = bmin; b <= bmax; ++b) { acc += pooled[(size_t)(a * nS + b) * D + d]; ++cnt; }
  return acc / (float)cnt;
}

__global__ void k_combine(const float* __restrict__ p0, const float* __restrict__ p1,
                          const float* __restrict__ p2, float* __restrict__ cat) {
  const int t = blockIdx.x, d = threadIdx.x;
  const int r = t >> 6, c = t & 63;
  float* o = cat + (size_t)t * 768;
  o[d]       = gatherp(p0, r, c, 4, 2, 31, d);
  o[256 + d] = gatherp(p1, r, c, 8, 4, 15, d);
  o[512 + d] = gatherp(p2, r, c, 16, 8, 7, d);
}

// ---------------------------------------------------------------------------
// Generic GEMM C[S][N] = A[S][K] @ W[K][N] + bias (ACT=1: exact GELU)
// ---------------------------------------------------------------------------
template <int K, int N, int ACT>
__global__ __launch_bounds__(256) void k_gemm(const float* __restrict__ A,
                                              const float* __restrict__ Wm,
                                              const float* __restrict__ bias,
                                              float* __restrict__ C) {
  constexpr int NC = N / 256;
  __shared__ float As[16][K];
  const int tid = threadIdx.x;
  const size_t t0 = (size_t)blockIdx.x * 16;
  for (int e = tid; e < 16 * (K / 4); e += 256) {
    int row = e / (K / 4), col = (e % (K / 4)) * 4;
    *(float4*)&As[row][col] = *(const float4*)(A + (t0 + row) * K + col);
  }
  __syncthreads();
  float acc[16][NC];
#pragma unroll
  for (int t = 0; t < 16; ++t)
#pragma unroll
    for (int c = 0; c < NC; ++c) acc[t][c] = 0.f;
  for (int k = 0; k < K; k += 4) {
    float w[4][NC];
#pragma unroll
    for (int kk = 0; kk < 4; ++kk)
#pragma unroll
      for (int c = 0; c < NC; ++c) w[kk][c] = Wm[(size_t)(k + kk) * N + tid + c * 256];
#pragma unroll
    for (int t = 0; t < 16; ++t) {
      float4 a4 = *(const float4*)&As[t][k];
#pragma unroll
      for (int c = 0; c < NC; ++c)
        acc[t][c] = fmaf(a4.x, w[0][c],
                    fmaf(a4.y, w[1][c], fmaf(a4.z, w[2][c], fmaf(a4.w, w[3][c], acc[t][c]))));
    }
  }
#pragma unroll
  for (int t = 0; t < 16; ++t)
#pragma unroll
    for (int c = 0; c < NC; ++c) {
      float v = acc[t][c] + bias[tid + c * 256];
      if (ACT == 1) v = 0.5f * v * (1.f + erff(v * 0.70710678118654752f));
      C[(t0 + t) * N + tid + c * 256] = v;
    }
}

// ---------------------------------------------------------------------------
// Block-wide sum of (a, b) over 256 threads
// ---------------------------------------------------------------------------
DEVFN float2 block_sum2(float a, float b) {
  __shared__ float sb[8];
#pragma unroll
  for (int m = 32; m; m >>= 1) { a += __shfl_xor(a, m); b += __shfl_xor(b, m); }
  const int w = threadIdx.x >> 6;
  __syncthreads();
  if ((threadIdx.x & 63) == 0) { sb[w] = a; sb[4 + w] = b; }
  __syncthreads();
  return make_float2(sb[0] + sb[1] + sb[2] + sb[3], sb[4] + sb[5] + sb[6] + sb[7]);
}

// out = LN(a (+ b), g, be); in-place safe (out==a) since reads precede writes
__global__ __launch_bounds__(256) void k_ln(float* __restrict__ out, const float* __restrict__ a,
                                            const float* __restrict__ b, const float* __restrict__ g,
                                            const float* __restrict__ be) {
  const size_t i = (size_t)blockIdx.x * D + threadIdx.x;
  float v = a[i] + (b ? b[i] : 0.f);
  float2 s = block_sum2(v, v * v);
  float mean = s.x * (1.f / D);
  float var = s.y * (1.f / D) - mean * mean;
  out[i] = (v - mean) * rsqrtf(var + 1e-5f) * g[threadIdx.x] + be[threadIdx.x];
}

// ---------------------------------------------------------------------------
// MFMA flash attention (bf16 16x16x32). Grid (S/64, NH), 256 thr = 4 waves,
// 16 queries/wave, KV tile = 64 keys staged fp32->bf16 in LDS.
// Fragment layouts (gfx950, learn_hip-verified):
//   A: a[j] = A[lane&15][(lane>>4)*8 + j]
//   B: b[j] = B[(lane>>4)*8 + j][lane&15]
//   C/D: d[r] = C[(lane>>4)*4 + r][lane&15]
// ---------------------------------------------------------------------------
__global__ __launch_bounds__(256) void k_flash_mfma(const float* __restrict__ Qg,
                                                    const float* __restrict__ Kg,
                                                    const float* __restrict__ Vg,
                                                    float* __restrict__ Og) {
  const int h = blockIdx.y;
  const int tid = threadIdx.x;
  const int wave = tid >> 6, lane = tid & 63;
  const int lr = lane & 15, lg = lane >> 4;

  __shared__ unsigned short Kf[64][40];     // [key][dh]   pad 32->40 (2-way free)
  __shared__ unsigned short VT[32][72];     // [dh][key]   pad 64->72 (2-way free)
  __shared__ unsigned short Pl[4][16][72];  // per-wave P  [q][key]

  const int q0 = blockIdx.x * 64 + wave * 16;
  const float scale = 0.17677669529663687f;  // 1/sqrt(32)

  // Q A-fragment, pre-scaled: a[j] = Q[q0+lr][lg*8+j]*scale
  bf16x8 qfrag;
  {
    const float* qp = Qg + (size_t)(q0 + lr) * D + h * DH + lg * 8;
    float4 a = *(const float4*)qp, b = *(const float4*)(qp + 4);
    qfrag[0] = (short)f2bf(a.x * scale); qfrag[1] = (short)f2bf(a.y * scale);
    qfrag[2] = (short)f2bf(a.z * scale); qfrag[3] = (short)f2bf(a.w * scale);
    qfrag[4] = (short)f2bf(b.x * scale); qfrag[5] = (short)f2bf(b.y * scale);
    qfrag[6] = (short)f2bf(b.z * scale); qfrag[7] = (short)f2bf(b.w * scale);
  }

  f32x4 o0 = {0.f, 0.f, 0.f, 0.f}, o1 = {0.f, 0.f, 0.f, 0.f};
  float mrow[4] = {-INFINITY, -INFINITY, -INFINITY, -INFINITY};
  float lrow[4] = {0.f, 0.f, 0.f, 0.f};

  for (int kt = 0; kt < S / 64; ++kt) {
    {  // stage 64 keys of K (row-major) and V (transposed), fp32 -> bf16
      const int key = tid >> 2, c8 = (tid & 3) * 8;
      const size_t rowb = (size_t)(kt * 64 + key) * D + h * DH + c8;
      float4 ka = *(const float4*)(Kg + rowb), kb2 = *(const float4*)(Kg + rowb + 4);
      bf16x8 kv;
      kv[0] = (short)f2bf(ka.x);  kv[1] = (short)f2bf(ka.y);
      kv[2] = (short)f2bf(ka.z);  kv[3] = (short)f2bf(ka.w);
      kv[4] = (short)f2bf(kb2.x); kv[5] = (short)f2bf(kb2.y);
      kv[6] = (short)f2bf(kb2.z); kv[7] = (short)f2bf(kb2.w);
      *(bf16x8*)&Kf[key][c8] = kv;
      float4 va = *(const float4*)(Vg + rowb), vb2 = *(const float4*)(Vg + rowb + 4);
      float vv[8] = {va.x, va.y, va.z, va.w, vb2.x, vb2.y, vb2.z, vb2.w};
#pragma unroll
      for (int i = 0; i < 8; ++i) VT[c8 + i][key] = f2bf(vv[i]);
    }
    __syncthreads();

    // scores: s[k16][r] = S[q = lg*4+r][key = k16*16 + lr]
    f32x4 s[4];
#pragma unroll
    for (int k16 = 0; k16 < 4; ++k16) {
      bf16x8 kb = *(const bf16x8*)&Kf[k16 * 16 + lr][lg * 8];
      f32x4 z = {0.f, 0.f, 0.f, 0.f};
      s[k16] = __builtin_amdgcn_mfma_f32_16x16x32_bf16(qfrag, kb, z, 0, 0, 0);
    }
    // online softmax per q-row
    float c[4];
#pragma unroll
    for (int r = 0; r < 4; ++r) {
      float tm = fmaxf(fmaxf(s[0][r], s[1][r]), fmaxf(s[2][r], s[3][r]));
      tm = fmaxf(tm, __shfl_xor(tm, 1)); tm = fmaxf(tm, __shfl_xor(tm, 2));
      tm = fmaxf(tm, __shfl_xor(tm, 4)); tm = fmaxf(tm, __shfl_xor(tm, 8));
      const float nm = fmaxf(mrow[r], tm);
      c[r] = __expf(mrow[r] - nm);
      mrow[r] = nm;
      float ls = 0.f;
#pragma unroll
      for (int k16 = 0; k16 < 4; ++k16) {
        const float p = __expf(s[k16][r] - nm);
        s[k16][r] = p;
        ls += p;
      }
      ls += __shfl_xor(ls, 1); ls += __shfl_xor(ls, 2);
      ls += __shfl_xor(ls, 4); ls += __shfl_xor(ls, 8);
      lrow[r] = lrow[r] * c[r] + ls;
    }
    // P -> per-wave LDS (bf16), reshaped to A-fragment layout on read
#pragma unroll
    for (int k16 = 0; k16 < 4; ++k16)
#pragma unroll
      for (int r = 0; r < 4; ++r)
        Pl[wave][lg * 4 + r][k16 * 16 + lr] = f2bf(s[k16][r]);
    // rescale O
#pragma unroll
    for (int r = 0; r < 4; ++r) { o0[r] *= c[r]; o1[r] *= c[r]; }
    // PV: accumulate over two 32-key chunks
#pragma unroll
    for (int kt2 = 0; kt2 < 2; ++kt2) {
      bf16x8 pa = *(const bf16x8*)&Pl[wave][lr][kt2 * 32 + lg * 8];
      bf16x8 v0 = *(const bf16x8*)&VT[lr][kt2 * 32 + lg * 8];
      bf16x8 v1 = *(const bf16x8*)&VT[16 + lr][kt2 * 32 + lg * 8];
      o0 = __builtin_amdgcn_mfma_f32_16x16x32_bf16(pa, v0, o0, 0, 0, 0);
      o1 = __builtin_amdgcn_mfma_f32_16x16x32_bf16(pa, v1, o1, 0, 0, 0);
    }
    __syncthreads();
  }

#pragma unroll
  for (int r = 0; r < 4; ++r) {
    const float inv = 1.f / lrow[r];
    float* op = Og + (size_t)(q0 + lg * 4 + r) * D + h * DH + lr;
    op[0]  = o0[r] * inv;
    op[16] = o1[r] * inv;
  }
}

// ---------------------------------------------------------------------------
// Gate helpers
// ---------------------------------------------------------------------------
__global__ __launch_bounds__(256) void k_colmean(const float* __restrict__ xl,
                                                 const float* __restrict__ xg,
                                                 float* __restrict__ gbuf) {
  const int j = threadIdx.x;
  const int t0 = blockIdx.x * 64;
  float s = 0.f;
  for (int t = 0; t < 64; ++t) {
    size_t i = (size_t)(t0 + t) * D + j;
    s += xl[i] + xg[i];
  }
  atomicAdd(&gbuf[j], s * 0.5f);
}

__global__ __launch_bounds__(256) void k_gate(float* __restrict__ gbuf,
                                              const float* __restrict__ gw,
                                              const float* __restrict__ gb) {
  const int j = threadIdx.x;
  const float gm = gbuf[j] * (1.f / (float)S);
  float2 s = block_sum2(gm * gw[2 * j], gm * gw[2 * j + 1]);
  if (j == 0) {
    float g0 = s.x + gb[0], g1 = s.y + gb[1];
    float mx = fmaxf(g0, g1);
    float e0 = __expf(g0 - mx), e1 = __expf(g1 - mx);
    gbuf[256] = e0 / (e0 + e1);
    gbuf[257] = e1 / (e0 + e1);
  }
}

__global__ __launch_bounds__(256) void k_xf(const float* __restrict__ xl,
                                            const float* __restrict__ xg,
                                            const float* __restrict__ gbuf,
                                            float* __restrict__ xf) {
  const float alpha = gbuf[256], beta = gbuf[257];
  const size_t i = ((size_t)blockIdx.x * 256 + threadIdx.x) * 4;
  float4 a = *(const float4*)(xg + i);
  float4 b = *(const float4*)(xl + i);
  float4 r;
  r.x = alpha * a.x + beta * b.x;
  r.y = alpha * a.y + beta * b.y;
  r.z = alpha * a.z + beta * b.z;
  r.w = alpha * a.w + beta * b.w;
  *(float4*)(xf + i) = r;
}

// ===========================================================================
extern "C" void kernel_launch(void* const* d_in, const int* in_sizes, int n_in,
                              void* d_out, int out_size, void* d_ws, size_t ws_size,
                              hipStream_t stream) {
  const float* x   = (const float*)d_in[0];
  const float* fw  = (const float*)d_in[2];
  const float* fb  = (const float*)d_in[3];
  const float* fg  = (const float*)d_in[4];
  const float* fbb = (const float*)d_in[5];
  const float* wq  = (const float*)d_in[6];
  const float* wk  = (const float*)d_in[7];
  const float* wv  = (const float*)d_in[8];
  const float* bq  = (const float*)d_in[9];
  const float* bk  = (const float*)d_in[10];
  const float* bv  = (const float*)d_in[11];
  const float* wo  = (const float*)d_in[12];
  const float* bo  = (const float*)d_in[13];
  const float* gw  = (const float*)d_in[14];
  const float* gb  = (const float*)d_in[15];
  const float* w1  = (const float*)d_in[16];
  const float* b1  = (const float*)d_in[17];
  const float* w2  = (const float*)d_in[18];
  const float* b2  = (const float*)d_in[19];
  const float* n1g = (const float*)d_in[20];
  const float* n1b = (const float*)d_in[21];
  const float* n2g = (const float*)d_in[22];
  const float* n2b = (const float*)d_in[23];
  const float* n3g = (const float*)d_in[24];
  const float* n3b = (const float*)d_in[25];
  float* out = (float*)d_out;
  float* ws = (float*)d_ws;

  // workspace layout (floats)
  float* p0   = ws;                         // 961*256
  float* p1   = p0 + 961 * 256;             // 225*256
  float* p2   = p1 + 225 * 256;             // 49*256
  float* cat  = ws + 316160;                // S*768 ; reused as q,k,v, then hbuf
  float* qb   = cat;
  float* kb   = cat + (size_t)S * D;
  float* vb   = cat + 2 * (size_t)S * D;
  float* t1   = cat + (size_t)S * 768;      // S*D ; attn pre-proj out
  float* hbuf = cat;                        // S*1024 (cat..t1 dead by FFN time)
  float* xl   = t1 + (size_t)S * D;         // S*D ; reused as ff out
  float* xg   = xl + (size_t)S * D;         // S*D
  float* xf   = xg + (size_t)S * D;         // S*D ; first holds attn proj out
  float* gbuf = xf + (size_t)S * D;         // 264 (gmean[256] + gate[2])

  hipMemsetAsync(p2, 0, 49 * 256 * sizeof(float), stream);
  hipMemsetAsync(gbuf, 0, 264 * sizeof(float), stream);

  // local multi-scale window attention -> pooled per window
  k_local<4, 16, 1><<<dim3(961), dim3(256), 0, stream>>>(x, p0, 31);
  k_local<8, 64, 1><<<dim3(225), dim3(256), 0, stream>>>(x, p1, 15);
  k_local<16, 32, 8><<<dim3(392), dim3(256), 0, stream>>>(x, p2, 7);
  // scatter/avg -> cat[S][768]
  k_combine<<<dim3(S), dim3(256), 0, stream>>>(p0, p1, p2, cat);
  // fuse: LN(cat@fw+fb) ; xl = LN(x + .)
  k_gemm<768, 256, 0><<<dim3(S / 16), dim3(256), 0, stream>>>(cat, fw, fb, t1);
  k_ln<<<dim3(S), dim3(256), 0, stream>>>(t1, t1, nullptr, fg, fbb);
  k_ln<<<dim3(S), dim3(256), 0, stream>>>(xl, x, t1, n1g, n1b);
  // global MHA
  k_gemm<256, 256, 0><<<dim3(S / 16), dim3(256), 0, stream>>>(xl, wq, bq, qb);
  k_gemm<256, 256, 0><<<dim3(S / 16), dim3(256), 0, stream>>>(xl, wk, bk, kb);
  k_gemm<256, 256, 0><<<dim3(S / 16), dim3(256), 0, stream>>>(xl, wv, bv, vb);
  k_flash_mfma<<<dim3(S / 64, NH), dim3(256), 0, stream>>>(qb, kb, vb, t1);
  k_gemm<256, 256, 0><<<dim3(S / 16), dim3(256), 0, stream>>>(t1, wo, bo, xf);
  k_ln<<<dim3(S), dim3(256), 0, stream>>>(xg, xl, xf, n2g, n2b);
  // gate
  k_colmean<<<dim3(64), dim3(256), 0, stream>>>(xl, xg, gbuf);
  k_gate<<<dim3(1), dim3(256), 0, stream>>>(gbuf, gw, gb);
  k_xf<<<dim3(S * D / 1024), dim3(256), 0, stream>>>(xl, xg, gbuf, xf);
  // FFN + final LN  (hbuf aliases cat/q/k/v/t1 region — all dead here)
  k_gemm<256, 1024, 1><<<dim3(S / 16), dim3(256), 0, stream>>>(xf, w1, b1, hbuf);
  k_gemm<1024, 256, 0><<<dim3(S / 16), dim3(256), 0, stream>>>(hbuf, w2, b2, xl);
  k_ln<<<dim3(S), dim3(256), 0, stream>>>(out, xf, xl, n3g, n3b);
}

// Round 4
// 574.666 us; speedup vs baseline: 2.5994x; 1.5976x over previous
//
#include <hip/hip_runtime.h>
#include <cstdint>
#include <cstddef>

// ============================================================================
// HierarchicalTransformerBlock: B=1, S=4096 (64x64 grid), D=256, NH=8, dh=32,
// DFF=1024, local windows w = 4,8,16 (stride w/2).
// Round 4: local windowed attention moved to MFMA (two-pass softmax).
//   w=16: 32x32x16 MFMA, one window/block (49 blocks).
//   w=8/4: 16x16x32 MFMA, one window/block (225 / 961 blocks).
// Global MHA already MFMA (round 3). GEMMs still scalar — next target.
// ============================================================================

#define DEVFN __device__ __forceinline__

constexpr int S    = 4096;
constexpr int D    = 256;
constexpr int GRID = 64;
constexpr int NH   = 8;
constexpr int DH   = 32;

typedef __attribute__((ext_vector_type(8))) short bf16x8;
typedef __attribute__((ext_vector_type(4))) float f32x4;
typedef __attribute__((ext_vector_type(16))) float f32x16;

DEVFN float asf(unsigned u) { return __uint_as_float(u); }

DEVFN unsigned short f2bf(float f) {  // round-to-nearest-even bf16
  unsigned u = __float_as_uint(f);
  u += 0x7fffu + ((u >> 16) & 1u);
  return (unsigned short)(u >> 16);
}
DEVFN float bf2f(unsigned short s) { return __uint_as_float(((unsigned)s) << 16); }

DEVFN bf16x8 pack8(float4 a, float4 b) {
  bf16x8 kv;
  kv[0] = (short)f2bf(a.x); kv[1] = (short)f2bf(a.y);
  kv[2] = (short)f2bf(a.z); kv[3] = (short)f2bf(a.w);
  kv[4] = (short)f2bf(b.x); kv[5] = (short)f2bf(b.y);
  kv[6] = (short)f2bf(b.z); kv[7] = (short)f2bf(b.w);
  return kv;
}

// ---------------------------------------------------------------------------
// Local windowed attention, w=4/8 (16x16x32 MFMA), one window per block.
// pooled[l][d] = (1/NT) * sum_q sum_k softmax(win win^T /16)[q,k] * win[k][d]
// Two-pass: A) per-lane online (m,Z) over this lane's columns + shuffle merge;
//           B) recompute scores, p=exp(s-m)/Z, column-sum -> a[k].
// ---------------------------------------------------------------------------
template <int W, int THREADS>
__global__ __launch_bounds__(THREADS) void k_local_s(const float* __restrict__ x,
                                                     float* __restrict__ pooled, int nS) {
  constexpr int NT  = W * W;
  constexpr int NCT = NT / 16;
  constexpr int LDE = 264;  // bf16 row pad: 528B stride, 16B aligned, ~2-way banks
  __shared__ unsigned short win[NT][LDE];
  __shared__ float a[NT];
  const int tid = threadIdx.x;
  const int wave = tid >> 6, lane = tid & 63;
  const int lr = lane & 15, lg = lane >> 4;
  const int l = blockIdx.x;
  const int row0 = (l / nS) * (W / 2), col0 = (l % nS) * (W / 2);

  for (int e8 = tid; e8 < NT * 32; e8 += THREADS) {
    const int t = e8 >> 5, c8 = (e8 & 31) * 8;
    const float* src = x + ((size_t)((row0 + t / W) * GRID + col0 + (t % W))) * D + c8;
    *(bf16x8*)&win[t][c8] = pack8(*(const float4*)src, *(const float4*)(src + 4));
  }
  if (tid < NT) a[tid] = 0.f;
  __syncthreads();

  // A-fragments for this wave's 16 q-rows
  bf16x8 af[8];
#pragma unroll
  for (int k2 = 0; k2 < 8; ++k2)
    af[k2] = *(const bf16x8*)&win[wave * 16 + lr][k2 * 32 + lg * 8];

  float m[4], Z[4], Zi[4];
#pragma unroll
  for (int r = 0; r < 4; ++r) { m[r] = -INFINITY; Z[r] = 0.f; }

  // ---- pass A: stats --------------------------------------------------------
  for (int ct = 0; ct < NCT; ++ct) {
    f32x4 Ca = {0.f, 0.f, 0.f, 0.f}, Cb = {0.f, 0.f, 0.f, 0.f};
#pragma unroll
    for (int k2 = 0; k2 < 8; k2 += 2) {
      bf16x8 b0 = *(const bf16x8*)&win[ct * 16 + lr][k2 * 32 + lg * 8];
      bf16x8 b1 = *(const bf16x8*)&win[ct * 16 + lr][(k2 + 1) * 32 + lg * 8];
      Ca = __builtin_amdgcn_mfma_f32_16x16x32_bf16(af[k2], b0, Ca, 0, 0, 0);
      Cb = __builtin_amdgcn_mfma_f32_16x16x32_bf16(af[k2 + 1], b1, Cb, 0, 0, 0);
    }
#pragma unroll
    for (int r = 0; r < 4; ++r) {
      const float sv = (Ca[r] + Cb[r]) * 0.0625f;
      const float nm = fmaxf(m[r], sv);
      Z[r] = Z[r] * __expf(m[r] - nm) + __expf(sv - nm);
      m[r] = nm;
    }
  }
#pragma unroll
  for (int r = 0; r < 4; ++r) {
#pragma unroll
    for (int msk = 1; msk <= 8; msk <<= 1) {
      const float om = __shfl_xor(m[r], msk), oz = __shfl_xor(Z[r], msk);
      const float nm = fmaxf(m[r], om);
      Z[r] = Z[r] * __expf(m[r] - nm) + oz * __expf(om - nm);
      m[r] = nm;
    }
    Zi[r] = 1.f / Z[r];
  }

  // ---- pass B: column sums --------------------------------------------------
  for (int ct = 0; ct < NCT; ++ct) {
    f32x4 Ca = {0.f, 0.f, 0.f, 0.f}, Cb = {0.f, 0.f, 0.f, 0.f};
#pragma unroll
    for (int k2 = 0; k2 < 8; k2 += 2) {
      bf16x8 b0 = *(const bf16x8*)&win[ct * 16 + lr][k2 * 32 + lg * 8];
      bf16x8 b1 = *(const bf16x8*)&win[ct * 16 + lr][(k2 + 1) * 32 + lg * 8];
      Ca = __builtin_amdgcn_mfma_f32_16x16x32_bf16(af[k2], b0, Ca, 0, 0, 0);
      Cb = __builtin_amdgcn_mfma_f32_16x16x32_bf16(af[k2 + 1], b1, Cb, 0, 0, 0);
    }
    float cs = 0.f;
#pragma unroll
    for (int r = 0; r < 4; ++r)
      cs += __expf((Ca[r] + Cb[r]) * 0.0625f - m[r]) * Zi[r];
    cs += __shfl_xor(cs, 16);
    cs += __shfl_xor(cs, 32);
    if (lg == 0) atomicAdd(&a[ct * 16 + lr], cs);
  }
  __syncthreads();

  // ---- pooled ---------------------------------------------------------------
  for (int d = tid; d < D; d += THREADS) {
    float acc = 0.f;
#pragma unroll 8
    for (int k = 0; k < NT; ++k) acc += a[k] * bf2f(win[k][d]);
    pooled[(size_t)l * D + d] = acc * (1.f / NT);
  }
}

// ---------------------------------------------------------------------------
// Local windowed attention, w=16 (NT=256), 32x32x16 MFMA, one window/block.
// 4 waves; wave owns 2 row-strips of 32 q-rows. Same two-pass scheme.
// C/D layout (32x32): col=lane&31, row=(reg&3)+8*(reg>>2)+4*(lane>>5)
// (S symmetric -> row/col mix-up is value-neutral here).
// ---------------------------------------------------------------------------
__global__ __launch_bounds__(256, 1) void k_local16(const float* __restrict__ x,
                                                    float* __restrict__ pooled, int nS) {
  constexpr int LDE = 264;
  __shared__ unsigned short win[256][LDE];  // 135168 B
  __shared__ float a[256];
  const int tid = threadIdx.x;
  const int wave = tid >> 6, lane = tid & 63;
  const int lc = lane & 31, hi = lane >> 5;
  const int l = blockIdx.x;
  const int row0 = (l / nS) * 8, col0 = (l % nS) * 8;

  for (int e8 = tid; e8 < 256 * 32; e8 += 256) {
    const int t = e8 >> 5, c8 = (e8 & 31) * 8;
    const float* src = x + ((size_t)((row0 + (t >> 4)) * GRID + col0 + (t & 15))) * D + c8;
    *(bf16x8*)&win[t][c8] = pack8(*(const float4*)src, *(const float4*)(src + 4));
  }
  a[tid] = 0.f;
  __syncthreads();

  float m[2][16], Z[2][16], Zi[2][16];
#pragma unroll
  for (int s = 0; s < 2; ++s)
#pragma unroll
    for (int r = 0; r < 16; ++r) { m[s][r] = -INFINITY; Z[s][r] = 0.f; }

  // ---- pass A: stats --------------------------------------------------------
#pragma unroll
  for (int s = 0; s < 2; ++s) {
    const int R0 = (wave * 2 + s) * 32;
    bf16x8 af[16];
#pragma unroll
    for (int k2 = 0; k2 < 16; ++k2)
      af[k2] = *(const bf16x8*)&win[R0 + lc][k2 * 16 + hi * 8];
    for (int ct = 0; ct < 8; ++ct) {
      f32x16 Ca = {0.f,0.f,0.f,0.f,0.f,0.f,0.f,0.f,0.f,0.f,0.f,0.f,0.f,0.f,0.f,0.f};
      f32x16 Cb = Ca;
#pragma unroll
      for (int k2 = 0; k2 < 16; k2 += 2) {
        bf16x8 b0 = *(const bf16x8*)&win[ct * 32 + lc][k2 * 16 + hi * 8];
        bf16x8 b1 = *(const bf16x8*)&win[ct * 32 + lc][(k2 + 1) * 16 + hi * 8];
        Ca = __builtin_amdgcn_mfma_f32_32x32x16_bf16(af[k2], b0, Ca, 0, 0, 0);
        Cb = __builtin_amdgcn_mfma_f32_32x32x16_bf16(af[k2 + 1], b1, Cb, 0, 0, 0);
      }
#pragma unroll
      for (int r = 0; r < 16; ++r) {
        const float sv = (Ca[r] + Cb[r]) * 0.0625f;
        const float nm = fmaxf(m[s][r], sv);
        Z[s][r] = Z[s][r] * __expf(m[s][r] - nm) + __expf(sv - nm);
        m[s][r] = nm;
      }
    }
#pragma unroll
    for (int r = 0; r < 16; ++r) {
#pragma unroll
      for (int msk = 1; msk <= 16; msk <<= 1) {
        const float om = __shfl_xor(m[s][r], msk), oz = __shfl_xor(Z[s][r], msk);
        const float nm = fmaxf(m[s][r], om);
        Z[s][r] = Z[s][r] * __expf(m[s][r] - nm) + oz * __expf(om - nm);
        m[s][r] = nm;
      }
      Zi[s][r] = 1.f / Z[s][r];
    }
  }

  // ---- pass B: column sums --------------------------------------------------
#pragma unroll
  for (int s = 0; s < 2; ++s) {
    const int R0 = (wave * 2 + s) * 32;
    bf16x8 af[16];
#pragma unroll
    for (int k2 = 0; k2 < 16; ++k2)
      af[k2] = *(const bf16x8*)&win[R0 + lc][k2 * 16 + hi * 8];
    for (int ct = 0; ct < 8; ++ct) {
      f32x16 Ca = {0.f,0.f,0.f,0.f,0.f,0.f,0.f,0.f,0.f,0.f,0.f,0.f,0.f,0.f,0.f,0.f};
      f32x16 Cb = Ca;
#pragma unroll
      for (int k2 = 0; k2 < 16; k2 += 2) {
        bf16x8 b0 = *(const bf16x8*)&win[ct * 32 + lc][k2 * 16 + hi * 8];
        bf16x8 b1 = *(const bf16x8*)&win[ct * 32 + lc][(k2 + 1) * 16 + hi * 8];
        Ca = __builtin_amdgcn_mfma_f32_32x32x16_bf16(af[k2], b0, Ca, 0, 0, 0);
        Cb = __builtin_amdgcn_mfma_f32_32x32x16_bf16(af[k2 + 1], b1, Cb, 0, 0, 0);
      }
      float cs = 0.f;
#pragma unroll
      for (int r = 0; r < 16; ++r)
        cs += __expf((Ca[r] + Cb[r]) * 0.0625f - m[s][r]) * Zi[s][r];
      cs += __shfl_xor(cs, 32);
      if (hi == 0) atomicAdd(&a[ct * 32 + lc], cs);
    }
  }
  __syncthreads();

  // ---- pooled ---------------------------------------------------------------
  {
    const int d = tid;
    float acc = 0.f;
#pragma unroll 8
    for (int k = 0; k < 256; ++k) acc += a[k] * bf2f(win[k][d]);
    pooled[(size_t)l * D + d] = acc * (1.f / 256.f);
  }
}

// ---------------------------------------------------------------------------
// Overlap-average scatter of pooled windows -> cat[t][3*256]
// ---------------------------------------------------------------------------
DEVFN float gatherp(const float* __restrict__ pooled, int r, int c, int W, int s, int nS, int d) {
  int amin = max(0, (r - W + s) / s), amax = min(nS - 1, r / s);
  int bmin = max(0, (c - W + s) / s), bmax = min(nS - 1, c / s);
  float acc = 0.f;
  int cnt = 0;
  for (int a = amin; a <= amax; ++a)
    for (int b = bmin; b <= bmax; ++b) { acc += pooled[(size_t)(a * nS + b) * D + d]; ++cnt; }
  return acc / (float)cnt;
}

__global__ void k_combine(const float* __restrict__ p0, const float* __restrict__ p1,
                          const float* __restrict__ p2, float* __restrict__ cat) {
  const int t = blockIdx.x, d = threadIdx.x;
  const int r = t >> 6, c = t & 63;
  float* o = cat + (size_t)t * 768;
  o[d]       = gatherp(p0, r, c, 4, 2, 31, d);
  o[256 + d] = gatherp(p1, r, c, 8, 4, 15, d);
  o[512 + d] = gatherp(p2, r, c, 16, 8, 7, d);
}

// ---------------------------------------------------------------------------
// Generic GEMM C[S][N] = A[S][K] @ W[K][N] + bias (ACT=1: exact GELU)
// ---------------------------------------------------------------------------
template <int K, int N, int ACT>
__global__ __launch_bounds__(256) void k_gemm(const float* __restrict__ A,
                                              const float* __restrict__ Wm,
                                              const float* __restrict__ bias,
                                              float* __restrict__ C) {
  constexpr int NC = N / 256;
  __shared__ float As[16][K];
  const int tid = threadIdx.x;
  const size_t t0 = (size_t)blockIdx.x * 16;
  for (int e = tid; e < 16 * (K / 4); e += 256) {
    int row = e / (K / 4), col = (e % (K / 4)) * 4;
    *(float4*)&As[row][col] = *(const float4*)(A + (t0 + row) * K + col);
  }
  __syncthreads();
  float acc[16][NC];
#pragma unroll
  for (int t = 0; t < 16; ++t)
#pragma unroll
    for (int c = 0; c < NC; ++c) acc[t][c] = 0.f;
  for (int k = 0; k < K; k += 4) {
    float w[4][NC];
#pragma unroll
    for (int kk = 0; kk < 4; ++kk)
#pragma unroll
      for (int c = 0; c < NC; ++c) w[kk][c] = Wm[(size_t)(k + kk) * N + tid + c * 256];
#pragma unroll
    for (int t = 0; t < 16; ++t) {
      float4 a4 = *(const float4*)&As[t][k];
#pragma unroll
      for (int c = 0; c < NC; ++c)
        acc[t][c] = fmaf(a4.x, w[0][c],
                    fmaf(a4.y, w[1][c], fmaf(a4.z, w[2][c], fmaf(a4.w, w[3][c], acc[t][c]))));
    }
  }
#pragma unroll
  for (int t = 0; t < 16; ++t)
#pragma unroll
    for (int c = 0; c < NC; ++c) {
      float v = acc[t][c] + bias[tid + c * 256];
      if (ACT == 1) v = 0.5f * v * (1.f + erff(v * 0.70710678118654752f));
      C[(t0 + t) * N + tid + c * 256] = v;
    }
}

// ---------------------------------------------------------------------------
// Block-wide sum of (a, b) over 256 threads
// ---------------------------------------------------------------------------
DEVFN float2 block_sum2(float a, float b) {
  __shared__ float sb[8];
#pragma unroll
  for (int m = 32; m; m >>= 1) { a += __shfl_xor(a, m); b += __shfl_xor(b, m); }
  const int w = threadIdx.x >> 6;
  __syncthreads();
  if ((threadIdx.x & 63) == 0) { sb[w] = a; sb[4 + w] = b; }
  __syncthreads();
  return make_float2(sb[0] + sb[1] + sb[2] + sb[3], sb[4] + sb[5] + sb[6] + sb[7]);
}

// out = LN(a (+ b), g, be); in-place safe (out==a) since reads precede writes
__global__ __launch_bounds__(256) void k_ln(float* __restrict__ out, const float* __restrict__ a,
                                            const float* __restrict__ b, const float* __restrict__ g,
                                            const float* __restrict__ be) {
  const size_t i = (size_t)blockIdx.x * D + threadIdx.x;
  float v = a[i] + (b ? b[i] : 0.f);
  float2 s = block_sum2(v, v * v);
  float mean = s.x * (1.f / D);
  float var = s.y * (1.f / D) - mean * mean;
  out[i] = (v - mean) * rsqrtf(var + 1e-5f) * g[threadIdx.x] + be[threadIdx.x];
}

// ---------------------------------------------------------------------------
// MFMA flash attention (bf16 16x16x32). Grid (S/64, NH), 256 thr = 4 waves,
// 16 queries/wave, KV tile = 64 keys staged fp32->bf16 in LDS.
// ---------------------------------------------------------------------------
__global__ __launch_bounds__(256) void k_flash_mfma(const float* __restrict__ Qg,
                                                    const float* __restrict__ Kg,
                                                    const float* __restrict__ Vg,
                                                    float* __restrict__ Og) {
  const int h = blockIdx.y;
  const int tid = threadIdx.x;
  const int wave = tid >> 6, lane = tid & 63;
  const int lr = lane & 15, lg = lane >> 4;

  __shared__ unsigned short Kf[64][40];     // [key][dh]   pad 32->40 (2-way free)
  __shared__ unsigned short VT[32][72];     // [dh][key]   pad 64->72 (2-way free)
  __shared__ unsigned short Pl[4][16][72];  // per-wave P  [q][key]

  const int q0 = blockIdx.x * 64 + wave * 16;
  const float scale = 0.17677669529663687f;  // 1/sqrt(32)

  bf16x8 qfrag;
  {
    const float* qp = Qg + (size_t)(q0 + lr) * D + h * DH + lg * 8;
    float4 a = *(const float4*)qp, b = *(const float4*)(qp + 4);
    qfrag[0] = (short)f2bf(a.x * scale); qfrag[1] = (short)f2bf(a.y * scale);
    qfrag[2] = (short)f2bf(a.z * scale); qfrag[3] = (short)f2bf(a.w * scale);
    qfrag[4] = (short)f2bf(b.x * scale); qfrag[5] = (short)f2bf(b.y * scale);
    qfrag[6] = (short)f2bf(b.z * scale); qfrag[7] = (short)f2bf(b.w * scale);
  }

  f32x4 o0 = {0.f, 0.f, 0.f, 0.f}, o1 = {0.f, 0.f, 0.f, 0.f};
  float mrow[4] = {-INFINITY, -INFINITY, -INFINITY, -INFINITY};
  float lrow[4] = {0.f, 0.f, 0.f, 0.f};

  for (int kt = 0; kt < S / 64; ++kt) {
    {  // stage 64 keys of K (row-major) and V (transposed), fp32 -> bf16
      const int key = tid >> 2, c8 = (tid & 3) * 8;
      const size_t rowb = (size_t)(kt * 64 + key) * D + h * DH + c8;
      float4 ka = *(const float4*)(Kg + rowb), kb2 = *(const float4*)(Kg + rowb + 4);
      *(bf16x8*)&Kf[key][c8] = pack8(ka, kb2);
      float4 va = *(const float4*)(Vg + rowb), vb2 = *(const float4*)(Vg + rowb + 4);
      float vv[8] = {va.x, va.y, va.z, va.w, vb2.x, vb2.y, vb2.z, vb2.w};
#pragma unroll
      for (int i = 0; i < 8; ++i) VT[c8 + i][key] = f2bf(vv[i]);
    }
    __syncthreads();

    f32x4 s[4];
#pragma unroll
    for (int k16 = 0; k16 < 4; ++k16) {
      bf16x8 kb = *(const bf16x8*)&Kf[k16 * 16 + lr][lg * 8];
      f32x4 z = {0.f, 0.f, 0.f, 0.f};
      s[k16] = __builtin_amdgcn_mfma_f32_16x16x32_bf16(qfrag, kb, z, 0, 0, 0);
    }
    float c[4];
#pragma unroll
    for (int r = 0; r < 4; ++r) {
      float tm = fmaxf(fmaxf(s[0][r], s[1][r]), fmaxf(s[2][r], s[3][r]));
      tm = fmaxf(tm, __shfl_xor(tm, 1)); tm = fmaxf(tm, __shfl_xor(tm, 2));
      tm = fmaxf(tm, __shfl_xor(tm, 4)); tm = fmaxf(tm, __shfl_xor(tm, 8));
      const float nm = fmaxf(mrow[r], tm);
      c[r] = __expf(mrow[r] - nm);
      mrow[r] = nm;
      float ls = 0.f;
#pragma unroll
      for (int k16 = 0; k16 < 4; ++k16) {
        const float p = __expf(s[k16][r] - nm);
        s[k16][r] = p;
        ls += p;
      }
      ls += __shfl_xor(ls, 1); ls += __shfl_xor(ls, 2);
      ls += __shfl_xor(ls, 4); ls += __shfl_xor(ls, 8);
      lrow[r] = lrow[r] * c[r] + ls;
    }
#pragma unroll
    for (int k16 = 0; k16 < 4; ++k16)
#pragma unroll
      for (int r = 0; r < 4; ++r)
        Pl[wave][lg * 4 + r][k16 * 16 + lr] = f2bf(s[k16][r]);
#pragma unroll
    for (int r = 0; r < 4; ++r) { o0[r] *= c[r]; o1[r] *= c[r]; }
#pragma unroll
    for (int kt2 = 0; kt2 < 2; ++kt2) {
      bf16x8 pa = *(const bf16x8*)&Pl[wave][lr][kt2 * 32 + lg * 8];
      bf16x8 v0 = *(const bf16x8*)&VT[lr][kt2 * 32 + lg * 8];
      bf16x8 v1 = *(const bf16x8*)&VT[16 + lr][kt2 * 32 + lg * 8];
      o0 = __builtin_amdgcn_mfma_f32_16x16x32_bf16(pa, v0, o0, 0, 0, 0);
      o1 = __builtin_amdgcn_mfma_f32_16x16x32_bf16(pa, v1, o1, 0, 0, 0);
    }
    __syncthreads();
  }

#pragma unroll
  for (int r = 0; r < 4; ++r) {
    const float inv = 1.f / lrow[r];
    float* op = Og + (size_t)(q0 + lg * 4 + r) * D + h * DH + lr;
    op[0]  = o0[r] * inv;
    op[16] = o1[r] * inv;
  }
}

// ---------------------------------------------------------------------------
// Gate helpers
// ---------------------------------------------------------------------------
__global__ __launch_bounds__(256) void k_colmean(const float* __restrict__ xl,
                                                 const float* __restrict__ xg,
                                                 float* __restrict__ gbuf) {
  const int j = threadIdx.x;
  const int t0 = blockIdx.x * 64;
  float s = 0.f;
  for (int t = 0; t < 64; ++t) {
    size_t i = (size_t)(t0 + t) * D + j;
    s += xl[i] + xg[i];
  }
  atomicAdd(&gbuf[j], s * 0.5f);
}

__global__ __launch_bounds__(256) void k_gate(float* __restrict__ gbuf,
                                              const float* __restrict__ gw,
                                              const float* __restrict__ gb) {
  const int j = threadIdx.x;
  const float gm = gbuf[j] * (1.f / (float)S);
  float2 s = block_sum2(gm * gw[2 * j], gm * gw[2 * j + 1]);
  if (j == 0) {
    float g0 = s.x + gb[0], g1 = s.y + gb[1];
    float mx = fmaxf(g0, g1);
    float e0 = __expf(g0 - mx), e1 = __expf(g1 - mx);
    gbuf[256] = e0 / (e0 + e1);
    gbuf[257] = e1 / (e0 + e1);
  }
}

__global__ __launch_bounds__(256) void k_xf(const float* __restrict__ xl,
                                            const float* __restrict__ xg,
                                            const float* __restrict__ gbuf,
                                            float* __restrict__ xf) {
  const float alpha = gbuf[256], beta = gbuf[257];
  const size_t i = ((size_t)blockIdx.x * 256 + threadIdx.x) * 4;
  float4 a = *(const float4*)(xg + i);
  float4 b = *(const float4*)(xl + i);
  float4 r;
  r.x = alpha * a.x + beta * b.x;
  r.y = alpha * a.y + beta * b.y;
  r.z = alpha * a.z + beta * b.z;
  r.w = alpha * a.w + beta * b.w;
  *(float4*)(xf + i) = r;
}

// ===========================================================================
extern "C" void kernel_launch(void* const* d_in, const int* in_sizes, int n_in,
                              void* d_out, int out_size, void* d_ws, size_t ws_size,
                              hipStream_t stream) {
  const float* x   = (const float*)d_in[0];
  const float* fw  = (const float*)d_in[2];
  const float* fb  = (const float*)d_in[3];
  const float* fg  = (const float*)d_in[4];
  const float* fbb = (const float*)d_in[5];
  const float* wq  = (const float*)d_in[6];
  const float* wk  = (const float*)d_in[7];
  const float* wv  = (const float*)d_in[8];
  const float* bq  = (const float*)d_in[9];
  const float* bk  = (const float*)d_in[10];
  const float* bv  = (const float*)d_in[11];
  const float* wo  = (const float*)d_in[12];
  const float* bo  = (const float*)d_in[13];
  const float* gw  = (const float*)d_in[14];
  const float* gb  = (const float*)d_in[15];
  const float* w1  = (const float*)d_in[16];
  const float* b1  = (const float*)d_in[17];
  const float* w2  = (const float*)d_in[18];
  const float* b2  = (const float*)d_in[19];
  const float* n1g = (const float*)d_in[20];
  const float* n1b = (const float*)d_in[21];
  const float* n2g = (const float*)d_in[22];
  const float* n2b = (const float*)d_in[23];
  const float* n3g = (const float*)d_in[24];
  const float* n3b = (const float*)d_in[25];
  float* out = (float*)d_out;
  float* ws = (float*)d_ws;

  // workspace layout (floats)
  float* p0   = ws;                         // 961*256
  float* p1   = p0 + 961 * 256;             // 225*256
  float* p2   = p1 + 225 * 256;             // 49*256
  float* cat  = ws + 316160;                // S*768 ; reused as q,k,v, then hbuf
  float* qb   = cat;
  float* kb   = cat + (size_t)S * D;
  float* vb   = cat + 2 * (size_t)S * D;
  float* t1   = cat + (size_t)S * 768;      // S*D ; attn pre-proj out
  float* hbuf = cat;                        // S*1024 (cat..t1 dead by FFN time)
  float* xl   = t1 + (size_t)S * D;         // S*D ; reused as ff out
  float* xg   = xl + (size_t)S * D;         // S*D
  float* xf   = xg + (size_t)S * D;         // S*D ; first holds attn proj out
  float* gbuf = xf + (size_t)S * D;         // 264 (gmean[256] + gate[2])

  hipMemsetAsync(gbuf, 0, 264 * sizeof(float), stream);

  // local multi-scale window attention -> pooled per window (MFMA)
  k_local_s<4, 64><<<dim3(961), dim3(64), 0, stream>>>(x, p0, 31);
  k_local_s<8, 256><<<dim3(225), dim3(256), 0, stream>>>(x, p1, 15);
  k_local16<<<dim3(49), dim3(256), 0, stream>>>(x, p2, 7);
  // scatter/avg -> cat[S][768]
  k_combine<<<dim3(S), dim3(256), 0, stream>>>(p0, p1, p2, cat);
  // fuse: LN(cat@fw+fb) ; xl = LN(x + .)
  k_gemm<768, 256, 0><<<dim3(S / 16), dim3(256), 0, stream>>>(cat, fw, fb, t1);
  k_ln<<<dim3(S), dim3(256), 0, stream>>>(t1, t1, nullptr, fg, fbb);
  k_ln<<<dim3(S), dim3(256), 0, stream>>>(xl, x, t1, n1g, n1b);
  // global MHA
  k_gemm<256, 256, 0><<<dim3(S / 16), dim3(256), 0, stream>>>(xl, wq, bq, qb);
  k_gemm<256, 256, 0><<<dim3(S / 16), dim3(256), 0, stream>>>(xl, wk, bk, kb);
  k_gemm<256, 256, 0><<<dim3(S / 16), dim3(256), 0, stream>>>(xl, wv, bv, vb);
  k_flash_mfma<<<dim3(S / 64, NH), dim3(256), 0, stream>>>(qb, kb, vb, t1);
  k_gemm<256, 256, 0><<<dim3(S / 16), dim3(256), 0, stream>>>(t1, wo, bo, xf);
  k_ln<<<dim3(S), dim3(256), 0, stream>>>(xg, xl, xf, n2g, n2b);
  // gate
  k_colmean<<<dim3(64), dim3(256), 0, stream>>>(xl, xg, gbuf);
  k_gate<<<dim3(1), dim3(256), 0, stream>>>(gbuf, gw, gb);
  k_xf<<<dim3(S * D / 1024), dim3(256), 0, stream>>>(xl, xg, gbuf, xf);
  // FFN + final LN  (hbuf aliases cat/q/k/v/t1 region — all dead here)
  k_gemm<256, 1024, 1><<<dim3(S / 16), dim3(256), 0, stream>>>(xf, w1, b1, hbuf);
  k_gemm<1024, 256, 0><<<dim3(S / 16), dim3(256), 0, stream>>>(hbuf, w2, b2, xl);
  k_ln<<<dim3(S), dim3(256), 0, stream>>>(out, xf, xl, n3g, n3b);
}

// Round 5
// 325.928 us; speedup vs baseline: 4.5831x; 1.7632x over previous
//
#include <hip/hip_runtime.h>
#include <cstdint>
#include <cstddef>

// ============================================================================
// HierarchicalTransformerBlock: B=1, S=4096 (64x64 grid), D=256, NH=8, dh=32,
// DFF=1024, local windows w = 4,8,16 (stride w/2).
// Round 5: all GEMMs -> MFMA (bf16 32x32x16, global-direct fragments, weights
// pre-transposed to WT[N][K] bf16). Flash: bf16 I/O + XOR-swizzled LDS.
// ============================================================================

#define DEVFN __device__ __forceinline__

constexpr int S    = 4096;
constexpr int D    = 256;
constexpr int GRID = 64;
constexpr int NH   = 8;
constexpr int DH   = 32;

typedef __attribute__((ext_vector_type(8))) short bf16x8;
typedef __attribute__((ext_vector_type(4))) float f32x4;
typedef __attribute__((ext_vector_type(16))) float f32x16;

DEVFN float asf(unsigned u) { return __uint_as_float(u); }

DEVFN unsigned short f2bf(float f) {  // round-to-nearest-even bf16
  unsigned u = __float_as_uint(f);
  u += 0x7fffu + ((u >> 16) & 1u);
  return (unsigned short)(u >> 16);
}
DEVFN float bf2f(unsigned short s) { return __uint_as_float(((unsigned)s) << 16); }

DEVFN bf16x8 pack8(float4 a, float4 b) {
  bf16x8 kv;
  kv[0] = (short)f2bf(a.x); kv[1] = (short)f2bf(a.y);
  kv[2] = (short)f2bf(a.z); kv[3] = (short)f2bf(a.w);
  kv[4] = (short)f2bf(b.x); kv[5] = (short)f2bf(b.y);
  kv[6] = (short)f2bf(b.z); kv[7] = (short)f2bf(b.w);
  return kv;
}

// XOR swizzle within a 64-entry key dim, 8-ushort granularity (keeps b128
// reads contiguous+aligned; spreads row-groups across banks).
DEVFN int swz(int key, int row) {
  return (key & 7) + 8 * (((key >> 3) ^ (row >> 2)) & 7);
}

// ---------------------------------------------------------------------------
// Weight pre-transpose: fp32 W[K][N] -> bf16 WT[N][K]; 32x32 tiles via LDS.
// ---------------------------------------------------------------------------
__global__ __launch_bounds__(256) void k_wt(
    const float* fw, const float* wq, const float* wk, const float* wv,
    const float* wo, const float* w1, const float* w2,
    unsigned short* fwT, unsigned short* wqT, unsigned short* wkT,
    unsigned short* wvT, unsigned short* woT, unsigned short* w1T,
    unsigned short* w2T) {
  __shared__ unsigned short tile[32][36];
  const int bid = blockIdx.x;
  const float* src; unsigned short* dst; int K, N, t;
  if (bid < 192)      { src = fw; dst = fwT; K = 768;  N = 256;  t = bid; }
  else if (bid < 256) { src = wq; dst = wqT; K = 256;  N = 256;  t = bid - 192; }
  else if (bid < 320) { src = wk; dst = wkT; K = 256;  N = 256;  t = bid - 256; }
  else if (bid < 384) { src = wv; dst = wvT; K = 256;  N = 256;  t = bid - 320; }
  else if (bid < 448) { src = wo; dst = woT; K = 256;  N = 256;  t = bid - 384; }
  else if (bid < 704) { src = w1; dst = w1T; K = 256;  N = 1024; t = bid - 448; }
  else                { src = w2; dst = w2T; K = 1024; N = 256;  t = bid - 704; }
  const int nkt = K >> 5;
  const int k0 = (t % nkt) * 32, n0 = (t / nkt) * 32;
  const int i = threadIdx.x >> 3, j4 = threadIdx.x & 7;
  const float4 v = *(const float4*)(src + (size_t)(k0 + i) * N + n0 + j4 * 4);
  unsigned lo = (unsigned)f2bf(v.x) | ((unsigned)f2bf(v.y) << 16);
  unsigned hi = (unsigned)f2bf(v.z) | ((unsigned)f2bf(v.w) << 16);
  *(uint2*)&tile[i][j4 * 4] = make_uint2(lo, hi);
  __syncthreads();
  unsigned o0 = tile[j4 * 4 + 0][i], o1 = tile[j4 * 4 + 1][i];
  unsigned o2 = tile[j4 * 4 + 2][i], o3 = tile[j4 * 4 + 3][i];
  *(uint2*)(dst + (size_t)(n0 + i) * K + k0 + j4 * 4) =
      make_uint2(o0 | (o1 << 16), o2 | (o3 << 16));
}

// ---------------------------------------------------------------------------
// MFMA GEMM: C[M][N] = Ab[M][K](bf16) @ WT[N][K]^T(bf16) + bias.
// 1 wave per 32x32 tile; fragments loaded straight from global (L2-resident).
// A-frag a[j]=A[m=lc][k=hi*8+j]; B-frag b[j]=B[k=hi*8+j][n=lc]=WT[n][k].
// C/D: col=lane&31, row=(r&3)+8*(r>>2)+4*(lane>>5).
// ---------------------------------------------------------------------------
template <int K, int OUTBF, int ACT>
__global__ __launch_bounds__(64) void k_gemm_m(const unsigned short* __restrict__ Ab,
                                               const unsigned short* __restrict__ WT,
                                               const float* __restrict__ bias,
                                               void* __restrict__ Cout, int N) {
  const int lane = threadIdx.x;
  const int lc = lane & 31, hi = lane >> 5;
  const int m0 = blockIdx.x * 32, n0 = blockIdx.y * 32;
  const unsigned short* ap = Ab + (size_t)(m0 + lc) * K + hi * 8;
  const unsigned short* bp = WT + (size_t)(n0 + lc) * K + hi * 8;
  f32x16 acc = {0.f,0.f,0.f,0.f,0.f,0.f,0.f,0.f,0.f,0.f,0.f,0.f,0.f,0.f,0.f,0.f};
#pragma unroll 4
  for (int k0 = 0; k0 < K; k0 += 16) {
    bf16x8 a = *(const bf16x8*)(ap + k0);
    bf16x8 b = *(const bf16x8*)(bp + k0);
    acc = __builtin_amdgcn_mfma_f32_32x32x16_bf16(a, b, acc, 0, 0, 0);
  }
  const float bv = bias[n0 + lc];
#pragma unroll
  for (int r = 0; r < 16; ++r) {
    const int row = (r & 3) + 8 * (r >> 2) + 4 * hi;
    float v = acc[r] + bv;
    if (ACT == 1) v = 0.5f * v * (1.f + erff(v * 0.70710678118654752f));
    if (OUTBF) ((unsigned short*)Cout)[(size_t)(m0 + row) * N + n0 + lc] = f2bf(v);
    else       ((float*)Cout)[(size_t)(m0 + row) * N + n0 + lc] = v;
  }
}

// ---------------------------------------------------------------------------
// Local windowed attention, w=4/8 (16x16x32 MFMA), one window per block.
// ---------------------------------------------------------------------------
template <int W, int THREADS>
__global__ __launch_bounds__(THREADS) void k_local_s(const float* __restrict__ x,
                                                     float* __restrict__ pooled, int nS) {
  constexpr int NT  = W * W;
  constexpr int NCT = NT / 16;
  constexpr int LDE = 264;
  __shared__ unsigned short win[NT][LDE];
  __shared__ float a[NT];
  const int tid = threadIdx.x;
  const int wave = tid >> 6, lane = tid & 63;
  const int lr = lane & 15, lg = lane >> 4;
  const int l = blockIdx.x;
  const int row0 = (l / nS) * (W / 2), col0 = (l % nS) * (W / 2);

  for (int e8 = tid; e8 < NT * 32; e8 += THREADS) {
    const int t = e8 >> 5, c8 = (e8 & 31) * 8;
    const float* src = x + ((size_t)((row0 + t / W) * GRID + col0 + (t % W))) * D + c8;
    *(bf16x8*)&win[t][c8] = pack8(*(const float4*)src, *(const float4*)(src + 4));
  }
  if (tid < NT) a[tid] = 0.f;
  __syncthreads();

  bf16x8 af[8];
#pragma unroll
  for (int k2 = 0; k2 < 8; ++k2)
    af[k2] = *(const bf16x8*)&win[wave * 16 + lr][k2 * 32 + lg * 8];

  float m[4], Z[4], Zi[4];
#pragma unroll
  for (int r = 0; r < 4; ++r) { m[r] = -INFINITY; Z[r] = 0.f; }

  for (int ct = 0; ct < NCT; ++ct) {
    f32x4 Ca = {0.f, 0.f, 0.f, 0.f}, Cb = {0.f, 0.f, 0.f, 0.f};
#pragma unroll
    for (int k2 = 0; k2 < 8; k2 += 2) {
      bf16x8 b0 = *(const bf16x8*)&win[ct * 16 + lr][k2 * 32 + lg * 8];
      bf16x8 b1 = *(const bf16x8*)&win[ct * 16 + lr][(k2 + 1) * 32 + lg * 8];
      Ca = __builtin_amdgcn_mfma_f32_16x16x32_bf16(af[k2], b0, Ca, 0, 0, 0);
      Cb = __builtin_amdgcn_mfma_f32_16x16x32_bf16(af[k2 + 1], b1, Cb, 0, 0, 0);
    }
#pragma unroll
    for (int r = 0; r < 4; ++r) {
      const float sv = (Ca[r] + Cb[r]) * 0.0625f;
      const float nm = fmaxf(m[r], sv);
      Z[r] = Z[r] * __expf(m[r] - nm) + __expf(sv - nm);
      m[r] = nm;
    }
  }
#pragma unroll
  for (int r = 0; r < 4; ++r) {
#pragma unroll
    for (int msk = 1; msk <= 8; msk <<= 1) {
      const float om = __shfl_xor(m[r], msk), oz = __shfl_xor(Z[r], msk);
      const float nm = fmaxf(m[r], om);
      Z[r] = Z[r] * __expf(m[r] - nm) + oz * __expf(om - nm);
      m[r] = nm;
    }
    Zi[r] = 1.f / Z[r];
  }

  for (int ct = 0; ct < NCT; ++ct) {
    f32x4 Ca = {0.f, 0.f, 0.f, 0.f}, Cb = {0.f, 0.f, 0.f, 0.f};
#pragma unroll
    for (int k2 = 0; k2 < 8; k2 += 2) {
      bf16x8 b0 = *(const bf16x8*)&win[ct * 16 + lr][k2 * 32 + lg * 8];
      bf16x8 b1 = *(const bf16x8*)&win[ct * 16 + lr][(k2 + 1) * 32 + lg * 8];
      Ca = __builtin_amdgcn_mfma_f32_16x16x32_bf16(af[k2], b0, Ca, 0, 0, 0);
      Cb = __builtin_amdgcn_mfma_f32_16x16x32_bf16(af[k2 + 1], b1, Cb, 0, 0, 0);
    }
    float cs = 0.f;
#pragma unroll
    for (int r = 0; r < 4; ++r)
      cs += __expf((Ca[r] + Cb[r]) * 0.0625f - m[r]) * Zi[r];
    cs += __shfl_xor(cs, 16);
    cs += __shfl_xor(cs, 32);
    if (lg == 0) atomicAdd(&a[ct * 16 + lr], cs);
  }
  __syncthreads();

  for (int d = tid; d < D; d += THREADS) {
    float acc = 0.f;
#pragma unroll 8
    for (int k = 0; k < NT; ++k) acc += a[k] * bf2f(win[k][d]);
    pooled[(size_t)l * D + d] = acc * (1.f / NT);
  }
}

// ---------------------------------------------------------------------------
// Local windowed attention, w=16 (NT=256), 32x32x16 MFMA, one window/block.
// ---------------------------------------------------------------------------
__global__ __launch_bounds__(256, 1) void k_local16(const float* __restrict__ x,
                                                    float* __restrict__ pooled, int nS) {
  constexpr int LDE = 264;
  __shared__ unsigned short win[256][LDE];
  __shared__ float a[256];
  const int tid = threadIdx.x;
  const int wave = tid >> 6, lane = tid & 63;
  const int lc = lane & 31, hi = lane >> 5;
  const int l = blockIdx.x;
  const int row0 = (l / nS) * 8, col0 = (l % nS) * 8;

  for (int e8 = tid; e8 < 256 * 32; e8 += 256) {
    const int t = e8 >> 5, c8 = (e8 & 31) * 8;
    const float* src = x + ((size_t)((row0 + (t >> 4)) * GRID + col0 + (t & 15))) * D + c8;
    *(bf16x8*)&win[t][c8] = pack8(*(const float4*)src, *(const float4*)(src + 4));
  }
  a[tid] = 0.f;
  __syncthreads();

  float m[2][16], Z[2][16], Zi[2][16];
#pragma unroll
  for (int s = 0; s < 2; ++s)
#pragma unroll
    for (int r = 0; r < 16; ++r) { m[s][r] = -INFINITY; Z[s][r] = 0.f; }

#pragma unroll
  for (int s = 0; s < 2; ++s) {
    const int R0 = (wave * 2 + s) * 32;
    bf16x8 af[16];
#pragma unroll
    for (int k2 = 0; k2 < 16; ++k2)
      af[k2] = *(const bf16x8*)&win[R0 + lc][k2 * 16 + hi * 8];
    for (int ct = 0; ct < 8; ++ct) {
      f32x16 Ca = {0.f,0.f,0.f,0.f,0.f,0.f,0.f,0.f,0.f,0.f,0.f,0.f,0.f,0.f,0.f,0.f};
      f32x16 Cb = Ca;
#pragma unroll
      for (int k2 = 0; k2 < 16; k2 += 2) {
        bf16x8 b0 = *(const bf16x8*)&win[ct * 32 + lc][k2 * 16 + hi * 8];
        bf16x8 b1 = *(const bf16x8*)&win[ct * 32 + lc][(k2 + 1) * 16 + hi * 8];
        Ca = __builtin_amdgcn_mfma_f32_32x32x16_bf16(af[k2], b0, Ca, 0, 0, 0);
        Cb = __builtin_amdgcn_mfma_f32_32x32x16_bf16(af[k2 + 1], b1, Cb, 0, 0, 0);
      }
#pragma unroll
      for (int r = 0; r < 16; ++r) {
        const float sv = (Ca[r] + Cb[r]) * 0.0625f;
        const float nm = fmaxf(m[s][r], sv);
        Z[s][r] = Z[s][r] * __expf(m[s][r] - nm) + __expf(sv - nm);
        m[s][r] = nm;
      }
    }
#pragma unroll
    for (int r = 0; r < 16; ++r) {
#pragma unroll
      for (int msk = 1; msk <= 16; msk <<= 1) {
        const float om = __shfl_xor(m[s][r], msk), oz = __shfl_xor(Z[s][r], msk);
        const float nm = fmaxf(m[s][r], om);
        Z[s][r] = Z[s][r] * __expf(m[s][r] - nm) + oz * __expf(om - nm);
        m[s][r] = nm;
      }
      Zi[s][r] = 1.f / Z[s][r];
    }
  }

#pragma unroll
  for (int s = 0; s < 2; ++s) {
    const int R0 = (wave * 2 + s) * 32;
    bf16x8 af[16];
#pragma unroll
    for (int k2 = 0; k2 < 16; ++k2)
      af[k2] = *(const bf16x8*)&win[R0 + lc][k2 * 16 + hi * 8];
    for (int ct = 0; ct < 8; ++ct) {
      f32x16 Ca = {0.f,0.f,0.f,0.f,0.f,0.f,0.f,0.f,0.f,0.f,0.f,0.f,0.f,0.f,0.f,0.f};
      f32x16 Cb = Ca;
#pragma unroll
      for (int k2 = 0; k2 < 16; k2 += 2) {
        bf16x8 b0 = *(const bf16x8*)&win[ct * 32 + lc][k2 * 16 + hi * 8];
        bf16x8 b1 = *(const bf16x8*)&win[ct * 32 + lc][(k2 + 1) * 16 + hi * 8];
        Ca = __builtin_amdgcn_mfma_f32_32x32x16_bf16(af[k2], b0, Ca, 0, 0, 0);
        Cb = __builtin_amdgcn_mfma_f32_32x32x16_bf16(af[k2 + 1], b1, Cb, 0, 0, 0);
      }
      float cs = 0.f;
#pragma unroll
      for (int r = 0; r < 16; ++r)
        cs += __expf((Ca[r] + Cb[r]) * 0.0625f - m[s][r]) * Zi[s][r];
      cs += __shfl_xor(cs, 32);
      if (hi == 0) atomicAdd(&a[ct * 32 + lc], cs);
    }
  }
  __syncthreads();

  {
    const int d = tid;
    float acc = 0.f;
#pragma unroll 8
    for (int k = 0; k < 256; ++k) acc += a[k] * bf2f(win[k][d]);
    pooled[(size_t)l * D + d] = acc * (1.f / 256.f);
  }
}

// ---------------------------------------------------------------------------
// Overlap-average scatter of pooled windows -> catb[t][768] (bf16)
// ---------------------------------------------------------------------------
DEVFN float gatherp(const float* __restrict__ pooled, int r, int c, int W, int s, int nS, int d) {
  int amin = max(0, (r - W + s) / s), amax = min(nS - 1, r / s);
  int bmin = max(0, (c - W + s) / s), bmax = min(nS - 1, c / s);
  float acc = 0.f;
  int cnt = 0;
  for (int a = amin; a <= amax; ++a)
    for (int b = bmin; b <= bmax; ++b) { acc += pooled[(size_t)(a * nS + b) * D + d]; ++cnt; }
  return acc / (float)cnt;
}

__global__ void k_combine(const float* __restrict__ p0, const float* __restrict__ p1,
                          const float* __restrict__ p2, unsigned short* __restrict__ catb) {
  const int t = blockIdx.x, d = threadIdx.x;
  const int r = t >> 6, c = t & 63;
  unsigned short* o = catb + (size_t)t * 768;
  o[d]       = f2bf(gatherp(p0, r, c, 4, 2, 31, d));
  o[256 + d] = f2bf(gatherp(p1, r, c, 8, 4, 15, d));
  o[512 + d] = f2bf(gatherp(p2, r, c, 16, 8, 7, d));
}

// ---------------------------------------------------------------------------
// Block-wide sum of (a, b) over 256 threads
// ---------------------------------------------------------------------------
DEVFN float2 block_sum2(float a, float b) {
  __shared__ float sb[8];
#pragma unroll
  for (int m = 32; m; m >>= 1) { a += __shfl_xor(a, m); b += __shfl_xor(b, m); }
  const int w = threadIdx.x >> 6;
  __syncthreads();
  if ((threadIdx.x & 63) == 0) { sb[w] = a; sb[4 + w] = b; }
  __syncthreads();
  return make_float2(sb[0] + sb[1] + sb[2] + sb[3], sb[4] + sb[5] + sb[6] + sb[7]);
}

// out = LN(a (+ b)); optional bf16 dual write. In-place safe (out==a).
__global__ __launch_bounds__(256) void k_ln(float* __restrict__ out, unsigned short* __restrict__ outb,
                                            const float* __restrict__ a, const float* __restrict__ b,
                                            const float* __restrict__ g, const float* __restrict__ be) {
  const size_t i = (size_t)blockIdx.x * D + threadIdx.x;
  float v = a[i] + (b ? b[i] : 0.f);
  float2 s = block_sum2(v, v * v);
  float mean = s.x * (1.f / D);
  float var = s.y * (1.f / D) - mean * mean;
  const float r = (v - mean) * rsqrtf(var + 1e-5f) * g[threadIdx.x] + be[threadIdx.x];
  out[i] = r;
  if (outb) outb[i] = f2bf(r);
}

// ---------------------------------------------------------------------------
// MFMA flash attention, bf16 I/O. Grid (S/64, NH), 4 waves, 16 q/wave.
// K row-major LDS; V & P XOR-swizzled transposed LDS (stride 64, 8-ush grains).
// ---------------------------------------------------------------------------
__global__ __launch_bounds__(256) void k_flash_mfma(const unsigned short* __restrict__ Qg,
                                                    const unsigned short* __restrict__ Kg,
                                                    const unsigned short* __restrict__ Vg,
                                                    unsigned short* __restrict__ Og) {
  const int h = blockIdx.y;
  const int tid = threadIdx.x;
  const int wave = tid >> 6, lane = tid & 63;
  const int lr = lane & 15, lg = lane >> 4;

  __shared__ unsigned short Kf[64][40];
  __shared__ unsigned short VT[32][64];
  __shared__ unsigned short Pl[4][16][64];

  const int q0 = blockIdx.x * 64 + wave * 16;
  const float scale = 0.17677669529663687f;  // 1/sqrt(32)

  const bf16x8 qfrag = *(const bf16x8*)(Qg + (size_t)(q0 + lr) * D + h * DH + lg * 8);

  f32x4 o0 = {0.f, 0.f, 0.f, 0.f}, o1 = {0.f, 0.f, 0.f, 0.f};
  float mrow[4] = {-INFINITY, -INFINITY, -INFINITY, -INFINITY};
  float lrow[4] = {0.f, 0.f, 0.f, 0.f};

  for (int kt = 0; kt < S / 64; ++kt) {
    {  // stage 64 keys of K (row-major) + V (transposed, swizzled), bf16
      const int key = tid >> 2, c8 = (tid & 3) * 8;
      const size_t rowb = (size_t)(kt * 64 + key) * D + h * DH + c8;
      *(bf16x8*)&Kf[key][c8] = *(const bf16x8*)(Kg + rowb);
      const bf16x8 vv = *(const bf16x8*)(Vg + rowb);
#pragma unroll
      for (int i = 0; i < 8; ++i)
        VT[c8 + i][swz(key, c8 + i)] = (unsigned short)vv[i];
    }
    __syncthreads();

    f32x4 s[4];
#pragma unroll
    for (int k16 = 0; k16 < 4; ++k16) {
      bf16x8 kb = *(const bf16x8*)&Kf[k16 * 16 + lr][lg * 8];
      f32x4 z = {0.f, 0.f, 0.f, 0.f};
      s[k16] = __builtin_amdgcn_mfma_f32_16x16x32_bf16(qfrag, kb, z, 0, 0, 0);
#pragma unroll
      for (int r = 0; r < 4; ++r) s[k16][r] *= scale;
    }
    float c[4];
#pragma unroll
    for (int r = 0; r < 4; ++r) {
      float tm = fmaxf(fmaxf(s[0][r], s[1][r]), fmaxf(s[2][r], s[3][r]));
      tm = fmaxf(tm, __shfl_xor(tm, 1)); tm = fmaxf(tm, __shfl_xor(tm, 2));
      tm = fmaxf(tm, __shfl_xor(tm, 4)); tm = fmaxf(tm, __shfl_xor(tm, 8));
      const float nm = fmaxf(mrow[r], tm);
      c[r] = __expf(mrow[r] - nm);
      mrow[r] = nm;
      float ls = 0.f;
#pragma unroll
      for (int k16 = 0; k16 < 4; ++k16) {
        const float p = __expf(s[k16][r] - nm);
        s[k16][r] = p;
        ls += p;
      }
      ls += __shfl_xor(ls, 1); ls += __shfl_xor(ls, 2);
      ls += __shfl_xor(ls, 4); ls += __shfl_xor(ls, 8);
      lrow[r] = lrow[r] * c[r] + ls;
    }
#pragma unroll
    for (int k16 = 0; k16 < 4; ++k16)
#pragma unroll
      for (int r = 0; r < 4; ++r)
        Pl[wave][lg * 4 + r][swz(k16 * 16 + lr, lg * 4 + r)] = f2bf(s[k16][r]);
#pragma unroll
    for (int r = 0; r < 4; ++r) { o0[r] *= c[r]; o1[r] *= c[r]; }
#pragma unroll
    for (int kt2 = 0; kt2 < 2; ++kt2) {
      const int kb0 = kt2 * 32 + lg * 8;
      bf16x8 pa = *(const bf16x8*)&Pl[wave][lr][swz(kb0, lr)];
      bf16x8 v0 = *(const bf16x8*)&VT[lr][swz(kb0, lr)];
      bf16x8 v1 = *(const bf16x8*)&VT[16 + lr][swz(kb0, 16 + lr)];
      o0 = __builtin_amdgcn_mfma_f32_16x16x32_bf16(pa, v0, o0, 0, 0, 0);
      o1 = __builtin_amdgcn_mfma_f32_16x16x32_bf16(pa, v1, o1, 0, 0, 0);
    }
    __syncthreads();
  }

#pragma unroll
  for (int r = 0; r < 4; ++r) {
    const float inv = 1.f / lrow[r];
    unsigned short* op = Og + (size_t)(q0 + lg * 4 + r) * D + h * DH + lr;
    op[0]  = f2bf(o0[r] * inv);
    op[16] = f2bf(o1[r] * inv);
  }
}

// ---------------------------------------------------------------------------
// Gate helpers
// ---------------------------------------------------------------------------
__global__ __launch_bounds__(256) void k_colmean(const float* __restrict__ xl,
                                                 const float* __restrict__ xg,
                                                 float* __restrict__ gbuf) {
  const int j = threadIdx.x;
  const int t0 = blockIdx.x * 64;
  float s = 0.f;
  for (int t = 0; t < 64; ++t) {
    size_t i = (size_t)(t0 + t) * D + j;
    s += xl[i] + xg[i];
  }
  atomicAdd(&gbuf[j], s * 0.5f);
}

__global__ __launch_bounds__(256) void k_gate(float* __restrict__ gbuf,
                                              const float* __restrict__ gw,
                                              const float* __restrict__ gb) {
  const int j = threadIdx.x;
  const float gm = gbuf[j] * (1.f / (float)S);
  float2 s = block_sum2(gm * gw[2 * j], gm * gw[2 * j + 1]);
  if (j == 0) {
    float g0 = s.x + gb[0], g1 = s.y + gb[1];
    float mx = fmaxf(g0, g1);
    float e0 = __expf(g0 - mx), e1 = __expf(g1 - mx);
    gbuf[256] = e0 / (e0 + e1);
    gbuf[257] = e1 / (e0 + e1);
  }
}

__global__ __launch_bounds__(256) void k_xf(const float* __restrict__ xl,
                                            const float* __restrict__ xg,
                                            const float* __restrict__ gbuf,
                                            float* __restrict__ xf,
                                            unsigned short* __restrict__ xfb) {
  const float alpha = gbuf[256], beta = gbuf[257];
  const size_t i = ((size_t)blockIdx.x * 256 + threadIdx.x) * 4;
  float4 a = *(const float4*)(xg + i);
  float4 b = *(const float4*)(xl + i);
  float4 r;
  r.x = alpha * a.x + beta * b.x;
  r.y = alpha * a.y + beta * b.y;
  r.z = alpha * a.z + beta * b.z;
  r.w = alpha * a.w + beta * b.w;
  *(float4*)(xf + i) = r;
  unsigned lo = (unsigned)f2bf(r.x) | ((unsigned)f2bf(r.y) << 16);
  unsigned hi = (unsigned)f2bf(r.z) | ((unsigned)f2bf(r.w) << 16);
  *(uint2*)(xfb + i) = make_uint2(lo, hi);
}

// ===========================================================================
extern "C" void kernel_launch(void* const* d_in, const int* in_sizes, int n_in,
                              void* d_out, int out_size, void* d_ws, size_t ws_size,
                              hipStream_t stream) {
  const float* x   = (const float*)d_in[0];
  const float* fw  = (const float*)d_in[2];
  const float* fb  = (const float*)d_in[3];
  const float* fg  = (const float*)d_in[4];
  const float* fbb = (const float*)d_in[5];
  const float* wq  = (const float*)d_in[6];
  const float* wk  = (const float*)d_in[7];
  const float* wv  = (const float*)d_in[8];
  const float* bq  = (const float*)d_in[9];
  const float* bk  = (const float*)d_in[10];
  const float* bv  = (const float*)d_in[11];
  const float* wo  = (const float*)d_in[12];
  const float* bo  = (const float*)d_in[13];
  const float* gw  = (const float*)d_in[14];
  const float* gb  = (const float*)d_in[15];
  const float* w1  = (const float*)d_in[16];
  const float* b1  = (const float*)d_in[17];
  const float* w2  = (const float*)d_in[18];
  const float* b2  = (const float*)d_in[19];
  const float* n1g = (const float*)d_in[20];
  const float* n1b = (const float*)d_in[21];
  const float* n2g = (const float*)d_in[22];
  const float* n2b = (const float*)d_in[23];
  const float* n3g = (const float*)d_in[24];
  const float* n3b = (const float*)d_in[25];
  float* out = (float*)d_out;

  // ---- workspace carve (bytes) ----
  char* base = (char*)d_ws;
  size_t off = 0;
  auto carve = [&](size_t bytes) { char* p = base + off; off += (bytes + 255) & ~(size_t)255; return p; };
  float* p0 = (float*)carve(961 * 256 * 4);
  float* p1 = (float*)carve(225 * 256 * 4);
  float* p2 = (float*)carve(49 * 256 * 4);
  unsigned short* fwT = (unsigned short*)carve(256 * 768 * 2);
  unsigned short* wqT = (unsigned short*)carve(256 * 256 * 2);
  unsigned short* wkT = (unsigned short*)carve(256 * 256 * 2);
  unsigned short* wvT = (unsigned short*)carve(256 * 256 * 2);
  unsigned short* woT = (unsigned short*)carve(256 * 256 * 2);
  unsigned short* w1T = (unsigned short*)carve(1024 * 256 * 2);
  unsigned short* w2T = (unsigned short*)carve(256 * 1024 * 2);
  char* R = carve(8388608);                      // catb(6.3MB) -> xg(4MB) -> hbuf(8MB)
  unsigned short* catb = (unsigned short*)R;
  float* xg            = (float*)R;
  unsigned short* hbuf = (unsigned short*)R;
  unsigned short* qb = (unsigned short*)carve((size_t)S * D * 2);
  unsigned short* kb = (unsigned short*)carve((size_t)S * D * 2);
  unsigned short* vb = (unsigned short*)carve((size_t)S * D * 2);
  float* xf            = (float*)qb;             // qb+kb region, dead after flash
  unsigned short* xfb  = vb;                     // vb region, dead after flash
  float* t1  = (float*)carve((size_t)S * D * 4); // fuse out; later ffo
  float* ffo = t1;
  unsigned short* t1b = (unsigned short*)carve((size_t)S * D * 2);
  float* xl  = (float*)carve((size_t)S * D * 4);
  unsigned short* xlb = (unsigned short*)carve((size_t)S * D * 2);
  float* gbuf = (float*)carve(264 * 4);

  hipMemsetAsync(gbuf, 0, 264 * sizeof(float), stream);

  // weight pre-transpose (bf16 WT[N][K])
  k_wt<<<dim3(960), dim3(256), 0, stream>>>(fw, wq, wk, wv, wo, w1, w2,
                                            fwT, wqT, wkT, wvT, woT, w1T, w2T);
  // local multi-scale window attention -> pooled per window (MFMA)
  k_local_s<4, 64><<<dim3(961), dim3(64), 0, stream>>>(x, p0, 31);
  k_local_s<8, 256><<<dim3(225), dim3(256), 0, stream>>>(x, p1, 15);
  k_local16<<<dim3(49), dim3(256), 0, stream>>>(x, p2, 7);
  // scatter/avg -> catb[S][768] bf16
  k_combine<<<dim3(S), dim3(256), 0, stream>>>(p0, p1, p2, catb);
  // fuse GEMM + LNs
  k_gemm_m<768, 0, 0><<<dim3(S / 32, 8), dim3(64), 0, stream>>>(catb, fwT, fb, t1, 256);
  k_ln<<<dim3(S), dim3(256), 0, stream>>>(t1, nullptr, t1, nullptr, fg, fbb);
  k_ln<<<dim3(S), dim3(256), 0, stream>>>(xl, xlb, x, t1, n1g, n1b);
  // global MHA (bf16 q/k/v)
  k_gemm_m<256, 1, 0><<<dim3(S / 32, 8), dim3(64), 0, stream>>>(xlb, wqT, bq, qb, 256);
  k_gemm_m<256, 1, 0><<<dim3(S / 32, 8), dim3(64), 0, stream>>>(xlb, wkT, bk, kb, 256);
  k_gemm_m<256, 1, 0><<<dim3(S / 32, 8), dim3(64), 0, stream>>>(xlb, wvT, bv, vb, 256);
  k_flash_mfma<<<dim3(S / 64, NH), dim3(256), 0, stream>>>(qb, kb, vb, t1b);
  k_gemm_m<256, 0, 0><<<dim3(S / 32, 8), dim3(64), 0, stream>>>(t1b, woT, bo, xf, 256);
  k_ln<<<dim3(S), dim3(256), 0, stream>>>(xg, nullptr, xl, xf, n2g, n2b);
  // gate
  k_colmean<<<dim3(64), dim3(256), 0, stream>>>(xl, xg, gbuf);
  k_gate<<<dim3(1), dim3(256), 0, stream>>>(gbuf, gw, gb);
  k_xf<<<dim3(S * D / 1024), dim3(256), 0, stream>>>(xl, xg, gbuf, xf, xfb);
  // FFN + final LN
  k_gemm_m<256, 1, 1><<<dim3(S / 32, 32), dim3(64), 0, stream>>>(xfb, w1T, b1, hbuf, 1024);
  k_gemm_m<1024, 0, 0><<<dim3(S / 32, 8), dim3(64), 0, stream>>>(hbuf, w2T, b2, ffo, 256);
  k_ln<<<dim3(S), dim3(256), 0, stream>>>(out, nullptr, xf, ffo, n3g, n3b);
}

// Round 6
// 265.351 us; speedup vs baseline: 5.6294x; 1.2283x over previous
//
#include <hip/hip_runtime.h>
#include <cstdint>
#include <cstddef>

// ============================================================================
// HierarchicalTransformerBlock: B=1, S=4096 (64x64 grid), D=256, NH=8, dh=32,
// DFF=1024, local windows w = 4,8,16 (stride w/2).
// Round 6: flash rewritten — swapped QK^T (P lane-local, zero P-LDS),
// V via ds_read_b64_tr_b16 from subtiled LDS, b128-only staging.
// GEMMs/locals unchanged from round 5.
// ============================================================================

#define DEVFN __device__ __forceinline__

constexpr int S    = 4096;
constexpr int D    = 256;
constexpr int GRID = 64;
constexpr int NH   = 8;
constexpr int DH   = 32;

typedef __attribute__((ext_vector_type(8))) short bf16x8;
typedef __attribute__((ext_vector_type(4))) float f32x4;
typedef __attribute__((ext_vector_type(16))) float f32x16;
typedef __attribute__((ext_vector_type(2))) unsigned int u32x2;

DEVFN float asf(unsigned u) { return __uint_as_float(u); }

DEVFN unsigned short f2bf(float f) {  // round-to-nearest-even bf16
  unsigned u = __float_as_uint(f);
  u += 0x7fffu + ((u >> 16) & 1u);
  return (unsigned short)(u >> 16);
}
DEVFN float bf2f(unsigned short s) { return __uint_as_float(((unsigned)s) << 16); }

DEVFN bf16x8 pack8(float4 a, float4 b) {
  bf16x8 kv;
  kv[0] = (short)f2bf(a.x); kv[1] = (short)f2bf(a.y);
  kv[2] = (short)f2bf(a.z); kv[3] = (short)f2bf(a.w);
  kv[4] = (short)f2bf(b.x); kv[5] = (short)f2bf(b.y);
  kv[6] = (short)f2bf(b.z); kv[7] = (short)f2bf(b.w);
  return kv;
}

// ---------------------------------------------------------------------------
// Weight pre-transpose: fp32 W[K][N] -> bf16 WT[N][K]; 32x32 tiles via LDS.
// ---------------------------------------------------------------------------
__global__ __launch_bounds__(256) void k_wt(
    const float* fw, const float* wq, const float* wk, const float* wv,
    const float* wo, const float* w1, const float* w2,
    unsigned short* fwT, unsigned short* wqT, unsigned short* wkT,
    unsigned short* wvT, unsigned short* woT, unsigned short* w1T,
    unsigned short* w2T) {
  __shared__ unsigned short tile[32][36];
  const int bid = blockIdx.x;
  const float* src; unsigned short* dst; int K, N, t;
  if (bid < 192)      { src = fw; dst = fwT; K = 768;  N = 256;  t = bid; }
  else if (bid < 256) { src = wq; dst = wqT; K = 256;  N = 256;  t = bid - 192; }
  else if (bid < 320) { src = wk; dst = wkT; K = 256;  N = 256;  t = bid - 256; }
  else if (bid < 384) { src = wv; dst = wvT; K = 256;  N = 256;  t = bid - 320; }
  else if (bid < 448) { src = wo; dst = woT; K = 256;  N = 256;  t = bid - 384; }
  else if (bid < 704) { src = w1; dst = w1T; K = 256;  N = 1024; t = bid - 448; }
  else                { src = w2; dst = w2T; K = 1024; N = 256;  t = bid - 704; }
  const int nkt = K >> 5;
  const int k0 = (t % nkt) * 32, n0 = (t / nkt) * 32;
  const int i = threadIdx.x >> 3, j4 = threadIdx.x & 7;
  const float4 v = *(const float4*)(src + (size_t)(k0 + i) * N + n0 + j4 * 4);
  unsigned lo = (unsigned)f2bf(v.x) | ((unsigned)f2bf(v.y) << 16);
  unsigned hi = (unsigned)f2bf(v.z) | ((unsigned)f2bf(v.w) << 16);
  *(uint2*)&tile[i][j4 * 4] = make_uint2(lo, hi);
  __syncthreads();
  unsigned o0 = tile[j4 * 4 + 0][i], o1 = tile[j4 * 4 + 1][i];
  unsigned o2 = tile[j4 * 4 + 2][i], o3 = tile[j4 * 4 + 3][i];
  *(uint2*)(dst + (size_t)(n0 + i) * K + k0 + j4 * 4) =
      make_uint2(o0 | (o1 << 16), o2 | (o3 << 16));
}

// ---------------------------------------------------------------------------
// MFMA GEMM: C[M][N] = Ab[M][K](bf16) @ WT[N][K]^T(bf16) + bias.
// ---------------------------------------------------------------------------
template <int K, int OUTBF, int ACT>
__global__ __launch_bounds__(64) void k_gemm_m(const unsigned short* __restrict__ Ab,
                                               const unsigned short* __restrict__ WT,
                                               const float* __restrict__ bias,
                                               void* __restrict__ Cout, int N) {
  const int lane = threadIdx.x;
  const int lc = lane & 31, hi = lane >> 5;
  const int m0 = blockIdx.x * 32, n0 = blockIdx.y * 32;
  const unsigned short* ap = Ab + (size_t)(m0 + lc) * K + hi * 8;
  const unsigned short* bp = WT + (size_t)(n0 + lc) * K + hi * 8;
  f32x16 acc = {0.f,0.f,0.f,0.f,0.f,0.f,0.f,0.f,0.f,0.f,0.f,0.f,0.f,0.f,0.f,0.f};
#pragma unroll 4
  for (int k0 = 0; k0 < K; k0 += 16) {
    bf16x8 a = *(const bf16x8*)(ap + k0);
    bf16x8 b = *(const bf16x8*)(bp + k0);
    acc = __builtin_amdgcn_mfma_f32_32x32x16_bf16(a, b, acc, 0, 0, 0);
  }
  const float bv = bias[n0 + lc];
#pragma unroll
  for (int r = 0; r < 16; ++r) {
    const int row = (r & 3) + 8 * (r >> 2) + 4 * hi;
    float v = acc[r] + bv;
    if (ACT == 1) v = 0.5f * v * (1.f + erff(v * 0.70710678118654752f));
    if (OUTBF) ((unsigned short*)Cout)[(size_t)(m0 + row) * N + n0 + lc] = f2bf(v);
    else       ((float*)Cout)[(size_t)(m0 + row) * N + n0 + lc] = v;
  }
}

// ---------------------------------------------------------------------------
// Local windowed attention, w=4/8 (16x16x32 MFMA), one window per block.
// ---------------------------------------------------------------------------
template <int W, int THREADS>
__global__ __launch_bounds__(THREADS) void k_local_s(const float* __restrict__ x,
                                                     float* __restrict__ pooled, int nS) {
  constexpr int NT  = W * W;
  constexpr int NCT = NT / 16;
  constexpr int LDE = 264;
  __shared__ unsigned short win[NT][LDE];
  __shared__ float a[NT];
  const int tid = threadIdx.x;
  const int wave = tid >> 6, lane = tid & 63;
  const int lr = lane & 15, lg = lane >> 4;
  const int l = blockIdx.x;
  const int row0 = (l / nS) * (W / 2), col0 = (l % nS) * (W / 2);

  for (int e8 = tid; e8 < NT * 32; e8 += THREADS) {
    const int t = e8 >> 5, c8 = (e8 & 31) * 8;
    const float* src = x + ((size_t)((row0 + t / W) * GRID + col0 + (t % W))) * D + c8;
    *(bf16x8*)&win[t][c8] = pack8(*(const float4*)src, *(const float4*)(src + 4));
  }
  if (tid < NT) a[tid] = 0.f;
  __syncthreads();

  bf16x8 af[8];
#pragma unroll
  for (int k2 = 0; k2 < 8; ++k2)
    af[k2] = *(const bf16x8*)&win[wave * 16 + lr][k2 * 32 + lg * 8];

  float m[4], Z[4], Zi[4];
#pragma unroll
  for (int r = 0; r < 4; ++r) { m[r] = -INFINITY; Z[r] = 0.f; }

  for (int ct = 0; ct < NCT; ++ct) {
    f32x4 Ca = {0.f, 0.f, 0.f, 0.f}, Cb = {0.f, 0.f, 0.f, 0.f};
#pragma unroll
    for (int k2 = 0; k2 < 8; k2 += 2) {
      bf16x8 b0 = *(const bf16x8*)&win[ct * 16 + lr][k2 * 32 + lg * 8];
      bf16x8 b1 = *(const bf16x8*)&win[ct * 16 + lr][(k2 + 1) * 32 + lg * 8];
      Ca = __builtin_amdgcn_mfma_f32_16x16x32_bf16(af[k2], b0, Ca, 0, 0, 0);
      Cb = __builtin_amdgcn_mfma_f32_16x16x32_bf16(af[k2 + 1], b1, Cb, 0, 0, 0);
    }
#pragma unroll
    for (int r = 0; r < 4; ++r) {
      const float sv = (Ca[r] + Cb[r]) * 0.0625f;
      const float nm = fmaxf(m[r], sv);
      Z[r] = Z[r] * __expf(m[r] - nm) + __expf(sv - nm);
      m[r] = nm;
    }
  }
#pragma unroll
  for (int r = 0; r < 4; ++r) {
#pragma unroll
    for (int msk = 1; msk <= 8; msk <<= 1) {
      const float om = __shfl_xor(m[r], msk), oz = __shfl_xor(Z[r], msk);
      const float nm = fmaxf(m[r], om);
      Z[r] = Z[r] * __expf(m[r] - nm) + oz * __expf(om - nm);
      m[r] = nm;
    }
    Zi[r] = 1.f / Z[r];
  }

  for (int ct = 0; ct < NCT; ++ct) {
    f32x4 Ca = {0.f, 0.f, 0.f, 0.f}, Cb = {0.f, 0.f, 0.f, 0.f};
#pragma unroll
    for (int k2 = 0; k2 < 8; k2 += 2) {
      bf16x8 b0 = *(const bf16x8*)&win[ct * 16 + lr][k2 * 32 + lg * 8];
      bf16x8 b1 = *(const bf16x8*)&win[ct * 16 + lr][(k2 + 1) * 32 + lg * 8];
      Ca = __builtin_amdgcn_mfma_f32_16x16x32_bf16(af[k2], b0, Ca, 0, 0, 0);
      Cb = __builtin_amdgcn_mfma_f32_16x16x32_bf16(af[k2 + 1], b1, Cb, 0, 0, 0);
    }
    float cs = 0.f;
#pragma unroll
    for (int r = 0; r < 4; ++r)
      cs += __expf((Ca[r] + Cb[r]) * 0.0625f - m[r]) * Zi[r];
    cs += __shfl_xor(cs, 16);
    cs += __shfl_xor(cs, 32);
    if (lg == 0) atomicAdd(&a[ct * 16 + lr], cs);
  }
  __syncthreads();

  for (int d = tid; d < D; d += THREADS) {
    float acc = 0.f;
#pragma unroll 8
    for (int k = 0; k < NT; ++k) acc += a[k] * bf2f(win[k][d]);
    pooled[(size_t)l * D + d] = acc * (1.f / NT);
  }
}

// ---------------------------------------------------------------------------
// Local windowed attention, w=16 (NT=256), 32x32x16 MFMA, one window/block.
// ---------------------------------------------------------------------------
__global__ __launch_bounds__(256, 1) void k_local16(const float* __restrict__ x,
                                                    float* __restrict__ pooled, int nS) {
  constexpr int LDE = 264;
  __shared__ unsigned short win[256][LDE];
  __shared__ float a[256];
  const int tid = threadIdx.x;
  const int wave = tid >> 6, lane = tid & 63;
  const int lc = lane & 31, hi = lane >> 5;
  const int l = blockIdx.x;
  const int row0 = (l / nS) * 8, col0 = (l % nS) * 8;

  for (int e8 = tid; e8 < 256 * 32; e8 += 256) {
    const int t = e8 >> 5, c8 = (e8 & 31) * 8;
    const float* src = x + ((size_t)((row0 + (t >> 4)) * GRID + col0 + (t & 15))) * D + c8;
    *(bf16x8*)&win[t][c8] = pack8(*(const float4*)src, *(const float4*)(src + 4));
  }
  a[tid] = 0.f;
  __syncthreads();

  float m[2][16], Z[2][16], Zi[2][16];
#pragma unroll
  for (int s = 0; s < 2; ++s)
#pragma unroll
    for (int r = 0; r < 16; ++r) { m[s][r] = -INFINITY; Z[s][r] = 0.f; }

#pragma unroll
  for (int s = 0; s < 2; ++s) {
    const int R0 = (wave * 2 + s) * 32;
    bf16x8 af[16];
#pragma unroll
    for (int k2 = 0; k2 < 16; ++k2)
      af[k2] = *(const bf16x8*)&win[R0 + lc][k2 * 16 + hi * 8];
    for (int ct = 0; ct < 8; ++ct) {
      f32x16 Ca = {0.f,0.f,0.f,0.f,0.f,0.f,0.f,0.f,0.f,0.f,0.f,0.f,0.f,0.f,0.f,0.f};
      f32x16 Cb = Ca;
#pragma unroll
      for (int k2 = 0; k2 < 16; k2 += 2) {
        bf16x8 b0 = *(const bf16x8*)&win[ct * 32 + lc][k2 * 16 + hi * 8];
        bf16x8 b1 = *(const bf16x8*)&win[ct * 32 + lc][(k2 + 1) * 16 + hi * 8];
        Ca = __builtin_amdgcn_mfma_f32_32x32x16_bf16(af[k2], b0, Ca, 0, 0, 0);
        Cb = __builtin_amdgcn_mfma_f32_32x32x16_bf16(af[k2 + 1], b1, Cb, 0, 0, 0);
      }
#pragma unroll
      for (int r = 0; r < 16; ++r) {
        const float sv = (Ca[r] + Cb[r]) * 0.0625f;
        const float nm = fmaxf(m[s][r], sv);
        Z[s][r] = Z[s][r] * __expf(m[s][r] - nm) + __expf(sv - nm);
        m[s][r] = nm;
      }
    }
#pragma unroll
    for (int r = 0; r < 16; ++r) {
#pragma unroll
      for (int msk = 1; msk <= 16; msk <<= 1) {
        const float om = __shfl_xor(m[s][r], msk), oz = __shfl_xor(Z[s][r], msk);
        const float nm = fmaxf(m[s][r], om);
        Z[s][r] = Z[s][r] * __expf(m[s][r] - nm) + oz * __expf(om - nm);
        m[s][r] = nm;
      }
      Zi[s][r] = 1.f / Z[s][r];
    }
  }

#pragma unroll
  for (int s = 0; s < 2; ++s) {
    const int R0 = (wave * 2 + s) * 32;
    bf16x8 af[16];
#pragma unroll
    for (int k2 = 0; k2 < 16; ++k2)
      af[k2] = *(const bf16x8*)&win[R0 + lc][k2 * 16 + hi * 8];
    for (int ct = 0; ct < 8; ++ct) {
      f32x16 Ca = {0.f,0.f,0.f,0.f,0.f,0.f,0.f,0.f,0.f,0.f,0.f,0.f,0.f,0.f,0.f,0.f};
      f32x16 Cb = Ca;
#pragma unroll
      for (int k2 = 0; k2 < 16; k2 += 2) {
        bf16x8 b0 = *(const bf16x8*)&win[ct * 32 + lc][k2 * 16 + hi * 8];
        bf16x8 b1 = *(const bf16x8*)&win[ct * 32 + lc][(k2 + 1) * 16 + hi * 8];
        Ca = __builtin_amdgcn_mfma_f32_32x32x16_bf16(af[k2], b0, Ca, 0, 0, 0);
        Cb = __builtin_amdgcn_mfma_f32_32x32x16_bf16(af[k2 + 1], b1, Cb, 0, 0, 0);
      }
      float cs = 0.f;
#pragma unroll
      for (int r = 0; r < 16; ++r)
        cs += __expf((Ca[r] + Cb[r]) * 0.0625f - m[s][r]) * Zi[s][r];
      cs += __shfl_xor(cs, 32);
      if (hi == 0) atomicAdd(&a[ct * 32 + lc], cs);
    }
  }
  __syncthreads();

  {
    const int d = tid;
    float acc = 0.f;
#pragma unroll 8
    for (int k = 0; k < 256; ++k) acc += a[k] * bf2f(win[k][d]);
    pooled[(size_t)l * D + d] = acc * (1.f / 256.f);
  }
}

// ---------------------------------------------------------------------------
// Overlap-average scatter of pooled windows -> catb[t][768] (bf16)
// ---------------------------------------------------------------------------
DEVFN float gatherp(const float* __restrict__ pooled, int r, int c, int W, int s, int nS, int d) {
  int amin = max(0, (r - W + s) / s), amax = min(nS - 1, r / s);
  int bmin = max(0, (c - W + s) / s), bmax = min(nS - 1, c / s);
  float acc = 0.f;
  int cnt = 0;
  for (int a = amin; a <= amax; ++a)
    for (int b = bmin; b <= bmax; ++b) { acc += pooled[(size_t)(a * nS + b) * D + d]; ++cnt; }
  return acc / (float)cnt;
}

__global__ void k_combine(const float* __restrict__ p0, const float* __restrict__ p1,
                          const float* __restrict__ p2, unsigned short* __restrict__ catb) {
  const int t = blockIdx.x, d = threadIdx.x;
  const int r = t >> 6, c = t & 63;
  unsigned short* o = catb + (size_t)t * 768;
  o[d]       = f2bf(gatherp(p0, r, c, 4, 2, 31, d));
  o[256 + d] = f2bf(gatherp(p1, r, c, 8, 4, 15, d));
  o[512 + d] = f2bf(gatherp(p2, r, c, 16, 8, 7, d));
}

// ---------------------------------------------------------------------------
// Block-wide sum of (a, b) over 256 threads
// ---------------------------------------------------------------------------
DEVFN float2 block_sum2(float a, float b) {
  __shared__ float sb[8];
#pragma unroll
  for (int m = 32; m; m >>= 1) { a += __shfl_xor(a, m); b += __shfl_xor(b, m); }
  const int w = threadIdx.x >> 6;
  __syncthreads();
  if ((threadIdx.x & 63) == 0) { sb[w] = a; sb[4 + w] = b; }
  __syncthreads();
  return make_float2(sb[0] + sb[1] + sb[2] + sb[3], sb[4] + sb[5] + sb[6] + sb[7]);
}

// out = LN(a (+ b)); optional bf16 dual write. In-place safe (out==a).
__global__ __launch_bounds__(256) void k_ln(float* __restrict__ out, unsigned short* __restrict__ outb,
                                            const float* __restrict__ a, const float* __restrict__ b,
                                            const float* __restrict__ g, const float* __restrict__ be) {
  const size_t i = (size_t)blockIdx.x * D + threadIdx.x;
  float v = a[i] + (b ? b[i] : 0.f);
  float2 s = block_sum2(v, v * v);
  float mean = s.x * (1.f / D);
  float var = s.y * (1.f / D) - mean * mean;
  const float r = (v - mean) * rsqrtf(var + 1e-5f) * g[threadIdx.x] + be[threadIdx.x];
  out[i] = r;
  if (outb) outb[i] = f2bf(r);
}

// ---------------------------------------------------------------------------
// MFMA flash attention, swapped QK^T, in-register P, tr-read V.
// Grid (S/64, NH), 4 waves, 16 q/wave, 64-key tiles.
//   QK: s = mfma(K_frag, Q_frag) -> lane(lr,lg) holds S[q=lr][k16*16+lg*4+r]
//   PV: A-frag lane-local {p[2kt2][0..3], p[2kt2+1][0..3]} with permuted k;
//       B-frag via ds_read_b64_tr_b16 (4 bf16, 16-ushort stride) from
//       V subtiled LDS [dgrp][key>>2][key&3][dh&15].
// ---------------------------------------------------------------------------
__global__ __launch_bounds__(256) void k_flash_mfma(const unsigned short* __restrict__ Qg,
                                                    const unsigned short* __restrict__ Kg,
                                                    const unsigned short* __restrict__ Vg,
                                                    unsigned short* __restrict__ Og) {
  const int h = blockIdx.y;
  const int tid = threadIdx.x;
  const int wave = tid >> 6, lane = tid & 63;
  const int lr = lane & 15, lg = lane >> 4;

  __shared__ unsigned short Kf[64][40];   // row-major keys, pad 32->40
  __shared__ unsigned short VS[2048];     // [dgrp][key>>2][key&3][dh&15]

  const int q0 = blockIdx.x * 64 + wave * 16;

  // Q fragment (B-operand of swapped QK), pre-scaled by 1/sqrt(dh)
  bf16x8 qfrag;
  {
    const bf16x8 qraw = *(const bf16x8*)(Qg + (size_t)(q0 + lr) * D + h * DH + lg * 8);
    const float scale = 0.17677669529663687f;
#pragma unroll
    for (int j = 0; j < 8; ++j)
      qfrag[j] = (short)f2bf(bf2f((unsigned short)qraw[j]) * scale);
  }

  f32x4 o0 = {0.f, 0.f, 0.f, 0.f}, o1 = {0.f, 0.f, 0.f, 0.f};
  float mrow = -INFINITY, lrow = 0.f;

  // per-lane LDS byte address for tr reads: column top of this lane's subtile
  // (low 32 bits of generic LDS pointer == LDS segment offset; 4GiB aperture)
  const unsigned vsbase =
      (unsigned)(unsigned long long)(const void*)&VS[0] + (unsigned)(lg * 128 + lr * 2);

  for (int kt = 0; kt < S / 64; ++kt) {
    {  // stage: K row-major + V subtiled, one b128 write each per lane
      const int key = tid >> 2, c8 = (tid & 3) * 8;
      const size_t rowb = (size_t)(kt * 64 + key) * D + h * DH + c8;
      *(bf16x8*)&Kf[key][c8] = *(const bf16x8*)(Kg + rowb);
      const int vidx = (c8 >> 4) * 1024 + (key >> 2) * 64 + (key & 3) * 16 + (c8 & 15);
      *(bf16x8*)&VS[vidx] = *(const bf16x8*)(Vg + rowb);
    }
    __syncthreads();

    // swapped QK^T: s[k16][r] = S[q=lr][key = k16*16 + lg*4 + r]
    f32x4 s[4];
#pragma unroll
    for (int k16 = 0; k16 < 4; ++k16) {
      bf16x8 ka = *(const bf16x8*)&Kf[k16 * 16 + lr][lg * 8];
      f32x4 z = {0.f, 0.f, 0.f, 0.f};
      s[k16] = __builtin_amdgcn_mfma_f32_16x16x32_bf16(ka, qfrag, z, 0, 0, 0);
    }

    // issue V tr-reads early (latency hidden under softmax VALU)
    // offset = dgrp*2048 + kt2*1024 + t*512 (bytes)
    u32x2 tv000, tv001, tv010, tv011, tv100, tv101, tv110, tv111;  // [kt2][t][dg]
    asm volatile("ds_read_b64_tr_b16 %0, %1 offset:0"    : "=v"(tv000) : "v"(vsbase));
    asm volatile("ds_read_b64_tr_b16 %0, %1 offset:2048" : "=v"(tv001) : "v"(vsbase));
    asm volatile("ds_read_b64_tr_b16 %0, %1 offset:512"  : "=v"(tv010) : "v"(vsbase));
    asm volatile("ds_read_b64_tr_b16 %0, %1 offset:2560" : "=v"(tv011) : "v"(vsbase));
    asm volatile("ds_read_b64_tr_b16 %0, %1 offset:1024" : "=v"(tv100) : "v"(vsbase));
    asm volatile("ds_read_b64_tr_b16 %0, %1 offset:3072" : "=v"(tv101) : "v"(vsbase));
    asm volatile("ds_read_b64_tr_b16 %0, %1 offset:1536" : "=v"(tv110) : "v"(vsbase));
    asm volatile("ds_read_b64_tr_b16 %0, %1 offset:3584" : "=v"(tv111) : "v"(vsbase));

    // online softmax for q=lr (lane-local slices; merge across lg lanes)
    float tm = s[0][0];
#pragma unroll
    for (int k16 = 0; k16 < 4; ++k16)
#pragma unroll
      for (int r = 0; r < 4; ++r) tm = fmaxf(tm, s[k16][r]);
    tm = fmaxf(tm, __shfl_xor(tm, 16));
    tm = fmaxf(tm, __shfl_xor(tm, 32));
    const float nm = fmaxf(mrow, tm);
    const float cfac = __expf(mrow - nm);
    mrow = nm;
    float ls = 0.f;
#pragma unroll
    for (int k16 = 0; k16 < 4; ++k16)
#pragma unroll
      for (int r = 0; r < 4; ++r) { s[k16][r] = __expf(s[k16][r] - nm); ls += s[k16][r]; }
    ls += __shfl_xor(ls, 16);
    ls += __shfl_xor(ls, 32);
    lrow = lrow * cfac + ls;

    // rescale O by this lane's OUTPUT q-rows (q = lg*4 + r)
#pragma unroll
    for (int r = 0; r < 4; ++r) {
      const float cr = __shfl(cfac, lg * 4 + r);
      o0[r] *= cr; o1[r] *= cr;
    }

    // drain tr-reads; pin ordering (rule #18)
    asm volatile("s_waitcnt lgkmcnt(0)" ::: "memory");
    __builtin_amdgcn_sched_barrier(0);

    // PV: a = lane-local P (permuted k), b = tr-read V fragments
    union VB { u32x2 u2[2]; bf16x8 b; };
#pragma unroll
    for (int kt2 = 0; kt2 < 2; ++kt2) {
      bf16x8 pa;
#pragma unroll
      for (int j = 0; j < 4; ++j) {
        pa[j]     = (short)f2bf(s[2 * kt2][j]);
        pa[4 + j] = (short)f2bf(s[2 * kt2 + 1][j]);
      }
      VB v0, v1;
      if (kt2 == 0) { v0.u2[0] = tv000; v0.u2[1] = tv010; v1.u2[0] = tv001; v1.u2[1] = tv011; }
      else          { v0.u2[0] = tv100; v0.u2[1] = tv110; v1.u2[0] = tv101; v1.u2[1] = tv111; }
      o0 = __builtin_amdgcn_mfma_f32_16x16x32_bf16(pa, v0.b, o0, 0, 0, 0);
      o1 = __builtin_amdgcn_mfma_f32_16x16x32_bf16(pa, v1.b, o1, 0, 0, 0);
    }
    __syncthreads();
  }

  const float linv = 1.f / lrow;
#pragma unroll
  for (int r = 0; r < 4; ++r) {
    const float inv = __shfl(linv, lg * 4 + r);
    unsigned short* op = Og + (size_t)(q0 + lg * 4 + r) * D + h * DH + lr;
    op[0]  = f2bf(o0[r] * inv);
    op[16] = f2bf(o1[r] * inv);
  }
}

// ---------------------------------------------------------------------------
// Gate helpers
// ---------------------------------------------------------------------------
__global__ __launch_bounds__(256) void k_colmean(const float* __restrict__ xl,
                                                 const float* __restrict__ xg,
                                                 float* __restrict__ gbuf) {
  const int j = threadIdx.x;
  const int t0 = blockIdx.x * 64;
  float s = 0.f;
  for (int t = 0; t < 64; ++t) {
    size_t i = (size_t)(t0 + t) * D + j;
    s += xl[i] + xg[i];
  }
  atomicAdd(&gbuf[j], s * 0.5f);
}

__global__ __launch_bounds__(256) void k_gate(float* __restrict__ gbuf,
                                              const float* __restrict__ gw,
                                              const float* __restrict__ gb) {
  const int j = threadIdx.x;
  const float gm = gbuf[j] * (1.f / (float)S);
  float2 s = block_sum2(gm * gw[2 * j], gm * gw[2 * j + 1]);
  if (j == 0) {
    float g0 = s.x + gb[0], g1 = s.y + gb[1];
    float mx = fmaxf(g0, g1);
    float e0 = __expf(g0 - mx), e1 = __expf(g1 - mx);
    gbuf[256] = e0 / (e0 + e1);
    gbuf[257] = e1 / (e0 + e1);
  }
}

__global__ __launch_bounds__(256) void k_xf(const float* __restrict__ xl,
                                            const float* __restrict__ xg,
                                            const float* __restrict__ gbuf,
                                            float* __restrict__ xf,
                                            unsigned short* __restrict__ xfb) {
  const float alpha = gbuf[256], beta = gbuf[257];
  const size_t i = ((size_t)blockIdx.x * 256 + threadIdx.x) * 4;
  float4 a = *(const float4*)(xg + i);
  float4 b = *(const float4*)(xl + i);
  float4 r;
  r.x = alpha * a.x + beta * b.x;
  r.y = alpha * a.y + beta * b.y;
  r.z = alpha * a.z + beta * b.z;
  r.w = alpha * a.w + beta * b.w;
  *(float4*)(xf + i) = r;
  unsigned lo = (unsigned)f2bf(r.x) | ((unsigned)f2bf(r.y) << 16);
  unsigned hi = (unsigned)f2bf(r.z) | ((unsigned)f2bf(r.w) << 16);
  *(uint2*)(xfb + i) = make_uint2(lo, hi);
}

// ===========================================================================
extern "C" void kernel_launch(void* const* d_in, const int* in_sizes, int n_in,
                              void* d_out, int out_size, void* d_ws, size_t ws_size,
                              hipStream_t stream) {
  const float* x   = (const float*)d_in[0];
  const float* fw  = (const float*)d_in[2];
  const float* fb  = (const float*)d_in[3];
  const float* fg  = (const float*)d_in[4];
  const float* fbb = (const float*)d_in[5];
  const float* wq  = (const float*)d_in[6];
  const float* wk  = (const float*)d_in[7];
  const float* wv  = (const float*)d_in[8];
  const float* bq  = (const float*)d_in[9];
  const float* bk  = (const float*)d_in[10];
  const float* bv  = (const float*)d_in[11];
  const float* wo  = (const float*)d_in[12];
  const float* bo  = (const float*)d_in[13];
  const float* gw  = (const float*)d_in[14];
  const float* gb  = (const float*)d_in[15];
  const float* w1  = (const float*)d_in[16];
  const float* b1  = (const float*)d_in[17];
  const float* w2  = (const float*)d_in[18];
  const float* b2  = (const float*)d_in[19];
  const float* n1g = (const float*)d_in[20];
  const float* n1b = (const float*)d_in[21];
  const float* n2g = (const float*)d_in[22];
  const float* n2b = (const float*)d_in[23];
  const float* n3g = (const float*)d_in[24];
  const float* n3b = (const float*)d_in[25];
  float* out = (float*)d_out;

  // ---- workspace carve (bytes) ----
  char* base = (char*)d_ws;
  size_t off = 0;
  auto carve = [&](size_t bytes) { char* p = base + off; off += (bytes + 255) & ~(size_t)255; return p; };
  float* p0 = (float*)carve(961 * 256 * 4);
  float* p1 = (float*)carve(225 * 256 * 4);
  float* p2 = (float*)carve(49 * 256 * 4);
  unsigned short* fwT = (unsigned short*)carve(256 * 768 * 2);
  unsigned short* wqT = (unsigned short*)carve(256 * 256 * 2);
  unsigned short* wkT = (unsigned short*)carve(256 * 256 * 2);
  unsigned short* wvT = (unsigned short*)carve(256 * 256 * 2);
  unsigned short* woT = (unsigned short*)carve(256 * 256 * 2);
  unsigned short* w1T = (unsigned short*)carve(1024 * 256 * 2);
  unsigned short* w2T = (unsigned short*)carve(256 * 1024 * 2);
  char* R = carve(8388608);                      // catb(6.3MB) -> xg(4MB) -> hbuf(8MB)
  unsigned short* catb = (unsigned short*)R;
  float* xg            = (float*)R;
  unsigned short* hbuf = (unsigned short*)R;
  unsigned short* qb = (unsigned short*)carve((size_t)S * D * 2);
  unsigned short* kb = (unsigned short*)carve((size_t)S * D * 2);
  unsigned short* vb = (unsigned short*)carve((size_t)S * D * 2);
  float* xf            = (float*)qb;             // qb+kb region, dead after flash
  unsigned short* xfb  = vb;                     // vb region, dead after flash
  float* t1  = (float*)carve((size_t)S * D * 4); // fuse out; later ffo
  float* ffo = t1;
  unsigned short* t1b = (unsigned short*)carve((size_t)S * D * 2);
  float* xl  = (float*)carve((size_t)S * D * 4);
  unsigned short* xlb = (unsigned short*)carve((size_t)S * D * 2);
  float* gbuf = (float*)carve(264 * 4);

  hipMemsetAsync(gbuf, 0, 264 * sizeof(float), stream);

  // weight pre-transpose (bf16 WT[N][K])
  k_wt<<<dim3(960), dim3(256), 0, stream>>>(fw, wq, wk, wv, wo, w1, w2,
                                            fwT, wqT, wkT, wvT, woT, w1T, w2T);
  // local multi-scale window attention -> pooled per window (MFMA)
  k_local_s<4, 64><<<dim3(961), dim3(64), 0, stream>>>(x, p0, 31);
  k_local_s<8, 256><<<dim3(225), dim3(256), 0, stream>>>(x, p1, 15);
  k_local16<<<dim3(49), dim3(256), 0, stream>>>(x, p2, 7);
  // scatter/avg -> catb[S][768] bf16
  k_combine<<<dim3(S), dim3(256), 0, stream>>>(p0, p1, p2, catb);
  // fuse GEMM + LNs
  k_gemm_m<768, 0, 0><<<dim3(S / 32, 8), dim3(64), 0, stream>>>(catb, fwT, fb, t1, 256);
  k_ln<<<dim3(S), dim3(256), 0, stream>>>(t1, nullptr, t1, nullptr, fg, fbb);
  k_ln<<<dim3(S), dim3(256), 0, stream>>>(xl, xlb, x, t1, n1g, n1b);
  // global MHA (bf16 q/k/v)
  k_gemm_m<256, 1, 0><<<dim3(S / 32, 8), dim3(64), 0, stream>>>(xlb, wqT, bq, qb, 256);
  k_gemm_m<256, 1, 0><<<dim3(S / 32, 8), dim3(64), 0, stream>>>(xlb, wkT, bk, kb, 256);
  k_gemm_m<256, 1, 0><<<dim3(S / 32, 8), dim3(64), 0, stream>>>(xlb, wvT, bv, vb, 256);
  k_flash_mfma<<<dim3(S / 64, NH), dim3(256), 0, stream>>>(qb, kb, vb, t1b);
  k_gemm_m<256, 0, 0><<<dim3(S / 32, 8), dim3(64), 0, stream>>>(t1b, woT, bo, xf, 256);
  k_ln<<<dim3(S), dim3(256), 0, stream>>>(xg, nullptr, xl, xf, n2g, n2b);
  // gate
  k_colmean<<<dim3(64), dim3(256), 0, stream>>>(xl, xg, gbuf);
  k_gate<<<dim3(1), dim3(256), 0, stream>>>(gbuf, gw, gb);
  k_xf<<<dim3(S * D / 1024), dim3(256), 0, stream>>>(xl, xg, gbuf, xf, xfb);
  // FFN + final LN
  k_gemm_m<256, 1, 1><<<dim3(S / 32, 32), dim3(64), 0, stream>>>(xfb, w1T, b1, hbuf, 1024);
  k_gemm_m<1024, 0, 0><<<dim3(S / 32, 8), dim3(64), 0, stream>>>(hbuf, w2T, b2, ffo, 256);
  k_ln<<<dim3(S), dim3(256), 0, stream>>>(out, nullptr, xf, ffo, n3g, n3b);
}

// Round 7
// 253.096 us; speedup vs baseline: 5.9019x; 1.0484x over previous
//
#include <hip/hip_runtime.h>
#include <cstdint>
#include <cstddef>

// ============================================================================
// HierarchicalTransformerBlock: B=1, S=4096 (64x64 grid), D=256, NH=8, dh=32,
// DFF=1024, local windows w = 4,8,16 (stride w/2).
// Round 7: flash K/V register double-buffer (hide HBM latency); QKV projection
// fused to one dispatch; fuse-LN pair fused. Rest unchanged from round 6.
// ============================================================================

#define DEVFN __device__ __forceinline__

constexpr int S    = 4096;
constexpr int D    = 256;
constexpr int GRID = 64;
constexpr int NH   = 8;
constexpr int DH   = 32;

typedef __attribute__((ext_vector_type(8))) short bf16x8;
typedef __attribute__((ext_vector_type(4))) float f32x4;
typedef __attribute__((ext_vector_type(16))) float f32x16;
typedef __attribute__((ext_vector_type(2))) unsigned int u32x2;

DEVFN float asf(unsigned u) { return __uint_as_float(u); }

DEVFN unsigned short f2bf(float f) {  // round-to-nearest-even bf16
  unsigned u = __float_as_uint(f);
  u += 0x7fffu + ((u >> 16) & 1u);
  return (unsigned short)(u >> 16);
}
DEVFN float bf2f(unsigned short s) { return __uint_as_float(((unsigned)s) << 16); }

DEVFN bf16x8 pack8(float4 a, float4 b) {
  bf16x8 kv;
  kv[0] = (short)f2bf(a.x); kv[1] = (short)f2bf(a.y);
  kv[2] = (short)f2bf(a.z); kv[3] = (short)f2bf(a.w);
  kv[4] = (short)f2bf(b.x); kv[5] = (short)f2bf(b.y);
  kv[6] = (short)f2bf(b.z); kv[7] = (short)f2bf(b.w);
  return kv;
}

// ---------------------------------------------------------------------------
// Weight pre-transpose: fp32 W[K][N] -> bf16 WT[N][K]; 32x32 tiles via LDS.
// wq/wk/wv land contiguously (wqkvT) so QKV runs as one GEMM dispatch.
// ---------------------------------------------------------------------------
__global__ __launch_bounds__(256) void k_wt(
    const float* fw, const float* wq, const float* wk, const float* wv,
    const float* wo, const float* w1, const float* w2,
    unsigned short* fwT, unsigned short* wqT, unsigned short* wkT,
    unsigned short* wvT, unsigned short* woT, unsigned short* w1T,
    unsigned short* w2T) {
  __shared__ unsigned short tile[32][36];
  const int bid = blockIdx.x;
  const float* src; unsigned short* dst; int K, N, t;
  if (bid < 192)      { src = fw; dst = fwT; K = 768;  N = 256;  t = bid; }
  else if (bid < 256) { src = wq; dst = wqT; K = 256;  N = 256;  t = bid - 192; }
  else if (bid < 320) { src = wk; dst = wkT; K = 256;  N = 256;  t = bid - 256; }
  else if (bid < 384) { src = wv; dst = wvT; K = 256;  N = 256;  t = bid - 320; }
  else if (bid < 448) { src = wo; dst = woT; K = 256;  N = 256;  t = bid - 384; }
  else if (bid < 704) { src = w1; dst = w1T; K = 256;  N = 1024; t = bid - 448; }
  else                { src = w2; dst = w2T; K = 1024; N = 256;  t = bid - 704; }
  const int nkt = K >> 5;
  const int k0 = (t % nkt) * 32, n0 = (t / nkt) * 32;
  const int i = threadIdx.x >> 3, j4 = threadIdx.x & 7;
  const float4 v = *(const float4*)(src + (size_t)(k0 + i) * N + n0 + j4 * 4);
  unsigned lo = (unsigned)f2bf(v.x) | ((unsigned)f2bf(v.y) << 16);
  unsigned hi = (unsigned)f2bf(v.z) | ((unsigned)f2bf(v.w) << 16);
  *(uint2*)&tile[i][j4 * 4] = make_uint2(lo, hi);
  __syncthreads();
  unsigned o0 = tile[j4 * 4 + 0][i], o1 = tile[j4 * 4 + 1][i];
  unsigned o2 = tile[j4 * 4 + 2][i], o3 = tile[j4 * 4 + 3][i];
  *(uint2*)(dst + (size_t)(n0 + i) * K + k0 + j4 * 4) =
      make_uint2(o0 | (o1 << 16), o2 | (o3 << 16));
}

// ---------------------------------------------------------------------------
// MFMA GEMM: C[M][N] = Ab[M][K](bf16) @ WT[N][K]^T(bf16) + bias.
// ---------------------------------------------------------------------------
template <int K, int OUTBF, int ACT>
__global__ __launch_bounds__(64) void k_gemm_m(const unsigned short* __restrict__ Ab,
                                               const unsigned short* __restrict__ WT,
                                               const float* __restrict__ bias,
                                               void* __restrict__ Cout, int N) {
  const int lane = threadIdx.x;
  const int lc = lane & 31, hi = lane >> 5;
  const int m0 = blockIdx.x * 32, n0 = blockIdx.y * 32;
  const unsigned short* ap = Ab + (size_t)(m0 + lc) * K + hi * 8;
  const unsigned short* bp = WT + (size_t)(n0 + lc) * K + hi * 8;
  f32x16 acc = {0.f,0.f,0.f,0.f,0.f,0.f,0.f,0.f,0.f,0.f,0.f,0.f,0.f,0.f,0.f,0.f};
#pragma unroll 4
  for (int k0 = 0; k0 < K; k0 += 16) {
    bf16x8 a = *(const bf16x8*)(ap + k0);
    bf16x8 b = *(const bf16x8*)(bp + k0);
    acc = __builtin_amdgcn_mfma_f32_32x32x16_bf16(a, b, acc, 0, 0, 0);
  }
  const float bv = bias[n0 + lc];
#pragma unroll
  for (int r = 0; r < 16; ++r) {
    const int row = (r & 3) + 8 * (r >> 2) + 4 * hi;
    float v = acc[r] + bv;
    if (ACT == 1) v = 0.5f * v * (1.f + erff(v * 0.70710678118654752f));
    if (OUTBF) ((unsigned short*)Cout)[(size_t)(m0 + row) * N + n0 + lc] = f2bf(v);
    else       ((float*)Cout)[(size_t)(m0 + row) * N + n0 + lc] = v;
  }
}

// QKV: grid (S/32, 24); sel = by>>3 picks {wq,bq,qb}/{wk,bk,kb}/{wv,bv,vb}.
__global__ __launch_bounds__(64) void k_gemm_qkv(const unsigned short* __restrict__ Ab,
                                                 const unsigned short* __restrict__ wqkvT,
                                                 const float* __restrict__ bq,
                                                 const float* __restrict__ bk,
                                                 const float* __restrict__ bv,
                                                 unsigned short* __restrict__ qb,
                                                 unsigned short* __restrict__ kb,
                                                 unsigned short* __restrict__ vb) {
  const int lane = threadIdx.x;
  const int lc = lane & 31, hi = lane >> 5;
  const int m0 = blockIdx.x * 32;
  const int sel = blockIdx.y >> 3, n0 = (blockIdx.y & 7) * 32;
  const unsigned short* WT = wqkvT + (size_t)sel * 256 * 256;
  const float* bias = sel == 0 ? bq : sel == 1 ? bk : bv;
  unsigned short* out = sel == 0 ? qb : sel == 1 ? kb : vb;
  const unsigned short* ap = Ab + (size_t)(m0 + lc) * 256 + hi * 8;
  const unsigned short* bp = WT + (size_t)(n0 + lc) * 256 + hi * 8;
  f32x16 acc = {0.f,0.f,0.f,0.f,0.f,0.f,0.f,0.f,0.f,0.f,0.f,0.f,0.f,0.f,0.f,0.f};
#pragma unroll 4
  for (int k0 = 0; k0 < 256; k0 += 16) {
    bf16x8 a = *(const bf16x8*)(ap + k0);
    bf16x8 b = *(const bf16x8*)(bp + k0);
    acc = __builtin_amdgcn_mfma_f32_32x32x16_bf16(a, b, acc, 0, 0, 0);
  }
  const float bvv = bias[n0 + lc];
#pragma unroll
  for (int r = 0; r < 16; ++r) {
    const int row = (r & 3) + 8 * (r >> 2) + 4 * hi;
    out[(size_t)(m0 + row) * 256 + n0 + lc] = f2bf(acc[r] + bvv);
  }
}

// ---------------------------------------------------------------------------
// Local windowed attention, w=4/8 (16x16x32 MFMA), one window per block.
// ---------------------------------------------------------------------------
template <int W, int THREADS>
__global__ __launch_bounds__(THREADS) void k_local_s(const float* __restrict__ x,
                                                     float* __restrict__ pooled, int nS) {
  constexpr int NT  = W * W;
  constexpr int NCT = NT / 16;
  constexpr int LDE = 264;
  __shared__ unsigned short win[NT][LDE];
  __shared__ float a[NT];
  const int tid = threadIdx.x;
  const int wave = tid >> 6, lane = tid & 63;
  const int lr = lane & 15, lg = lane >> 4;
  const int l = blockIdx.x;
  const int row0 = (l / nS) * (W / 2), col0 = (l % nS) * (W / 2);

  for (int e8 = tid; e8 < NT * 32; e8 += THREADS) {
    const int t = e8 >> 5, c8 = (e8 & 31) * 8;
    const float* src = x + ((size_t)((row0 + t / W) * GRID + col0 + (t % W))) * D + c8;
    *(bf16x8*)&win[t][c8] = pack8(*(const float4*)src, *(const float4*)(src + 4));
  }
  if (tid < NT) a[tid] = 0.f;
  __syncthreads();

  bf16x8 af[8];
#pragma unroll
  for (int k2 = 0; k2 < 8; ++k2)
    af[k2] = *(const bf16x8*)&win[wave * 16 + lr][k2 * 32 + lg * 8];

  float m[4], Z[4], Zi[4];
#pragma unroll
  for (int r = 0; r < 4; ++r) { m[r] = -INFINITY; Z[r] = 0.f; }

  for (int ct = 0; ct < NCT; ++ct) {
    f32x4 Ca = {0.f, 0.f, 0.f, 0.f}, Cb = {0.f, 0.f, 0.f, 0.f};
#pragma unroll
    for (int k2 = 0; k2 < 8; k2 += 2) {
      bf16x8 b0 = *(const bf16x8*)&win[ct * 16 + lr][k2 * 32 + lg * 8];
      bf16x8 b1 = *(const bf16x8*)&win[ct * 16 + lr][(k2 + 1) * 32 + lg * 8];
      Ca = __builtin_amdgcn_mfma_f32_16x16x32_bf16(af[k2], b0, Ca, 0, 0, 0);
      Cb = __builtin_amdgcn_mfma_f32_16x16x32_bf16(af[k2 + 1], b1, Cb, 0, 0, 0);
    }
#pragma unroll
    for (int r = 0; r < 4; ++r) {
      const float sv = (Ca[r] + Cb[r]) * 0.0625f;
      const float nm = fmaxf(m[r], sv);
      Z[r] = Z[r] * __expf(m[r] - nm) + __expf(sv - nm);
      m[r] = nm;
    }
  }
#pragma unroll
  for (int r = 0; r < 4; ++r) {
#pragma unroll
    for (int msk = 1; msk <= 8; msk <<= 1) {
      const float om = __shfl_xor(m[r], msk), oz = __shfl_xor(Z[r], msk);
      const float nm = fmaxf(m[r], om);
      Z[r] = Z[r] * __expf(m[r] - nm) + oz * __expf(om - nm);
      m[r] = nm;
    }
    Zi[r] = 1.f / Z[r];
  }

  for (int ct = 0; ct < NCT; ++ct) {
    f32x4 Ca = {0.f, 0.f, 0.f, 0.f}, Cb = {0.f, 0.f, 0.f, 0.f};
#pragma unroll
    for (int k2 = 0; k2 < 8; k2 += 2) {
      bf16x8 b0 = *(const bf16x8*)&win[ct * 16 + lr][k2 * 32 + lg * 8];
      bf16x8 b1 = *(const bf16x8*)&win[ct * 16 + lr][(k2 + 1) * 32 + lg * 8];
      Ca = __builtin_amdgcn_mfma_f32_16x16x32_bf16(af[k2], b0, Ca, 0, 0, 0);
      Cb = __builtin_amdgcn_mfma_f32_16x16x32_bf16(af[k2 + 1], b1, Cb, 0, 0, 0);
    }
    float cs = 0.f;
#pragma unroll
    for (int r = 0; r < 4; ++r)
      cs += __expf((Ca[r] + Cb[r]) * 0.0625f - m[r]) * Zi[r];
    cs += __shfl_xor(cs, 16);
    cs += __shfl_xor(cs, 32);
    if (lg == 0) atomicAdd(&a[ct * 16 + lr], cs);
  }
  __syncthreads();

  for (int d = tid; d < D; d += THREADS) {
    float acc = 0.f;
#pragma unroll 8
    for (int k = 0; k < NT; ++k) acc += a[k] * bf2f(win[k][d]);
    pooled[(size_t)l * D + d] = acc * (1.f / NT);
  }
}

// ---------------------------------------------------------------------------
// Local windowed attention, w=16 (NT=256), 32x32x16 MFMA, one window/block.
// ---------------------------------------------------------------------------
__global__ __launch_bounds__(256, 1) void k_local16(const float* __restrict__ x,
                                                    float* __restrict__ pooled, int nS) {
  constexpr int LDE = 264;
  __shared__ unsigned short win[256][LDE];
  __shared__ float a[256];
  const int tid = threadIdx.x;
  const int wave = tid >> 6, lane = tid & 63;
  const int lc = lane & 31, hi = lane >> 5;
  const int l = blockIdx.x;
  const int row0 = (l / nS) * 8, col0 = (l % nS) * 8;

  for (int e8 = tid; e8 < 256 * 32; e8 += 256) {
    const int t = e8 >> 5, c8 = (e8 & 31) * 8;
    const float* src = x + ((size_t)((row0 + (t >> 4)) * GRID + col0 + (t & 15))) * D + c8;
    *(bf16x8*)&win[t][c8] = pack8(*(const float4*)src, *(const float4*)(src + 4));
  }
  a[tid] = 0.f;
  __syncthreads();

  float m[2][16], Z[2][16], Zi[2][16];
#pragma unroll
  for (int s = 0; s < 2; ++s)
#pragma unroll
    for (int r = 0; r < 16; ++r) { m[s][r] = -INFINITY; Z[s][r] = 0.f; }

#pragma unroll
  for (int s = 0; s < 2; ++s) {
    const int R0 = (wave * 2 + s) * 32;
    bf16x8 af[16];
#pragma unroll
    for (int k2 = 0; k2 < 16; ++k2)
      af[k2] = *(const bf16x8*)&win[R0 + lc][k2 * 16 + hi * 8];
    for (int ct = 0; ct < 8; ++ct) {
      f32x16 Ca = {0.f,0.f,0.f,0.f,0.f,0.f,0.f,0.f,0.f,0.f,0.f,0.f,0.f,0.f,0.f,0.f};
      f32x16 Cb = Ca;
#pragma unroll
      for (int k2 = 0; k2 < 16; k2 += 2) {
        bf16x8 b0 = *(const bf16x8*)&win[ct * 32 + lc][k2 * 16 + hi * 8];
        bf16x8 b1 = *(const bf16x8*)&win[ct * 32 + lc][(k2 + 1) * 16 + hi * 8];
        Ca = __builtin_amdgcn_mfma_f32_32x32x16_bf16(af[k2], b0, Ca, 0, 0, 0);
        Cb = __builtin_amdgcn_mfma_f32_32x32x16_bf16(af[k2 + 1], b1, Cb, 0, 0, 0);
      }
#pragma unroll
      for (int r = 0; r < 16; ++r) {
        const float sv = (Ca[r] + Cb[r]) * 0.0625f;
        const float nm = fmaxf(m[s][r], sv);
        Z[s][r] = Z[s][r] * __expf(m[s][r] - nm) + __expf(sv - nm);
        m[s][r] = nm;
      }
    }
#pragma unroll
    for (int r = 0; r < 16; ++r) {
#pragma unroll
      for (int msk = 1; msk <= 16; msk <<= 1) {
        const float om = __shfl_xor(m[s][r], msk), oz = __shfl_xor(Z[s][r], msk);
        const float nm = fmaxf(m[s][r], om);
        Z[s][r] = Z[s][r] * __expf(m[s][r] - nm) + oz * __expf(om - nm);
        m[s][r] = nm;
      }
      Zi[s][r] = 1.f / Z[s][r];
    }
  }

#pragma unroll
  for (int s = 0; s < 2; ++s) {
    const int R0 = (wave * 2 + s) * 32;
    bf16x8 af[16];
#pragma unroll
    for (int k2 = 0; k2 < 16; ++k2)
      af[k2] = *(const bf16x8*)&win[R0 + lc][k2 * 16 + hi * 8];
    for (int ct = 0; ct < 8; ++ct) {
      f32x16 Ca = {0.f,0.f,0.f,0.f,0.f,0.f,0.f,0.f,0.f,0.f,0.f,0.f,0.f,0.f,0.f,0.f};
      f32x16 Cb = Ca;
#pragma unroll
      for (int k2 = 0; k2 < 16; k2 += 2) {
        bf16x8 b0 = *(const bf16x8*)&win[ct * 32 + lc][k2 * 16 + hi * 8];
        bf16x8 b1 = *(const bf16x8*)&win[ct * 32 + lc][(k2 + 1) * 16 + hi * 8];
        Ca = __builtin_amdgcn_mfma_f32_32x32x16_bf16(af[k2], b0, Ca, 0, 0, 0);
        Cb = __builtin_amdgcn_mfma_f32_32x32x16_bf16(af[k2 + 1], b1, Cb, 0, 0, 0);
      }
      float cs = 0.f;
#pragma unroll
      for (int r = 0; r < 16; ++r)
        cs += __expf((Ca[r] + Cb[r]) * 0.0625f - m[s][r]) * Zi[s][r];
      cs += __shfl_xor(cs, 32);
      if (hi == 0) atomicAdd(&a[ct * 32 + lc], cs);
    }
  }
  __syncthreads();

  {
    const int d = tid;
    float acc = 0.f;
#pragma unroll 8
    for (int k = 0; k < 256; ++k) acc += a[k] * bf2f(win[k][d]);
    pooled[(size_t)l * D + d] = acc * (1.f / 256.f);
  }
}

// ---------------------------------------------------------------------------
// Overlap-average scatter of pooled windows -> catb[t][768] (bf16)
// ---------------------------------------------------------------------------
DEVFN float gatherp(const float* __restrict__ pooled, int r, int c, int W, int s, int nS, int d) {
  int amin = max(0, (r - W + s) / s), amax = min(nS - 1, r / s);
  int bmin = max(0, (c - W + s) / s), bmax = min(nS - 1, c / s);
  float acc = 0.f;
  int cnt = 0;
  for (int a = amin; a <= amax; ++a)
    for (int b = bmin; b <= bmax; ++b) { acc += pooled[(size_t)(a * nS + b) * D + d]; ++cnt; }
  return acc / (float)cnt;
}

__global__ void k_combine(const float* __restrict__ p0, const float* __restrict__ p1,
                          const float* __restrict__ p2, unsigned short* __restrict__ catb) {
  const int t = blockIdx.x, d = threadIdx.x;
  const int r = t >> 6, c = t & 63;
  unsigned short* o = catb + (size_t)t * 768;
  o[d]       = f2bf(gatherp(p0, r, c, 4, 2, 31, d));
  o[256 + d] = f2bf(gatherp(p1, r, c, 8, 4, 15, d));
  o[512 + d] = f2bf(gatherp(p2, r, c, 16, 8, 7, d));
}

// ---------------------------------------------------------------------------
// Block-wide sum of (a, b) over 256 threads
// ---------------------------------------------------------------------------
DEVFN float2 block_sum2(float a, float b) {
  __shared__ float sb[8];
#pragma unroll
  for (int m = 32; m; m >>= 1) { a += __shfl_xor(a, m); b += __shfl_xor(b, m); }
  const int w = threadIdx.x >> 6;
  __syncthreads();
  if ((threadIdx.x & 63) == 0) { sb[w] = a; sb[4 + w] = b; }
  __syncthreads();
  return make_float2(sb[0] + sb[1] + sb[2] + sb[3], sb[4] + sb[5] + sb[6] + sb[7]);
}

// out = LN(a (+ b)); optional bf16 dual write. In-place safe (out==a).
__global__ __launch_bounds__(256) void k_ln(float* __restrict__ out, unsigned short* __restrict__ outb,
                                            const float* __restrict__ a, const float* __restrict__ b,
                                            const float* __restrict__ g, const float* __restrict__ be) {
  const size_t i = (size_t)blockIdx.x * D + threadIdx.x;
  float v = a[i] + (b ? b[i] : 0.f);
  float2 s = block_sum2(v, v * v);
  float mean = s.x * (1.f / D);
  float var = s.y * (1.f / D) - mean * mean;
  const float r = (v - mean) * rsqrtf(var + 1e-5f) * g[threadIdx.x] + be[threadIdx.x];
  out[i] = r;
  if (outb) outb[i] = f2bf(r);
}

// xl = LN2(x + LN1(t1)); writes fp32 + bf16 (fuses the two post-fuse LNs)
__global__ __launch_bounds__(256) void k_ln_fuse(const float* __restrict__ t1,
                                                 const float* __restrict__ x,
                                                 float* __restrict__ xl,
                                                 unsigned short* __restrict__ xlb,
                                                 const float* __restrict__ fg,
                                                 const float* __restrict__ fbb,
                                                 const float* __restrict__ n1g,
                                                 const float* __restrict__ n1b) {
  const size_t i = (size_t)blockIdx.x * D + threadIdx.x;
  const float v1 = t1[i];
  float2 s1 = block_sum2(v1, v1 * v1);
  const float mean1 = s1.x * (1.f / D);
  const float var1 = s1.y * (1.f / D) - mean1 * mean1;
  const float r1 = (v1 - mean1) * rsqrtf(var1 + 1e-5f) * fg[threadIdx.x] + fbb[threadIdx.x];
  const float v2 = x[i] + r1;
  float2 s2 = block_sum2(v2, v2 * v2);
  const float mean2 = s2.x * (1.f / D);
  const float var2 = s2.y * (1.f / D) - mean2 * mean2;
  const float r2 = (v2 - mean2) * rsqrtf(var2 + 1e-5f) * n1g[threadIdx.x] + n1b[threadIdx.x];
  xl[i] = r2;
  xlb[i] = f2bf(r2);
}

// ---------------------------------------------------------------------------
// MFMA flash attention, swapped QK^T, in-register P, tr-read V,
// K/V register double-buffer (prefetch tile kt+1 during compute of kt).
// ---------------------------------------------------------------------------
__global__ __launch_bounds__(256) void k_flash_mfma(const unsigned short* __restrict__ Qg,
                                                    const unsigned short* __restrict__ Kg,
                                                    const unsigned short* __restrict__ Vg,
                                                    unsigned short* __restrict__ Og) {
  const int h = blockIdx.y;
  const int tid = threadIdx.x;
  const int wave = tid >> 6, lane = tid & 63;
  const int lr = lane & 15, lg = lane >> 4;

  __shared__ unsigned short Kf[64][40];   // row-major keys, pad 32->40
  __shared__ unsigned short VS[2048];     // [dgrp][key>>2][key&3][dh&15]

  const int q0 = blockIdx.x * 64 + wave * 16;

  // Q fragment (B-operand of swapped QK), pre-scaled by 1/sqrt(dh)
  bf16x8 qfrag;
  {
    const bf16x8 qraw = *(const bf16x8*)(Qg + (size_t)(q0 + lr) * D + h * DH + lg * 8);
    const float scale = 0.17677669529663687f;
#pragma unroll
    for (int j = 0; j < 8; ++j)
      qfrag[j] = (short)f2bf(bf2f((unsigned short)qraw[j]) * scale);
  }

  f32x4 o0 = {0.f, 0.f, 0.f, 0.f}, o1 = {0.f, 0.f, 0.f, 0.f};
  float mrow = -INFINITY, lrow = 0.f;

  const unsigned vsbase =
      (unsigned)(unsigned long long)(const void*)&VS[0] + (unsigned)(lg * 128 + lr * 2);

  // per-lane staging geometry
  const int key = tid >> 2, c8 = (tid & 3) * 8;
  const int vidx = (c8 >> 4) * 1024 + (key >> 2) * 64 + (key & 3) * 16 + (c8 & 15);
  const unsigned short* kp = Kg + (size_t)key * D + h * DH + c8;
  const unsigned short* vp = Vg + (size_t)key * D + h * DH + c8;
  constexpr int KSTEP = 64 * D;  // elements per 64-key tile

  // prologue: prefetch tile 0
  bf16x8 kreg = *(const bf16x8*)kp;
  bf16x8 vreg = *(const bf16x8*)vp;

  for (int kt = 0; kt < S / 64; ++kt) {
    // commit staged registers to LDS (vmcnt drain happens here)
    *(bf16x8*)&Kf[key][c8] = kreg;
    *(bf16x8*)&VS[vidx] = vreg;
    __syncthreads();

    // prefetch next tile (wraps on last iter; harmless)
    const int ktn = (kt + 1) & (S / 64 - 1);
    kreg = *(const bf16x8*)(kp + (size_t)ktn * KSTEP);
    vreg = *(const bf16x8*)(vp + (size_t)ktn * KSTEP);

    // swapped QK^T: s[k16][r] = S[q=lr][key = k16*16 + lg*4 + r]
    f32x4 s[4];
#pragma unroll
    for (int k16 = 0; k16 < 4; ++k16) {
      bf16x8 ka = *(const bf16x8*)&Kf[k16 * 16 + lr][lg * 8];
      f32x4 z = {0.f, 0.f, 0.f, 0.f};
      s[k16] = __builtin_amdgcn_mfma_f32_16x16x32_bf16(ka, qfrag, z, 0, 0, 0);
    }

    // issue V tr-reads early (latency hidden under softmax VALU)
    u32x2 tv000, tv001, tv010, tv011, tv100, tv101, tv110, tv111;  // [kt2][t][dg]
    asm volatile("ds_read_b64_tr_b16 %0, %1 offset:0"    : "=v"(tv000) : "v"(vsbase));
    asm volatile("ds_read_b64_tr_b16 %0, %1 offset:2048" : "=v"(tv001) : "v"(vsbase));
    asm volatile("ds_read_b64_tr_b16 %0, %1 offset:512"  : "=v"(tv010) : "v"(vsbase));
    asm volatile("ds_read_b64_tr_b16 %0, %1 offset:2560" : "=v"(tv011) : "v"(vsbase));
    asm volatile("ds_read_b64_tr_b16 %0, %1 offset:1024" : "=v"(tv100) : "v"(vsbase));
    asm volatile("ds_read_b64_tr_b16 %0, %1 offset:3072" : "=v"(tv101) : "v"(vsbase));
    asm volatile("ds_read_b64_tr_b16 %0, %1 offset:1536" : "=v"(tv110) : "v"(vsbase));
    asm volatile("ds_read_b64_tr_b16 %0, %1 offset:3584" : "=v"(tv111) : "v"(vsbase));

    // online softmax for q=lr (lane-local slices; merge across lg lanes)
    float tm = s[0][0];
#pragma unroll
    for (int k16 = 0; k16 < 4; ++k16)
#pragma unroll
      for (int r = 0; r < 4; ++r) tm = fmaxf(tm, s[k16][r]);
    tm = fmaxf(tm, __shfl_xor(tm, 16));
    tm = fmaxf(tm, __shfl_xor(tm, 32));
    const float nm = fmaxf(mrow, tm);
    const float cfac = __expf(mrow - nm);
    mrow = nm;
    float ls = 0.f;
#pragma unroll
    for (int k16 = 0; k16 < 4; ++k16)
#pragma unroll
      for (int r = 0; r < 4; ++r) { s[k16][r] = __expf(s[k16][r] - nm); ls += s[k16][r]; }
    ls += __shfl_xor(ls, 16);
    ls += __shfl_xor(ls, 32);
    lrow = lrow * cfac + ls;

    // rescale O by this lane's OUTPUT q-rows (q = lg*4 + r)
#pragma unroll
    for (int r = 0; r < 4; ++r) {
      const float cr = __shfl(cfac, lg * 4 + r);
      o0[r] *= cr; o1[r] *= cr;
    }

    // drain tr-reads; pin ordering (rule #18)
    asm volatile("s_waitcnt lgkmcnt(0)" ::: "memory");
    __builtin_amdgcn_sched_barrier(0);

    // PV: a = lane-local P (permuted k), b = tr-read V fragments
    union VB { u32x2 u2[2]; bf16x8 b; };
#pragma unroll
    for (int kt2 = 0; kt2 < 2; ++kt2) {
      bf16x8 pa;
#pragma unroll
      for (int j = 0; j < 4; ++j) {
        pa[j]     = (short)f2bf(s[2 * kt2][j]);
        pa[4 + j] = (short)f2bf(s[2 * kt2 + 1][j]);
      }
      VB v0, v1;
      if (kt2 == 0) { v0.u2[0] = tv000; v0.u2[1] = tv010; v1.u2[0] = tv001; v1.u2[1] = tv011; }
      else          { v0.u2[0] = tv100; v0.u2[1] = tv110; v1.u2[0] = tv101; v1.u2[1] = tv111; }
      o0 = __builtin_amdgcn_mfma_f32_16x16x32_bf16(pa, v0.b, o0, 0, 0, 0);
      o1 = __builtin_amdgcn_mfma_f32_16x16x32_bf16(pa, v1.b, o1, 0, 0, 0);
    }
    __syncthreads();
  }

  const float linv = 1.f / lrow;
#pragma unroll
  for (int r = 0; r < 4; ++r) {
    const float inv = __shfl(linv, lg * 4 + r);
    unsigned short* op = Og + (size_t)(q0 + lg * 4 + r) * D + h * DH + lr;
    op[0]  = f2bf(o0[r] * inv);
    op[16] = f2bf(o1[r] * inv);
  }
}

// ---------------------------------------------------------------------------
// Gate helpers
// ---------------------------------------------------------------------------
__global__ __launch_bounds__(256) void k_colmean(const float* __restrict__ xl,
                                                 const float* __restrict__ xg,
                                                 float* __restrict__ gbuf) {
  const int j = threadIdx.x;
  const int t0 = blockIdx.x * 64;
  float s = 0.f;
  for (int t = 0; t < 64; ++t) {
    size_t i = (size_t)(t0 + t) * D + j;
    s += xl[i] + xg[i];
  }
  atomicAdd(&gbuf[j], s * 0.5f);
}

__global__ __launch_bounds__(256) void k_gate(float* __restrict__ gbuf,
                                              const float* __restrict__ gw,
                                              const float* __restrict__ gb) {
  const int j = threadIdx.x;
  const float gm = gbuf[j] * (1.f / (float)S);
  float2 s = block_sum2(gm * gw[2 * j], gm * gw[2 * j + 1]);
  if (j == 0) {
    float g0 = s.x + gb[0], g1 = s.y + gb[1];
    float mx = fmaxf(g0, g1);
    float e0 = __expf(g0 - mx), e1 = __expf(g1 - mx);
    gbuf[256] = e0 / (e0 + e1);
    gbuf[257] = e1 / (e0 + e1);
  }
}

__global__ __launch_bounds__(256) void k_xf(const float* __restrict__ xl,
                                            const float* __restrict__ xg,
                                            const float* __restrict__ gbuf,
                                            float* __restrict__ xf,
                                            unsigned short* __restrict__ xfb) {
  const float alpha = gbuf[256], beta = gbuf[257];
  const size_t i = ((size_t)blockIdx.x * 256 + threadIdx.x) * 4;
  float4 a = *(const float4*)(xg + i);
  float4 b = *(const float4*)(xl + i);
  float4 r;
  r.x = alpha * a.x + beta * b.x;
  r.y = alpha * a.y + beta * b.y;
  r.z = alpha * a.z + beta * b.z;
  r.w = alpha * a.w + beta * b.w;
  *(float4*)(xf + i) = r;
  unsigned lo = (unsigned)f2bf(r.x) | ((unsigned)f2bf(r.y) << 16);
  unsigned hi = (unsigned)f2bf(r.z) | ((unsigned)f2bf(r.w) << 16);
  *(uint2*)(xfb + i) = make_uint2(lo, hi);
}

// ===========================================================================
extern "C" void kernel_launch(void* const* d_in, const int* in_sizes, int n_in,
                              void* d_out, int out_size, void* d_ws, size_t ws_size,
                              hipStream_t stream) {
  const float* x   = (const float*)d_in[0];
  const float* fw  = (const float*)d_in[2];
  const float* fb  = (const float*)d_in[3];
  const float* fg  = (const float*)d_in[4];
  const float* fbb = (const float*)d_in[5];
  const float* wq  = (const float*)d_in[6];
  const float* wk  = (const float*)d_in[7];
  const float* wv  = (const float*)d_in[8];
  const float* bq  = (const float*)d_in[9];
  const float* bk  = (const float*)d_in[10];
  const float* bv  = (const float*)d_in[11];
  const float* wo  = (const float*)d_in[12];
  const float* bo  = (const float*)d_in[13];
  const float* gw  = (const float*)d_in[14];
  const float* gb  = (const float*)d_in[15];
  const float* w1  = (const float*)d_in[16];
  const float* b1  = (const float*)d_in[17];
  const float* w2  = (const float*)d_in[18];
  const float* b2  = (const float*)d_in[19];
  const float* n1g = (const float*)d_in[20];
  const float* n1b = (const float*)d_in[21];
  const float* n2g = (const float*)d_in[22];
  const float* n2b = (const float*)d_in[23];
  const float* n3g = (const float*)d_in[24];
  const float* n3b = (const float*)d_in[25];
  float* out = (float*)d_out;

  // ---- workspace carve (bytes) ----
  char* base = (char*)d_ws;
  size_t off = 0;
  auto carve = [&](size_t bytes) { char* p = base + off; off += (bytes + 255) & ~(size_t)255; return p; };
  float* p0 = (float*)carve(961 * 256 * 4);
  float* p1 = (float*)carve(225 * 256 * 4);
  float* p2 = (float*)carve(49 * 256 * 4);
  unsigned short* fwT = (unsigned short*)carve(256 * 768 * 2);
  unsigned short* wqkvT = (unsigned short*)carve(3 * 256 * 256 * 2);  // q|k|v
  unsigned short* wqT = wqkvT;
  unsigned short* wkT = wqkvT + 256 * 256;
  unsigned short* wvT = wqkvT + 2 * 256 * 256;
  unsigned short* woT = (unsigned short*)carve(256 * 256 * 2);
  unsigned short* w1T = (unsigned short*)carve(1024 * 256 * 2);
  unsigned short* w2T = (unsigned short*)carve(256 * 1024 * 2);
  char* R = carve(8388608);                      // catb(6.3MB) -> xg(4MB) -> hbuf(8MB)
  unsigned short* catb = (unsigned short*)R;
  float* xg            = (float*)R;
  unsigned short* hbuf = (unsigned short*)R;
  unsigned short* qb = (unsigned short*)carve((size_t)S * D * 2);
  unsigned short* kb = (unsigned short*)carve((size_t)S * D * 2);
  unsigned short* vb = (unsigned short*)carve((size_t)S * D * 2);
  float* xf            = (float*)qb;             // qb+kb region, dead after flash
  unsigned short* xfb  = vb;                     // vb region, dead after flash
  float* t1  = (float*)carve((size_t)S * D * 4); // fuse out; later ffo
  float* ffo = t1;
  unsigned short* t1b = (unsigned short*)carve((size_t)S * D * 2);
  float* xl  = (float*)carve((size_t)S * D * 4);
  unsigned short* xlb = (unsigned short*)carve((size_t)S * D * 2);
  float* gbuf = (float*)carve(264 * 4);

  hipMemsetAsync(gbuf, 0, 264 * sizeof(float), stream);

  // weight pre-transpose (bf16 WT[N][K]; wq/wk/wv contiguous)
  k_wt<<<dim3(960), dim3(256), 0, stream>>>(fw, wq, wk, wv, wo, w1, w2,
                                            fwT, wqT, wkT, wvT, woT, w1T, w2T);
  // local multi-scale window attention -> pooled per window (MFMA)
  k_local_s<4, 64><<<dim3(961), dim3(64), 0, stream>>>(x, p0, 31);
  k_local_s<8, 256><<<dim3(225), dim3(256), 0, stream>>>(x, p1, 15);
  k_local16<<<dim3(49), dim3(256), 0, stream>>>(x, p2, 7);
  // scatter/avg -> catb[S][768] bf16
  k_combine<<<dim3(S), dim3(256), 0, stream>>>(p0, p1, p2, catb);
  // fuse GEMM + fused LN pair
  k_gemm_m<768, 0, 0><<<dim3(S / 32, 8), dim3(64), 0, stream>>>(catb, fwT, fb, t1, 256);
  k_ln_fuse<<<dim3(S), dim3(256), 0, stream>>>(t1, x, xl, xlb, fg, fbb, n1g, n1b);
  // global MHA (bf16 q/k/v; single QKV dispatch)
  k_gemm_qkv<<<dim3(S / 32, 24), dim3(64), 0, stream>>>(xlb, wqkvT, bq, bk, bv, qb, kb, vb);
  k_flash_mfma<<<dim3(S / 64, NH), dim3(256), 0, stream>>>(qb, kb, vb, t1b);
  k_gemm_m<256, 0, 0><<<dim3(S / 32, 8), dim3(64), 0, stream>>>(t1b, woT, bo, xf, 256);
  k_ln<<<dim3(S), dim3(256), 0, stream>>>(xg, nullptr, xl, xf, n2g, n2b);
  // gate
  k_colmean<<<dim3(64), dim3(256), 0, stream>>>(xl, xg, gbuf);
  k_gate<<<dim3(1), dim3(256), 0, stream>>>(gbuf, gw, gb);
  k_xf<<<dim3(S * D / 1024), dim3(256), 0, stream>>>(xl, xg, gbuf, xf, xfb);
  // FFN + final LN
  k_gemm_m<256, 1, 1><<<dim3(S / 32, 32), dim3(64), 0, stream>>>(xfb, w1T, b1, hbuf, 1024);
  k_gemm_m<1024, 0, 0><<<dim3(S / 32, 8), dim3(64), 0, stream>>>(hbuf, w2T, b2, ffo, 256);
  k_ln<<<dim3(S), dim3(256), 0, stream>>>(out, nullptr, xf, ffo, n3g, n3b);
}

// Round 8
// 235.292 us; speedup vs baseline: 6.3485x; 1.0757x over previous
//
#include <hip/hip_runtime.h>
#include <cstdint>
#include <cstddef>

// ============================================================================
// HierarchicalTransformerBlock: B=1, S=4096 (64x64 grid), D=256, NH=8, dh=32,
// DFF=1024, local windows w = 4,8,16 (stride w/2).
// Round 8: flash split-KV (2 halves, 1024 blocks) + LDS ping-pong (1 barrier/
// iter) + defer-max + setprio; partial-merge kernel. GELU via tanh form.
// Q pre-scaled in QKV GEMM.
// ============================================================================

#define DEVFN __device__ __forceinline__

constexpr int S    = 4096;
constexpr int D    = 256;
constexpr int GRID = 64;
constexpr int NH   = 8;
constexpr int DH   = 32;

typedef __attribute__((ext_vector_type(8))) short bf16x8;
typedef __attribute__((ext_vector_type(4))) float f32x4;
typedef __attribute__((ext_vector_type(16))) float f32x16;
typedef __attribute__((ext_vector_type(2))) unsigned int u32x2;

DEVFN float asf(unsigned u) { return __uint_as_float(u); }

DEVFN unsigned short f2bf(float f) {  // round-to-nearest-even bf16
  unsigned u = __float_as_uint(f);
  u += 0x7fffu + ((u >> 16) & 1u);
  return (unsigned short)(u >> 16);
}
DEVFN float bf2f(unsigned short s) { return __uint_as_float(((unsigned)s) << 16); }

DEVFN bf16x8 pack8(float4 a, float4 b) {
  bf16x8 kv;
  kv[0] = (short)f2bf(a.x); kv[1] = (short)f2bf(a.y);
  kv[2] = (short)f2bf(a.z); kv[3] = (short)f2bf(a.w);
  kv[4] = (short)f2bf(b.x); kv[5] = (short)f2bf(b.y);
  kv[6] = (short)f2bf(b.z); kv[7] = (short)f2bf(b.w);
  return kv;
}

DEVFN float gelu_t(float u) {  // tanh-form GELU (|err| <= ~3e-3 vs exact)
  const float y = 0.7978845608028654f * (u + 0.044715f * u * u * u);
  const float e = __expf(2.f * y);
  return 0.5f * u * (2.f - 2.f / (e + 1.f));
}

// ---------------------------------------------------------------------------
// Weight pre-transpose: fp32 W[K][N] -> bf16 WT[N][K]; 32x32 tiles via LDS.
// ---------------------------------------------------------------------------
__global__ __launch_bounds__(256) void k_wt(
    const float* fw, const float* wq, const float* wk, const float* wv,
    const float* wo, const float* w1, const float* w2,
    unsigned short* fwT, unsigned short* wqT, unsigned short* wkT,
    unsigned short* wvT, unsigned short* woT, unsigned short* w1T,
    unsigned short* w2T) {
  __shared__ unsigned short tile[32][36];
  const int bid = blockIdx.x;
  const float* src; unsigned short* dst; int K, N, t;
  if (bid < 192)      { src = fw; dst = fwT; K = 768;  N = 256;  t = bid; }
  else if (bid < 256) { src = wq; dst = wqT; K = 256;  N = 256;  t = bid - 192; }
  else if (bid < 320) { src = wk; dst = wkT; K = 256;  N = 256;  t = bid - 256; }
  else if (bid < 384) { src = wv; dst = wvT; K = 256;  N = 256;  t = bid - 320; }
  else if (bid < 448) { src = wo; dst = woT; K = 256;  N = 256;  t = bid - 384; }
  else if (bid < 704) { src = w1; dst = w1T; K = 256;  N = 1024; t = bid - 448; }
  else                { src = w2; dst = w2T; K = 1024; N = 256;  t = bid - 704; }
  const int nkt = K >> 5;
  const int k0 = (t % nkt) * 32, n0 = (t / nkt) * 32;
  const int i = threadIdx.x >> 3, j4 = threadIdx.x & 7;
  const float4 v = *(const float4*)(src + (size_t)(k0 + i) * N + n0 + j4 * 4);
  unsigned lo = (unsigned)f2bf(v.x) | ((unsigned)f2bf(v.y) << 16);
  unsigned hi = (unsigned)f2bf(v.z) | ((unsigned)f2bf(v.w) << 16);
  *(uint2*)&tile[i][j4 * 4] = make_uint2(lo, hi);
  __syncthreads();
  unsigned o0 = tile[j4 * 4 + 0][i], o1 = tile[j4 * 4 + 1][i];
  unsigned o2 = tile[j4 * 4 + 2][i], o3 = tile[j4 * 4 + 3][i];
  *(uint2*)(dst + (size_t)(n0 + i) * K + k0 + j4 * 4) =
      make_uint2(o0 | (o1 << 16), o2 | (o3 << 16));
}

// ---------------------------------------------------------------------------
// MFMA GEMM: C[M][N] = Ab[M][K](bf16) @ WT[N][K]^T(bf16) + bias.
// ---------------------------------------------------------------------------
template <int K, int OUTBF, int ACT>
__global__ __launch_bounds__(64) void k_gemm_m(const unsigned short* __restrict__ Ab,
                                               const unsigned short* __restrict__ WT,
                                               const float* __restrict__ bias,
                                               void* __restrict__ Cout, int N) {
  const int lane = threadIdx.x;
  const int lc = lane & 31, hi = lane >> 5;
  const int m0 = blockIdx.x * 32, n0 = blockIdx.y * 32;
  const unsigned short* ap = Ab + (size_t)(m0 + lc) * K + hi * 8;
  const unsigned short* bp = WT + (size_t)(n0 + lc) * K + hi * 8;
  f32x16 acc = {0.f,0.f,0.f,0.f,0.f,0.f,0.f,0.f,0.f,0.f,0.f,0.f,0.f,0.f,0.f,0.f};
#pragma unroll 4
  for (int k0 = 0; k0 < K; k0 += 16) {
    bf16x8 a = *(const bf16x8*)(ap + k0);
    bf16x8 b = *(const bf16x8*)(bp + k0);
    acc = __builtin_amdgcn_mfma_f32_32x32x16_bf16(a, b, acc, 0, 0, 0);
  }
  const float bv = bias[n0 + lc];
#pragma unroll
  for (int r = 0; r < 16; ++r) {
    const int row = (r & 3) + 8 * (r >> 2) + 4 * hi;
    float v = acc[r] + bv;
    if (ACT == 1) v = gelu_t(v);
    if (OUTBF) ((unsigned short*)Cout)[(size_t)(m0 + row) * N + n0 + lc] = f2bf(v);
    else       ((float*)Cout)[(size_t)(m0 + row) * N + n0 + lc] = v;
  }
}

// QKV: grid (S/32, 24); sel = by>>3 picks {wq,bq,qb}/{wk,bk,kb}/{wv,bv,vb}.
// Q is pre-scaled by 1/sqrt(dh).
__global__ __launch_bounds__(64) void k_gemm_qkv(const unsigned short* __restrict__ Ab,
                                                 const unsigned short* __restrict__ wqkvT,
                                                 const float* __restrict__ bq,
                                                 const float* __restrict__ bk,
                                                 const float* __restrict__ bv,
                                                 unsigned short* __restrict__ qb,
                                                 unsigned short* __restrict__ kb,
                                                 unsigned short* __restrict__ vb) {
  const int lane = threadIdx.x;
  const int lc = lane & 31, hi = lane >> 5;
  const int m0 = blockIdx.x * 32;
  const int sel = blockIdx.y >> 3, n0 = (blockIdx.y & 7) * 32;
  const unsigned short* WT = wqkvT + (size_t)sel * 256 * 256;
  const float* bias = sel == 0 ? bq : sel == 1 ? bk : bv;
  unsigned short* out = sel == 0 ? qb : sel == 1 ? kb : vb;
  const float oscale = sel == 0 ? 0.17677669529663687f : 1.f;
  const unsigned short* ap = Ab + (size_t)(m0 + lc) * 256 + hi * 8;
  const unsigned short* bp = WT + (size_t)(n0 + lc) * 256 + hi * 8;
  f32x16 acc = {0.f,0.f,0.f,0.f,0.f,0.f,0.f,0.f,0.f,0.f,0.f,0.f,0.f,0.f,0.f,0.f};
#pragma unroll 4
  for (int k0 = 0; k0 < 256; k0 += 16) {
    bf16x8 a = *(const bf16x8*)(ap + k0);
    bf16x8 b = *(const bf16x8*)(bp + k0);
    acc = __builtin_amdgcn_mfma_f32_32x32x16_bf16(a, b, acc, 0, 0, 0);
  }
  const float bvv = bias[n0 + lc];
#pragma unroll
  for (int r = 0; r < 16; ++r) {
    const int row = (r & 3) + 8 * (r >> 2) + 4 * hi;
    out[(size_t)(m0 + row) * 256 + n0 + lc] = f2bf((acc[r] + bvv) * oscale);
  }
}

// ---------------------------------------------------------------------------
// Local windowed attention, w=4/8 (16x16x32 MFMA), one window per block.
// ---------------------------------------------------------------------------
template <int W, int THREADS>
__global__ __launch_bounds__(THREADS) void k_local_s(const float* __restrict__ x,
                                                     float* __restrict__ pooled, int nS) {
  constexpr int NT  = W * W;
  constexpr int NCT = NT / 16;
  constexpr int LDE = 264;
  __shared__ unsigned short win[NT][LDE];
  __shared__ float a[NT];
  const int tid = threadIdx.x;
  const int wave = tid >> 6, lane = tid & 63;
  const int lr = lane & 15, lg = lane >> 4;
  const int l = blockIdx.x;
  const int row0 = (l / nS) * (W / 2), col0 = (l % nS) * (W / 2);

  for (int e8 = tid; e8 < NT * 32; e8 += THREADS) {
    const int t = e8 >> 5, c8 = (e8 & 31) * 8;
    const float* src = x + ((size_t)((row0 + t / W) * GRID + col0 + (t % W))) * D + c8;
    *(bf16x8*)&win[t][c8] = pack8(*(const float4*)src, *(const float4*)(src + 4));
  }
  if (tid < NT) a[tid] = 0.f;
  __syncthreads();

  bf16x8 af[8];
#pragma unroll
  for (int k2 = 0; k2 < 8; ++k2)
    af[k2] = *(const bf16x8*)&win[wave * 16 + lr][k2 * 32 + lg * 8];

  float m[4], Z[4], Zi[4];
#pragma unroll
  for (int r = 0; r < 4; ++r) { m[r] = -INFINITY; Z[r] = 0.f; }

  for (int ct = 0; ct < NCT; ++ct) {
    f32x4 Ca = {0.f, 0.f, 0.f, 0.f}, Cb = {0.f, 0.f, 0.f, 0.f};
#pragma unroll
    for (int k2 = 0; k2 < 8; k2 += 2) {
      bf16x8 b0 = *(const bf16x8*)&win[ct * 16 + lr][k2 * 32 + lg * 8];
      bf16x8 b1 = *(const bf16x8*)&win[ct * 16 + lr][(k2 + 1) * 32 + lg * 8];
      Ca = __builtin_amdgcn_mfma_f32_16x16x32_bf16(af[k2], b0, Ca, 0, 0, 0);
      Cb = __builtin_amdgcn_mfma_f32_16x16x32_bf16(af[k2 + 1], b1, Cb, 0, 0, 0);
    }
#pragma unroll
    for (int r = 0; r < 4; ++r) {
      const float sv = (Ca[r] + Cb[r]) * 0.0625f;
      const float nm = fmaxf(m[r], sv);
      Z[r] = Z[r] * __expf(m[r] - nm) + __expf(sv - nm);
      m[r] = nm;
    }
  }
#pragma unroll
  for (int r = 0; r < 4; ++r) {
#pragma unroll
    for (int msk = 1; msk <= 8; msk <<= 1) {
      const float om = __shfl_xor(m[r], msk), oz = __shfl_xor(Z[r], msk);
      const float nm = fmaxf(m[r], om);
      Z[r] = Z[r] * __expf(m[r] - nm) + oz * __expf(om - nm);
      m[r] = nm;
    }
    Zi[r] = 1.f / Z[r];
  }

  for (int ct = 0; ct < NCT; ++ct) {
    f32x4 Ca = {0.f, 0.f, 0.f, 0.f}, Cb = {0.f, 0.f, 0.f, 0.f};
#pragma unroll
    for (int k2 = 0; k2 < 8; k2 += 2) {
      bf16x8 b0 = *(const bf16x8*)&win[ct * 16 + lr][k2 * 32 + lg * 8];
      bf16x8 b1 = *(const bf16x8*)&win[ct * 16 + lr][(k2 + 1) * 32 + lg * 8];
      Ca = __builtin_amdgcn_mfma_f32_16x16x32_bf16(af[k2], b0, Ca, 0, 0, 0);
      Cb = __builtin_amdgcn_mfma_f32_16x16x32_bf16(af[k2 + 1], b1, Cb, 0, 0, 0);
    }
    float cs = 0.f;
#pragma unroll
    for (int r = 0; r < 4; ++r)
      cs += __expf((Ca[r] + Cb[r]) * 0.0625f - m[r]) * Zi[r];
    cs += __shfl_xor(cs, 16);
    cs += __shfl_xor(cs, 32);
    if (lg == 0) atomicAdd(&a[ct * 16 + lr], cs);
  }
  __syncthreads();

  for (int d = tid; d < D; d += THREADS) {
    float acc = 0.f;
#pragma unroll 8
    for (int k = 0; k < NT; ++k) acc += a[k] * bf2f(win[k][d]);
    pooled[(size_t)l * D + d] = acc * (1.f / NT);
  }
}

// ---------------------------------------------------------------------------
// Local windowed attention, w=16 (NT=256), 32x32x16 MFMA, one window/block.
// ---------------------------------------------------------------------------
__global__ __launch_bounds__(256, 1) void k_local16(const float* __restrict__ x,
                                                    float* __restrict__ pooled, int nS) {
  constexpr int LDE = 264;
  __shared__ unsigned short win[256][LDE];
  __shared__ float a[256];
  const int tid = threadIdx.x;
  const int wave = tid >> 6, lane = tid & 63;
  const int lc = lane & 31, hi = lane >> 5;
  const int l = blockIdx.x;
  const int row0 = (l / nS) * 8, col0 = (l % nS) * 8;

  for (int e8 = tid; e8 < 256 * 32; e8 += 256) {
    const int t = e8 >> 5, c8 = (e8 & 31) * 8;
    const float* src = x + ((size_t)((row0 + (t >> 4)) * GRID + col0 + (t & 15))) * D + c8;
    *(bf16x8*)&win[t][c8] = pack8(*(const float4*)src, *(const float4*)(src + 4));
  }
  a[tid] = 0.f;
  __syncthreads();

  float m[2][16], Z[2][16], Zi[2][16];
#pragma unroll
  for (int s = 0; s < 2; ++s)
#pragma unroll
    for (int r = 0; r < 16; ++r) { m[s][r] = -INFINITY; Z[s][r] = 0.f; }

#pragma unroll
  for (int s = 0; s < 2; ++s) {
    const int R0 = (wave * 2 + s) * 32;
    bf16x8 af[16];
#pragma unroll
    for (int k2 = 0; k2 < 16; ++k2)
      af[k2] = *(const bf16x8*)&win[R0 + lc][k2 * 16 + hi * 8];
    for (int ct = 0; ct < 8; ++ct) {
      f32x16 Ca = {0.f,0.f,0.f,0.f,0.f,0.f,0.f,0.f,0.f,0.f,0.f,0.f,0.f,0.f,0.f,0.f};
      f32x16 Cb = Ca;
#pragma unroll
      for (int k2 = 0; k2 < 16; k2 += 2) {
        bf16x8 b0 = *(const bf16x8*)&win[ct * 32 + lc][k2 * 16 + hi * 8];
        bf16x8 b1 = *(const bf16x8*)&win[ct * 32 + lc][(k2 + 1) * 16 + hi * 8];
        Ca = __builtin_amdgcn_mfma_f32_32x32x16_bf16(af[k2], b0, Ca, 0, 0, 0);
        Cb = __builtin_amdgcn_mfma_f32_32x32x16_bf16(af[k2 + 1], b1, Cb, 0, 0, 0);
      }
#pragma unroll
      for (int r = 0; r < 16; ++r) {
        const float sv = (Ca[r] + Cb[r]) * 0.0625f;
        const float nm = fmaxf(m[s][r], sv);
        Z[s][r] = Z[s][r] * __expf(m[s][r] - nm) + __expf(sv - nm);
        m[s][r] = nm;
      }
    }
#pragma unroll
    for (int r = 0; r < 16; ++r) {
#pragma unroll
      for (int msk = 1; msk <= 16; msk <<= 1) {
        const float om = __shfl_xor(m[s][r], msk), oz = __shfl_xor(Z[s][r], msk);
        const float nm = fmaxf(m[s][r], om);
        Z[s][r] = Z[s][r] * __expf(m[s][r] - nm) + oz * __expf(om - nm);
        m[s][r] = nm;
      }
      Zi[s][r] = 1.f / Z[s][r];
    }
  }

#pragma unroll
  for (int s = 0; s < 2; ++s) {
    const int R0 = (wave * 2 + s) * 32;
    bf16x8 af[16];
#pragma unroll
    for (int k2 = 0; k2 < 16; ++k2)
      af[k2] = *(const bf16x8*)&win[R0 + lc][k2 * 16 + hi * 8];
    for (int ct = 0; ct < 8; ++ct) {
      f32x16 Ca = {0.f,0.f,0.f,0.f,0.f,0.f,0.f,0.f,0.f,0.f,0.f,0.f,0.f,0.f,0.f,0.f};
      f32x16 Cb = Ca;
#pragma unroll
      for (int k2 = 0; k2 < 16; k2 += 2) {
        bf16x8 b0 = *(const bf16x8*)&win[ct * 32 + lc][k2 * 16 + hi * 8];
        bf16x8 b1 = *(const bf16x8*)&win[ct * 32 + lc][(k2 + 1) * 16 + hi * 8];
        Ca = __builtin_amdgcn_mfma_f32_32x32x16_bf16(af[k2], b0, Ca, 0, 0, 0);
        Cb = __builtin_amdgcn_mfma_f32_32x32x16_bf16(af[k2 + 1], b1, Cb, 0, 0, 0);
      }
      float cs = 0.f;
#pragma unroll
      for (int r = 0; r < 16; ++r)
        cs += __expf((Ca[r] + Cb[r]) * 0.0625f - m[s][r]) * Zi[s][r];
      cs += __shfl_xor(cs, 32);
      if (hi == 0) atomicAdd(&a[ct * 32 + lc], cs);
    }
  }
  __syncthreads();

  {
    const int d = tid;
    float acc = 0.f;
#pragma unroll 8
    for (int k = 0; k < 256; ++k) acc += a[k] * bf2f(win[k][d]);
    pooled[(size_t)l * D + d] = acc * (1.f / 256.f);
  }
}

// ---------------------------------------------------------------------------
// Overlap-average scatter of pooled windows -> catb[t][768] (bf16)
// ---------------------------------------------------------------------------
DEVFN float gatherp(const float* __restrict__ pooled, int r, int c, int W, int s, int nS, int d) {
  int amin = max(0, (r - W + s) / s), amax = min(nS - 1, r / s);
  int bmin = max(0, (c - W + s) / s), bmax = min(nS - 1, c / s);
  float acc = 0.f;
  int cnt = 0;
  for (int a = amin; a <= amax; ++a)
    for (int b = bmin; b <= bmax; ++b) { acc += pooled[(size_t)(a * nS + b) * D + d]; ++cnt; }
  return acc / (float)cnt;
}

__global__ void k_combine(const float* __restrict__ p0, const float* __restrict__ p1,
                          const float* __restrict__ p2, unsigned short* __restrict__ catb) {
  const int t = blockIdx.x, d = threadIdx.x;
  const int r = t >> 6, c = t & 63;
  unsigned short* o = catb + (size_t)t * 768;
  o[d]       = f2bf(gatherp(p0, r, c, 4, 2, 31, d));
  o[256 + d] = f2bf(gatherp(p1, r, c, 8, 4, 15, d));
  o[512 + d] = f2bf(gatherp(p2, r, c, 16, 8, 7, d));
}

// ---------------------------------------------------------------------------
// Block-wide sum of (a, b) over 256 threads
// ---------------------------------------------------------------------------
DEVFN float2 block_sum2(float a, float b) {
  __shared__ float sb[8];
#pragma unroll
  for (int m = 32; m; m >>= 1) { a += __shfl_xor(a, m); b += __shfl_xor(b, m); }
  const int w = threadIdx.x >> 6;
  __syncthreads();
  if ((threadIdx.x & 63) == 0) { sb[w] = a; sb[4 + w] = b; }
  __syncthreads();
  return make_float2(sb[0] + sb[1] + sb[2] + sb[3], sb[4] + sb[5] + sb[6] + sb[7]);
}

// out = LN(a (+ b)); optional bf16 dual write. In-place safe (out==a).
__global__ __launch_bounds__(256) void k_ln(float* __restrict__ out, unsigned short* __restrict__ outb,
                                            const float* __restrict__ a, const float* __restrict__ b,
                                            const float* __restrict__ g, const float* __restrict__ be) {
  const size_t i = (size_t)blockIdx.x * D + threadIdx.x;
  float v = a[i] + (b ? b[i] : 0.f);
  float2 s = block_sum2(v, v * v);
  float mean = s.x * (1.f / D);
  float var = s.y * (1.f / D) - mean * mean;
  const float r = (v - mean) * rsqrtf(var + 1e-5f) * g[threadIdx.x] + be[threadIdx.x];
  out[i] = r;
  if (outb) outb[i] = f2bf(r);
}

// xl = LN2(x + LN1(t1)); writes fp32 + bf16 (fuses the two post-fuse LNs)
__global__ __launch_bounds__(256) void k_ln_fuse(const float* __restrict__ t1,
                                                 const float* __restrict__ x,
                                                 float* __restrict__ xl,
                                                 unsigned short* __restrict__ xlb,
                                                 const float* __restrict__ fg,
                                                 const float* __restrict__ fbb,
                                                 const float* __restrict__ n1g,
                                                 const float* __restrict__ n1b) {
  const size_t i = (size_t)blockIdx.x * D + threadIdx.x;
  const float v1 = t1[i];
  float2 s1 = block_sum2(v1, v1 * v1);
  const float mean1 = s1.x * (1.f / D);
  const float var1 = s1.y * (1.f / D) - mean1 * mean1;
  const float r1 = (v1 - mean1) * rsqrtf(var1 + 1e-5f) * fg[threadIdx.x] + fbb[threadIdx.x];
  const float v2 = x[i] + r1;
  float2 s2 = block_sum2(v2, v2 * v2);
  const float mean2 = s2.x * (1.f / D);
  const float var2 = s2.y * (1.f / D) - mean2 * mean2;
  const float r2 = (v2 - mean2) * rsqrtf(var2 + 1e-5f) * n1g[threadIdx.x] + n1b[threadIdx.x];
  xl[i] = r2;
  xlb[i] = f2bf(r2);
}

// ---------------------------------------------------------------------------
// MFMA flash attention, split-KV: grid (S/64, NH, 2); each block processes
// 2048 keys, writes unnormalized partial O (fp32) + per-q (m,l).
// Ping-pong LDS (1 barrier/iter), swapped QK^T, in-register P, tr-read V,
// defer-max rescale, setprio around MFMA.
// ---------------------------------------------------------------------------
__global__ __launch_bounds__(256) void k_flash_mfma(const unsigned short* __restrict__ Qg,
                                                    const unsigned short* __restrict__ Kg,
                                                    const unsigned short* __restrict__ Vg,
                                                    float* __restrict__ po,
                                                    float* __restrict__ pml) {
  const int h = blockIdx.y, z = blockIdx.z;
  const int tid = threadIdx.x;
  const int wave = tid >> 6, lane = tid & 63;
  const int lr = lane & 15, lg = lane >> 4;
  constexpr int NT2 = 32;            // 32 tiles x 64 keys = 2048 keys per half

  __shared__ unsigned short Kf[2][64][40];
  __shared__ unsigned short VS[2][2048];

  const int q0 = blockIdx.x * 64 + wave * 16;
  const int kbase = z * 2048;

  // Q fragment (B-operand of swapped QK); already pre-scaled in QKV GEMM
  const bf16x8 qfrag = *(const bf16x8*)(Qg + (size_t)(q0 + lr) * D + h * DH + lg * 8);

  f32x4 o0 = {0.f, 0.f, 0.f, 0.f}, o1 = {0.f, 0.f, 0.f, 0.f};
  float mrow = -INFINITY, lrow = 0.f;

  const unsigned vsbase0 =
      (unsigned)(unsigned long long)(const void*)&VS[0][0] + (unsigned)(lg * 128 + lr * 2);

  // per-lane staging geometry
  const int key = tid >> 2, c8 = (tid & 3) * 8;
  const int vidx = (c8 >> 4) * 1024 + (key >> 2) * 64 + (key & 3) * 16 + (c8 & 15);
  const unsigned short* kp = Kg + (size_t)(kbase + key) * D + h * DH + c8;
  const unsigned short* vp = Vg + (size_t)(kbase + key) * D + h * DH + c8;
  constexpr int KSTEP = 64 * D;

  // prologue: stage tile 0 into buf 0
  {
    bf16x8 k0r = *(const bf16x8*)kp;
    bf16x8 v0r = *(const bf16x8*)vp;
    *(bf16x8*)&Kf[0][key][c8] = k0r;
    *(bf16x8*)&VS[0][vidx] = v0r;
  }
  __syncthreads();

  for (int kt = 0; kt < NT2; ++kt) {
    const int cur = kt & 1;
    // prefetch next tile into registers (hidden under compute)
    const int ktn = (kt + 1 < NT2) ? kt + 1 : kt;
    bf16x8 kreg = *(const bf16x8*)(kp + (size_t)ktn * KSTEP);
    bf16x8 vreg = *(const bf16x8*)(vp + (size_t)ktn * KSTEP);

    // swapped QK^T: s[k16][r] = S[q=lr][key = k16*16 + lg*4 + r]
    f32x4 s[4];
    __builtin_amdgcn_s_setprio(1);
#pragma unroll
    for (int k16 = 0; k16 < 4; ++k16) {
      bf16x8 ka = *(const bf16x8*)&Kf[cur][k16 * 16 + lr][lg * 8];
      f32x4 zc = {0.f, 0.f, 0.f, 0.f};
      s[k16] = __builtin_amdgcn_mfma_f32_16x16x32_bf16(ka, qfrag, zc, 0, 0, 0);
    }
    __builtin_amdgcn_s_setprio(0);

    // issue V tr-reads early (latency hidden under softmax VALU)
    const unsigned vb = vsbase0 + (unsigned)(cur << 12);
    u32x2 tv000, tv001, tv010, tv011, tv100, tv101, tv110, tv111;  // [kt2][t][dg]
    asm volatile("ds_read_b64_tr_b16 %0, %1 offset:0"    : "=v"(tv000) : "v"(vb));
    asm volatile("ds_read_b64_tr_b16 %0, %1 offset:2048" : "=v"(tv001) : "v"(vb));
    asm volatile("ds_read_b64_tr_b16 %0, %1 offset:512"  : "=v"(tv010) : "v"(vb));
    asm volatile("ds_read_b64_tr_b16 %0, %1 offset:2560" : "=v"(tv011) : "v"(vb));
    asm volatile("ds_read_b64_tr_b16 %0, %1 offset:1024" : "=v"(tv100) : "v"(vb));
    asm volatile("ds_read_b64_tr_b16 %0, %1 offset:3072" : "=v"(tv101) : "v"(vb));
    asm volatile("ds_read_b64_tr_b16 %0, %1 offset:1536" : "=v"(tv110) : "v"(vb));
    asm volatile("ds_read_b64_tr_b16 %0, %1 offset:3584" : "=v"(tv111) : "v"(vb));

    // online softmax with defer-max (THR=8)
    float tm = s[0][0];
#pragma unroll
    for (int k16 = 0; k16 < 4; ++k16)
#pragma unroll
      for (int r = 0; r < 4; ++r) tm = fmaxf(tm, s[k16][r]);
    const bool skip = __all(tm - mrow <= 8.f);
    if (!skip) {
      float tmm = fmaxf(tm, __shfl_xor(tm, 16));
      tmm = fmaxf(tmm, __shfl_xor(tmm, 32));
      const float nm = fmaxf(mrow, tmm);
      const float cfac = __expf(mrow - nm);
      mrow = nm;
      lrow *= cfac;
#pragma unroll
      for (int r = 0; r < 4; ++r) {
        const float cr = __shfl(cfac, lg * 4 + r);
        o0[r] *= cr; o1[r] *= cr;
      }
    }
    float ls = 0.f;
#pragma unroll
    for (int k16 = 0; k16 < 4; ++k16)
#pragma unroll
      for (int r = 0; r < 4; ++r) { s[k16][r] = __expf(s[k16][r] - mrow); ls += s[k16][r]; }
    ls += __shfl_xor(ls, 16);
    ls += __shfl_xor(ls, 32);
    lrow += ls;

    // drain tr-reads; pin ordering (rule #18)
    asm volatile("s_waitcnt lgkmcnt(0)" ::: "memory");
    __builtin_amdgcn_sched_barrier(0);

    // PV: a = lane-local P (permuted k), b = tr-read V fragments
    union VB { u32x2 u2[2]; bf16x8 b; };
    __builtin_amdgcn_s_setprio(1);
#pragma unroll
    for (int kt2 = 0; kt2 < 2; ++kt2) {
      bf16x8 pa;
#pragma unroll
      for (int j = 0; j < 4; ++j) {
        pa[j]     = (short)f2bf(s[2 * kt2][j]);
        pa[4 + j] = (short)f2bf(s[2 * kt2 + 1][j]);
      }
      VB v0f, v1f;
      if (kt2 == 0) { v0f.u2[0] = tv000; v0f.u2[1] = tv010; v1f.u2[0] = tv001; v1f.u2[1] = tv011; }
      else          { v0f.u2[0] = tv100; v0f.u2[1] = tv110; v1f.u2[0] = tv101; v1f.u2[1] = tv111; }
      o0 = __builtin_amdgcn_mfma_f32_16x16x32_bf16(pa, v0f.b, o0, 0, 0, 0);
      o1 = __builtin_amdgcn_mfma_f32_16x16x32_bf16(pa, v1f.b, o1, 0, 0, 0);
    }
    __builtin_amdgcn_s_setprio(0);

    // commit prefetched tile to the other buffer; single barrier per iter
    if (kt + 1 < NT2) {
      *(bf16x8*)&Kf[cur ^ 1][key][c8] = kreg;
      *(bf16x8*)&VS[cur ^ 1][vidx] = vreg;
      __syncthreads();
    }
  }

  // partial outputs (unnormalized) + per-q (m,l)
#pragma unroll
  for (int r = 0; r < 4; ++r) {
    float* op = po + (size_t)z * S * D + (size_t)(q0 + lg * 4 + r) * D + h * DH + lr;
    op[0]  = o0[r];
    op[16] = o1[r];
  }
  if (lane < 16) {
    float* mlp = pml + ((size_t)(z * NH + h) * S + q0 + lr) * 2;
    mlp[0] = mrow;
    mlp[1] = lrow;
  }
}

// merge the two KV halves: out bf16 t1b[q][d]
__global__ __launch_bounds__(256) void k_fmerge(const float* __restrict__ po,
                                                const float* __restrict__ pml,
                                                unsigned short* __restrict__ t1b) {
  const int t = blockIdx.x, d = threadIdx.x;
  const int h = d >> 5;
  const float* ml0 = pml + ((size_t)h * S + t) * 2;
  const float* ml1 = pml + ((size_t)(NH + h) * S + t) * 2;
  const float m0 = ml0[0], l0 = ml0[1], m1 = ml1[0], l1 = ml1[1];
  const float M = fmaxf(m0, m1);
  const float a0 = __expf(m0 - M), a1 = __expf(m1 - M);
  const float L = l0 * a0 + l1 * a1;
  const float v = (po[(size_t)t * D + d] * a0 + po[(size_t)S * D + (size_t)t * D + d] * a1) / L;
  t1b[(size_t)t * D + d] = f2bf(v);
}

// ---------------------------------------------------------------------------
// Gate helpers
// ---------------------------------------------------------------------------
__global__ __launch_bounds__(256) void k_colmean(const float* __restrict__ xl,
                                                 const float* __restrict__ xg,
                                                 float* __restrict__ gbuf) {
  const int j = threadIdx.x;
  const int t0 = blockIdx.x * 64;
  float s = 0.f;
  for (int t = 0; t < 64; ++t) {
    size_t i = (size_t)(t0 + t) * D + j;
    s += xl[i] + xg[i];
  }
  atomicAdd(&gbuf[j], s * 0.5f);
}

__global__ __launch_bounds__(256) void k_gate(float* __restrict__ gbuf,
                                              const float* __restrict__ gw,
                                              const float* __restrict__ gb) {
  const int j = threadIdx.x;
  const float gm = gbuf[j] * (1.f / (float)S);
  float2 s = block_sum2(gm * gw[2 * j], gm * gw[2 * j + 1]);
  if (j == 0) {
    float g0 = s.x + gb[0], g1 = s.y + gb[1];
    float mx = fmaxf(g0, g1);
    float e0 = __expf(g0 - mx), e1 = __expf(g1 - mx);
    gbuf[256] = e0 / (e0 + e1);
    gbuf[257] = e1 / (e0 + e1);
  }
}

__global__ __launch_bounds__(256) void k_xf(const float* __restrict__ xl,
                                            const float* __restrict__ xg,
                                            const float* __restrict__ gbuf,
                                            float* __restrict__ xf,
                                            unsigned short* __restrict__ xfb) {
  const float alpha = gbuf[256], beta = gbuf[257];
  const size_t i = ((size_t)blockIdx.x * 256 + threadIdx.x) * 4;
  float4 a = *(const float4*)(xg + i);
  float4 b = *(const float4*)(xl + i);
  float4 r;
  r.x = alpha * a.x + beta * b.x;
  r.y = alpha * a.y + beta * b.y;
  r.z = alpha * a.z + beta * b.z;
  r.w = alpha * a.w + beta * b.w;
  *(float4*)(xf + i) = r;
  unsigned lo = (unsigned)f2bf(r.x) | ((unsigned)f2bf(r.y) << 16);
  unsigned hi = (unsigned)f2bf(r.z) | ((unsigned)f2bf(r.w) << 16);
  *(uint2*)(xfb + i) = make_uint2(lo, hi);
}

// ===========================================================================
extern "C" void kernel_launch(void* const* d_in, const int* in_sizes, int n_in,
                              void* d_out, int out_size, void* d_ws, size_t ws_size,
                              hipStream_t stream) {
  const float* x   = (const float*)d_in[0];
  const float* fw  = (const float*)d_in[2];
  const float* fb  = (const float*)d_in[3];
  const float* fg  = (const float*)d_in[4];
  const float* fbb = (const float*)d_in[5];
  const float* wq  = (const float*)d_in[6];
  const float* wk  = (const float*)d_in[7];
  const float* wv  = (const float*)d_in[8];
  const float* bq  = (const float*)d_in[9];
  const float* bk  = (const float*)d_in[10];
  const float* bv  = (const float*)d_in[11];
  const float* wo  = (const float*)d_in[12];
  const float* bo  = (const float*)d_in[13];
  const float* gw  = (const float*)d_in[14];
  const float* gb  = (const float*)d_in[15];
  const float* w1  = (const float*)d_in[16];
  const float* b1  = (const float*)d_in[17];
  const float* w2  = (const float*)d_in[18];
  const float* b2  = (const float*)d_in[19];
  const float* n1g = (const float*)d_in[20];
  const float* n1b = (const float*)d_in[21];
  const float* n2g = (const float*)d_in[22];
  const float* n2b = (const float*)d_in[23];
  const float* n3g = (const float*)d_in[24];
  const float* n3b = (const float*)d_in[25];
  float* out = (float*)d_out;

  // ---- workspace carve (bytes) ----
  char* base = (char*)d_ws;
  size_t off = 0;
  auto carve = [&](size_t bytes) { char* p = base + off; off += (bytes + 255) & ~(size_t)255; return p; };
  float* p0 = (float*)carve(961 * 256 * 4);
  float* p1 = (float*)carve(225 * 256 * 4);
  float* p2 = (float*)carve(49 * 256 * 4);
  unsigned short* fwT = (unsigned short*)carve(256 * 768 * 2);
  unsigned short* wqkvT = (unsigned short*)carve(3 * 256 * 256 * 2);  // q|k|v
  unsigned short* wqT = wqkvT;
  unsigned short* wkT = wqkvT + 256 * 256;
  unsigned short* wvT = wqkvT + 2 * 256 * 256;
  unsigned short* woT = (unsigned short*)carve(256 * 256 * 2);
  unsigned short* w1T = (unsigned short*)carve(1024 * 256 * 2);
  unsigned short* w2T = (unsigned short*)carve(256 * 1024 * 2);
  char* R = carve(8388608);        // catb(6.3MB) -> po(8MB) -> xg(4MB) -> hbuf(8MB)
  unsigned short* catb = (unsigned short*)R;
  float* po            = (float*)R;
  float* xg            = (float*)R;
  unsigned short* hbuf = (unsigned short*)R;
  float* pml = (float*)carve(2 * NH * (size_t)S * 2 * 4);
  unsigned short* qb = (unsigned short*)carve((size_t)S * D * 2);
  unsigned short* kb = (unsigned short*)carve((size_t)S * D * 2);
  unsigned short* vb = (unsigned short*)carve((size_t)S * D * 2);
  float* xf            = (float*)qb;             // qb+kb region, dead after flash
  unsigned short* xfb  = vb;                     // vb region, dead after flash
  float* t1  = (float*)carve((size_t)S * D * 4); // fuse out; later ffo
  float* ffo = t1;
  unsigned short* t1b = (unsigned short*)carve((size_t)S * D * 2);
  float* xl  = (float*)carve((size_t)S * D * 4);
  unsigned short* xlb = (unsigned short*)carve((size_t)S * D * 2);
  float* gbuf = (float*)carve(264 * 4);

  hipMemsetAsync(gbuf, 0, 264 * sizeof(float), stream);

  // weight pre-transpose (bf16 WT[N][K]; wq/wk/wv contiguous)
  k_wt<<<dim3(960), dim3(256), 0, stream>>>(fw, wq, wk, wv, wo, w1, w2,
                                            fwT, wqT, wkT, wvT, woT, w1T, w2T);
  // local multi-scale window attention -> pooled per window (MFMA)
  k_local_s<4, 64><<<dim3(961), dim3(64), 0, stream>>>(x, p0, 31);
  k_local_s<8, 256><<<dim3(225), dim3(256), 0, stream>>>(x, p1, 15);
  k_local16<<<dim3(49), dim3(256), 0, stream>>>(x, p2, 7);
  // scatter/avg -> catb[S][768] bf16
  k_combine<<<dim3(S), dim3(256), 0, stream>>>(p0, p1, p2, catb);
  // fuse GEMM + fused LN pair
  k_gemm_m<768, 0, 0><<<dim3(S / 32, 8), dim3(64), 0, stream>>>(catb, fwT, fb, t1, 256);
  k_ln_fuse<<<dim3(S), dim3(256), 0, stream>>>(t1, x, xl, xlb, fg, fbb, n1g, n1b);
  // global MHA (bf16 q/k/v; single QKV dispatch; q pre-scaled)
  k_gemm_qkv<<<dim3(S / 32, 24), dim3(64), 0, stream>>>(xlb, wqkvT, bq, bk, bv, qb, kb, vb);
  k_flash_mfma<<<dim3(S / 64, NH, 2), dim3(256), 0, stream>>>(qb, kb, vb, po, pml);
  k_fmerge<<<dim3(S), dim3(256), 0, stream>>>(po, pml, t1b);
  k_gemm_m<256, 0, 0><<<dim3(S / 32, 8), dim3(64), 0, stream>>>(t1b, woT, bo, xf, 256);
  k_ln<<<dim3(S), dim3(256), 0, stream>>>(xg, nullptr, xl, xf, n2g, n2b);
  // gate
  k_colmean<<<dim3(64), dim3(256), 0, stream>>>(xl, xg, gbuf);
  k_gate<<<dim3(1), dim3(256), 0, stream>>>(gbuf, gw, gb);
  k_xf<<<dim3(S * D / 1024), dim3(256), 0, stream>>>(xl, xg, gbuf, xf, xfb);
  // FFN + final LN
  k_gemm_m<256, 1, 1><<<dim3(S / 32, 32), dim3(64), 0, stream>>>(xfb, w1T, b1, hbuf, 1024);
  k_gemm_m<1024, 0, 0><<<dim3(S / 32, 8), dim3(64), 0, stream>>>(hbuf, w2T, b2, ffo, 256);
  k_ln<<<dim3(S), dim3(256), 0, stream>>>(out, nullptr, xf, ffo, n3g, n3b);
}

// Round 9
// 229.943 us; speedup vs baseline: 6.4962x; 1.0233x over previous
//
#include <hip/hip_runtime.h>
#include <hip/hip_bf16.h>
#include <cstdint>
#include <cstddef>

// ============================================================================
// HierarchicalTransformerBlock: B=1, S=4096 (64x64 grid), D=256, NH=8, dh=32,
// DFF=1024, local windows w = 4,8,16 (stride w/2).
// Round 9: flash 4-way split-KV (8 blocks/CU), exp2-domain softmax, cvt_pk
// bf16 packing, bf16 partial-O; GEMMs dual-accumulator (2 MFMA chains).
// ============================================================================

#define DEVFN __device__ __forceinline__

constexpr int S    = 4096;
constexpr int D    = 256;
constexpr int GRID = 64;
constexpr int NH   = 8;
constexpr int DH   = 32;

typedef __attribute__((ext_vector_type(8))) short bf16x8;
typedef __attribute__((ext_vector_type(4))) float f32x4;
typedef __attribute__((ext_vector_type(16))) float f32x16;
typedef __attribute__((ext_vector_type(2))) unsigned int u32x2;

DEVFN float asf(unsigned u) { return __uint_as_float(u); }

DEVFN unsigned short f2bf(float f) {  // round-to-nearest-even bf16
  unsigned u = __float_as_uint(f);
  u += 0x7fffu + ((u >> 16) & 1u);
  return (unsigned short)(u >> 16);
}
DEVFN float bf2f(unsigned short s) { return __uint_as_float(((unsigned)s) << 16); }

DEVFN unsigned pk2(float a, float b) {  // packed HW cvt (v_cvt_pk_bf16_f32)
  __hip_bfloat162 h = __float22bfloat162_rn(make_float2(a, b));
  return *(unsigned*)&h;
}

DEVFN bf16x8 pack8(float4 a, float4 b) {
  union { unsigned w[4]; bf16x8 v; } u;
  u.w[0] = pk2(a.x, a.y); u.w[1] = pk2(a.z, a.w);
  u.w[2] = pk2(b.x, b.y); u.w[3] = pk2(b.z, b.w);
  return u.v;
}

DEVFN float ex2(float x) {  // 2^x
#if __has_builtin(__builtin_amdgcn_exp2f)
  return __builtin_amdgcn_exp2f(x);
#else
  return __expf(x * 0.6931471805599453f);
#endif
}

DEVFN float gelu_t(float u) {  // tanh-form GELU (|err| <= ~3e-3 vs exact)
  const float y = 0.7978845608028654f * (u + 0.044715f * u * u * u);
  const float e = __expf(2.f * y);
  return 0.5f * u * (2.f - 2.f / (e + 1.f));
}

// ---------------------------------------------------------------------------
// Weight pre-transpose: fp32 W[K][N] -> bf16 WT[N][K]; 32x32 tiles via LDS.
// ---------------------------------------------------------------------------
__global__ __launch_bounds__(256) void k_wt(
    const float* fw, const float* wq, const float* wk, const float* wv,
    const float* wo, const float* w1, const float* w2,
    unsigned short* fwT, unsigned short* wqT, unsigned short* wkT,
    unsigned short* wvT, unsigned short* woT, unsigned short* w1T,
    unsigned short* w2T) {
  __shared__ unsigned short tile[32][36];
  const int bid = blockIdx.x;
  const float* src; unsigned short* dst; int K, N, t;
  if (bid < 192)      { src = fw; dst = fwT; K = 768;  N = 256;  t = bid; }
  else if (bid < 256) { src = wq; dst = wqT; K = 256;  N = 256;  t = bid - 192; }
  else if (bid < 320) { src = wk; dst = wkT; K = 256;  N = 256;  t = bid - 256; }
  else if (bid < 384) { src = wv; dst = wvT; K = 256;  N = 256;  t = bid - 320; }
  else if (bid < 448) { src = wo; dst = woT; K = 256;  N = 256;  t = bid - 384; }
  else if (bid < 704) { src = w1; dst = w1T; K = 256;  N = 1024; t = bid - 448; }
  else                { src = w2; dst = w2T; K = 1024; N = 256;  t = bid - 704; }
  const int nkt = K >> 5;
  const int k0 = (t % nkt) * 32, n0 = (t / nkt) * 32;
  const int i = threadIdx.x >> 3, j4 = threadIdx.x & 7;
  const float4 v = *(const float4*)(src + (size_t)(k0 + i) * N + n0 + j4 * 4);
  *(uint2*)&tile[i][j4 * 4] = make_uint2(pk2(v.x, v.y), pk2(v.z, v.w));
  __syncthreads();
  unsigned o0 = tile[j4 * 4 + 0][i], o1 = tile[j4 * 4 + 1][i];
  unsigned o2 = tile[j4 * 4 + 2][i], o3 = tile[j4 * 4 + 3][i];
  *(uint2*)(dst + (size_t)(n0 + i) * K + k0 + j4 * 4) =
      make_uint2(o0 | (o1 << 16), o2 | (o3 << 16));
}

// ---------------------------------------------------------------------------
// MFMA GEMM: C[M][N] = Ab[M][K](bf16) @ WT[N][K]^T(bf16) + bias.
// Dual accumulator: two independent MFMA chains (K split even/odd 16-steps).
// ---------------------------------------------------------------------------
template <int K, int OUTBF, int ACT>
__global__ __launch_bounds__(64) void k_gemm_m(const unsigned short* __restrict__ Ab,
                                               const unsigned short* __restrict__ WT,
                                               const float* __restrict__ bias,
                                               void* __restrict__ Cout, int N) {
  const int lane = threadIdx.x;
  const int lc = lane & 31, hi = lane >> 5;
  const int m0 = blockIdx.x * 32, n0 = blockIdx.y * 32;
  const unsigned short* ap = Ab + (size_t)(m0 + lc) * K + hi * 8;
  const unsigned short* bp = WT + (size_t)(n0 + lc) * K + hi * 8;
  f32x16 acc0 = {0.f,0.f,0.f,0.f,0.f,0.f,0.f,0.f,0.f,0.f,0.f,0.f,0.f,0.f,0.f,0.f};
  f32x16 acc1 = acc0;
#pragma unroll 4
  for (int k0 = 0; k0 < K; k0 += 32) {
    bf16x8 a0 = *(const bf16x8*)(ap + k0);
    bf16x8 b0 = *(const bf16x8*)(bp + k0);
    bf16x8 a1 = *(const bf16x8*)(ap + k0 + 16);
    bf16x8 b1 = *(const bf16x8*)(bp + k0 + 16);
    acc0 = __builtin_amdgcn_mfma_f32_32x32x16_bf16(a0, b0, acc0, 0, 0, 0);
    acc1 = __builtin_amdgcn_mfma_f32_32x32x16_bf16(a1, b1, acc1, 0, 0, 0);
  }
  const float bv = bias[n0 + lc];
#pragma unroll
  for (int r = 0; r < 16; ++r) {
    const int row = (r & 3) + 8 * (r >> 2) + 4 * hi;
    float v = acc0[r] + acc1[r] + bv;
    if (ACT == 1) v = gelu_t(v);
    if (OUTBF) ((unsigned short*)Cout)[(size_t)(m0 + row) * N + n0 + lc] = f2bf(v);
    else       ((float*)Cout)[(size_t)(m0 + row) * N + n0 + lc] = v;
  }
}

// QKV: grid (S/32, 24); sel = by>>3 picks {wq,bq,qb}/{wk,bk,kb}/{wv,bv,vb}.
// Q pre-scaled by log2(e)/sqrt(dh) (exp2-domain softmax downstream).
__global__ __launch_bounds__(64) void k_gemm_qkv(const unsigned short* __restrict__ Ab,
                                                 const unsigned short* __restrict__ wqkvT,
                                                 const float* __restrict__ bq,
                                                 const float* __restrict__ bk,
                                                 const float* __restrict__ bv,
                                                 unsigned short* __restrict__ qb,
                                                 unsigned short* __restrict__ kb,
                                                 unsigned short* __restrict__ vb) {
  const int lane = threadIdx.x;
  const int lc = lane & 31, hi = lane >> 5;
  const int m0 = blockIdx.x * 32;
  const int sel = blockIdx.y >> 3, n0 = (blockIdx.y & 7) * 32;
  const unsigned short* WT = wqkvT + (size_t)sel * 256 * 256;
  const float* bias = sel == 0 ? bq : sel == 1 ? bk : bv;
  unsigned short* out = sel == 0 ? qb : sel == 1 ? kb : vb;
  const float oscale = sel == 0 ? 0.25505889254f : 1.f;  // (1/sqrt(32))*log2(e)
  const unsigned short* ap = Ab + (size_t)(m0 + lc) * 256 + hi * 8;
  const unsigned short* bp = WT + (size_t)(n0 + lc) * 256 + hi * 8;
  f32x16 acc0 = {0.f,0.f,0.f,0.f,0.f,0.f,0.f,0.f,0.f,0.f,0.f,0.f,0.f,0.f,0.f,0.f};
  f32x16 acc1 = acc0;
#pragma unroll 4
  for (int k0 = 0; k0 < 256; k0 += 32) {
    bf16x8 a0 = *(const bf16x8*)(ap + k0);
    bf16x8 b0 = *(const bf16x8*)(bp + k0);
    bf16x8 a1 = *(const bf16x8*)(ap + k0 + 16);
    bf16x8 b1 = *(const bf16x8*)(bp + k0 + 16);
    acc0 = __builtin_amdgcn_mfma_f32_32x32x16_bf16(a0, b0, acc0, 0, 0, 0);
    acc1 = __builtin_amdgcn_mfma_f32_32x32x16_bf16(a1, b1, acc1, 0, 0, 0);
  }
  const float bvv = bias[n0 + lc];
#pragma unroll
  for (int r = 0; r < 16; ++r) {
    const int row = (r & 3) + 8 * (r >> 2) + 4 * hi;
    out[(size_t)(m0 + row) * 256 + n0 + lc] = f2bf((acc0[r] + acc1[r] + bvv) * oscale);
  }
}

// ---------------------------------------------------------------------------
// Local windowed attention, w=4/8 (16x16x32 MFMA), one window per block.
// ---------------------------------------------------------------------------
template <int W, int THREADS>
__global__ __launch_bounds__(THREADS) void k_local_s(const float* __restrict__ x,
                                                     float* __restrict__ pooled, int nS) {
  constexpr int NT  = W * W;
  constexpr int NCT = NT / 16;
  constexpr int LDE = 264;
  __shared__ unsigned short win[NT][LDE];
  __shared__ float a[NT];
  const int tid = threadIdx.x;
  const int wave = tid >> 6, lane = tid & 63;
  const int lr = lane & 15, lg = lane >> 4;
  const int l = blockIdx.x;
  const int row0 = (l / nS) * (W / 2), col0 = (l % nS) * (W / 2);

  for (int e8 = tid; e8 < NT * 32; e8 += THREADS) {
    const int t = e8 >> 5, c8 = (e8 & 31) * 8;
    const float* src = x + ((size_t)((row0 + t / W) * GRID + col0 + (t % W))) * D + c8;
    *(bf16x8*)&win[t][c8] = pack8(*(const float4*)src, *(const float4*)(src + 4));
  }
  if (tid < NT) a[tid] = 0.f;
  __syncthreads();

  bf16x8 af[8];
#pragma unroll
  for (int k2 = 0; k2 < 8; ++k2)
    af[k2] = *(const bf16x8*)&win[wave * 16 + lr][k2 * 32 + lg * 8];

  float m[4], Z[4], Zi[4];
#pragma unroll
  for (int r = 0; r < 4; ++r) { m[r] = -INFINITY; Z[r] = 0.f; }

  for (int ct = 0; ct < NCT; ++ct) {
    f32x4 Ca = {0.f, 0.f, 0.f, 0.f}, Cb = {0.f, 0.f, 0.f, 0.f};
#pragma unroll
    for (int k2 = 0; k2 < 8; k2 += 2) {
      bf16x8 b0 = *(const bf16x8*)&win[ct * 16 + lr][k2 * 32 + lg * 8];
      bf16x8 b1 = *(const bf16x8*)&win[ct * 16 + lr][(k2 + 1) * 32 + lg * 8];
      Ca = __builtin_amdgcn_mfma_f32_16x16x32_bf16(af[k2], b0, Ca, 0, 0, 0);
      Cb = __builtin_amdgcn_mfma_f32_16x16x32_bf16(af[k2 + 1], b1, Cb, 0, 0, 0);
    }
#pragma unroll
    for (int r = 0; r < 4; ++r) {
      const float sv = (Ca[r] + Cb[r]) * 0.0625f;
      const float nm = fmaxf(m[r], sv);
      Z[r] = Z[r] * __expf(m[r] - nm) + __expf(sv - nm);
      m[r] = nm;
    }
  }
#pragma unroll
  for (int r = 0; r < 4; ++r) {
#pragma unroll
    for (int msk = 1; msk <= 8; msk <<= 1) {
      const float om = __shfl_xor(m[r], msk), oz = __shfl_xor(Z[r], msk);
      const float nm = fmaxf(m[r], om);
      Z[r] = Z[r] * __expf(m[r] - nm) + oz * __expf(om - nm);
      m[r] = nm;
    }
    Zi[r] = 1.f / Z[r];
  }

  for (int ct = 0; ct < NCT; ++ct) {
    f32x4 Ca = {0.f, 0.f, 0.f, 0.f}, Cb = {0.f, 0.f, 0.f, 0.f};
#pragma unroll
    for (int k2 = 0; k2 < 8; k2 += 2) {
      bf16x8 b0 = *(const bf16x8*)&win[ct * 16 + lr][k2 * 32 + lg * 8];
      bf16x8 b1 = *(const bf16x8*)&win[ct * 16 + lr][(k2 + 1) * 32 + lg * 8];
      Ca = __builtin_amdgcn_mfma_f32_16x16x32_bf16(af[k2], b0, Ca, 0, 0, 0);
      Cb = __builtin_amdgcn_mfma_f32_16x16x32_bf16(af[k2 + 1], b1, Cb, 0, 0, 0);
    }
    float cs = 0.f;
#pragma unroll
    for (int r = 0; r < 4; ++r)
      cs += __expf((Ca[r] + Cb[r]) * 0.0625f - m[r]) * Zi[r];
    cs += __shfl_xor(cs, 16);
    cs += __shfl_xor(cs, 32);
    if (lg == 0) atomicAdd(&a[ct * 16 + lr], cs);
  }
  __syncthreads();

  for (int d = tid; d < D; d += THREADS) {
    float acc = 0.f;
#pragma unroll 8
    for (int k = 0; k < NT; ++k) acc += a[k] * bf2f(win[k][d]);
    pooled[(size_t)l * D + d] = acc * (1.f / NT);
  }
}

// ---------------------------------------------------------------------------
// Local windowed attention, w=16 (NT=256), 32x32x16 MFMA, one window/block.
// ---------------------------------------------------------------------------
__global__ __launch_bounds__(256, 1) void k_local16(const float* __restrict__ x,
                                                    float* __restrict__ pooled, int nS) {
  constexpr int LDE = 264;
  __shared__ unsigned short win[256][LDE];
  __shared__ float a[256];
  const int tid = threadIdx.x;
  const int wave = tid >> 6, lane = tid & 63;
  const int lc = lane & 31, hi = lane >> 5;
  const int l = blockIdx.x;
  const int row0 = (l / nS) * 8, col0 = (l % nS) * 8;

  for (int e8 = tid; e8 < 256 * 32; e8 += 256) {
    const int t = e8 >> 5, c8 = (e8 & 31) * 8;
    const float* src = x + ((size_t)((row0 + (t >> 4)) * GRID + col0 + (t & 15))) * D + c8;
    *(bf16x8*)&win[t][c8] = pack8(*(const float4*)src, *(const float4*)(src + 4));
  }
  a[tid] = 0.f;
  __syncthreads();

  float m[2][16], Z[2][16], Zi[2][16];
#pragma unroll
  for (int s = 0; s < 2; ++s)
#pragma unroll
    for (int r = 0; r < 16; ++r) { m[s][r] = -INFINITY; Z[s][r] = 0.f; }

#pragma unroll
  for (int s = 0; s < 2; ++s) {
    const int R0 = (wave * 2 + s) * 32;
    bf16x8 af[16];
#pragma unroll
    for (int k2 = 0; k2 < 16; ++k2)
      af[k2] = *(const bf16x8*)&win[R0 + lc][k2 * 16 + hi * 8];
    for (int ct = 0; ct < 8; ++ct) {
      f32x16 Ca = {0.f,0.f,0.f,0.f,0.f,0.f,0.f,0.f,0.f,0.f,0.f,0.f,0.f,0.f,0.f,0.f};
      f32x16 Cb = Ca;
#pragma unroll
      for (int k2 = 0; k2 < 16; k2 += 2) {
        bf16x8 b0 = *(const bf16x8*)&win[ct * 32 + lc][k2 * 16 + hi * 8];
        bf16x8 b1 = *(const bf16x8*)&win[ct * 32 + lc][(k2 + 1) * 16 + hi * 8];
        Ca = __builtin_amdgcn_mfma_f32_32x32x16_bf16(af[k2], b0, Ca, 0, 0, 0);
        Cb = __builtin_amdgcn_mfma_f32_32x32x16_bf16(af[k2 + 1], b1, Cb, 0, 0, 0);
      }
#pragma unroll
      for (int r = 0; r < 16; ++r) {
        const float sv = (Ca[r] + Cb[r]) * 0.0625f;
        const float nm = fmaxf(m[s][r], sv);
        Z[s][r] = Z[s][r] * __expf(m[s][r] - nm) + __expf(sv - nm);
        m[s][r] = nm;
      }
    }
#pragma unroll
    for (int r = 0; r < 16; ++r) {
#pragma unroll
      for (int msk = 1; msk <= 16; msk <<= 1) {
        const float om = __shfl_xor(m[s][r], msk), oz = __shfl_xor(Z[s][r], msk);
        const float nm = fmaxf(m[s][r], om);
        Z[s][r] = Z[s][r] * __expf(m[s][r] - nm) + oz * __expf(om - nm);
        m[s][r] = nm;
      }
      Zi[s][r] = 1.f / Z[s][r];
    }
  }

#pragma unroll
  for (int s = 0; s < 2; ++s) {
    const int R0 = (wave * 2 + s) * 32;
    bf16x8 af[16];
#pragma unroll
    for (int k2 = 0; k2 < 16; ++k2)
      af[k2] = *(const bf16x8*)&win[R0 + lc][k2 * 16 + hi * 8];
    for (int ct = 0; ct < 8; ++ct) {
      f32x16 Ca = {0.f,0.f,0.f,0.f,0.f,0.f,0.f,0.f,0.f,0.f,0.f,0.f,0.f,0.f,0.f,0.f};
      f32x16 Cb = Ca;
#pragma unroll
      for (int k2 = 0; k2 < 16; k2 += 2) {
        bf16x8 b0 = *(const bf16x8*)&win[ct * 32 + lc][k2 * 16 + hi * 8];
        bf16x8 b1 = *(const bf16x8*)&win[ct * 32 + lc][(k2 + 1) * 16 + hi * 8];
        Ca = __builtin_amdgcn_mfma_f32_32x32x16_bf16(af[k2], b0, Ca, 0, 0, 0);
        Cb = __builtin_amdgcn_mfma_f32_32x32x16_bf16(af[k2 + 1], b1, Cb, 0, 0, 0);
      }
      float cs = 0.f;
#pragma unroll
      for (int r = 0; r < 16; ++r)
        cs += __expf((Ca[r] + Cb[r]) * 0.0625f - m[s][r]) * Zi[s][r];
      cs += __shfl_xor(cs, 32);
      if (hi == 0) atomicAdd(&a[ct * 32 + lc], cs);
    }
  }
  __syncthreads();

  {
    const int d = tid;
    float acc = 0.f;
#pragma unroll 8
    for (int k = 0; k < 256; ++k) acc += a[k] * bf2f(win[k][d]);
    pooled[(size_t)l * D + d] = acc * (1.f / 256.f);
  }
}

// ---------------------------------------------------------------------------
// Overlap-average scatter of pooled windows -> catb[t][768] (bf16)
// ---------------------------------------------------------------------------
DEVFN float gatherp(const float* __restrict__ pooled, int r, int c, int W, int s, int nS, int d) {
  int amin = max(0, (r - W + s) / s), amax = min(nS - 1, r / s);
  int bmin = max(0, (c - W + s) / s), bmax = min(nS - 1, c / s);
  float acc = 0.f;
  int cnt = 0;
  for (int a = amin; a <= amax; ++a)
    for (int b = bmin; b <= bmax; ++b) { acc += pooled[(size_t)(a * nS + b) * D + d]; ++cnt; }
  return acc / (float)cnt;
}

__global__ void k_combine(const float* __restrict__ p0, const float* __restrict__ p1,
                          const float* __restrict__ p2, unsigned short* __restrict__ catb) {
  const int t = blockIdx.x, d = threadIdx.x;
  const int r = t >> 6, c = t & 63;
  unsigned short* o = catb + (size_t)t * 768;
  o[d]       = f2bf(gatherp(p0, r, c, 4, 2, 31, d));
  o[256 + d] = f2bf(gatherp(p1, r, c, 8, 4, 15, d));
  o[512 + d] = f2bf(gatherp(p2, r, c, 16, 8, 7, d));
}

// ---------------------------------------------------------------------------
// Block-wide sum of (a, b) over 256 threads
// ---------------------------------------------------------------------------
DEVFN float2 block_sum2(float a, float b) {
  __shared__ float sb[8];
#pragma unroll
  for (int m = 32; m; m >>= 1) { a += __shfl_xor(a, m); b += __shfl_xor(b, m); }
  const int w = threadIdx.x >> 6;
  __syncthreads();
  if ((threadIdx.x & 63) == 0) { sb[w] = a; sb[4 + w] = b; }
  __syncthreads();
  return make_float2(sb[0] + sb[1] + sb[2] + sb[3], sb[4] + sb[5] + sb[6] + sb[7]);
}

// out = LN(a (+ b)); optional bf16 dual write. In-place safe (out==a).
__global__ __launch_bounds__(256) void k_ln(float* __restrict__ out, unsigned short* __restrict__ outb,
                                            const float* __restrict__ a, const float* __restrict__ b,
                                            const float* __restrict__ g, const float* __restrict__ be) {
  const size_t i = (size_t)blockIdx.x * D + threadIdx.x;
  float v = a[i] + (b ? b[i] : 0.f);
  float2 s = block_sum2(v, v * v);
  float mean = s.x * (1.f / D);
  float var = s.y * (1.f / D) - mean * mean;
  const float r = (v - mean) * rsqrtf(var + 1e-5f) * g[threadIdx.x] + be[threadIdx.x];
  out[i] = r;
  if (outb) outb[i] = f2bf(r);
}

// xl = LN2(x + LN1(t1)); writes fp32 + bf16 (fuses the two post-fuse LNs)
__global__ __launch_bounds__(256) void k_ln_fuse(const float* __restrict__ t1,
                                                 const float* __restrict__ x,
                                                 float* __restrict__ xl,
                                                 unsigned short* __restrict__ xlb,
                                                 const float* __restrict__ fg,
                                                 const float* __restrict__ fbb,
                                                 const float* __restrict__ n1g,
                                                 const float* __restrict__ n1b) {
  const size_t i = (size_t)blockIdx.x * D + threadIdx.x;
  const float v1 = t1[i];
  float2 s1 = block_sum2(v1, v1 * v1);
  const float mean1 = s1.x * (1.f / D);
  const float var1 = s1.y * (1.f / D) - mean1 * mean1;
  const float r1 = (v1 - mean1) * rsqrtf(var1 + 1e-5f) * fg[threadIdx.x] + fbb[threadIdx.x];
  const float v2 = x[i] + r1;
  float2 s2 = block_sum2(v2, v2 * v2);
  const float mean2 = s2.x * (1.f / D);
  const float var2 = s2.y * (1.f / D) - mean2 * mean2;
  const float r2 = (v2 - mean2) * rsqrtf(var2 + 1e-5f) * n1g[threadIdx.x] + n1b[threadIdx.x];
  xl[i] = r2;
  xlb[i] = f2bf(r2);
}

// ---------------------------------------------------------------------------
// MFMA flash attention, split-KV x4: grid (S/64, NH, 4); each block processes
// 1024 keys; exp2-domain softmax (Q pre-scaled by log2e/sqrt(dh)); bf16
// partial O + per-q (m,l). Ping-pong LDS, swapped QK^T, tr-read V, defer-max.
// ---------------------------------------------------------------------------
__global__ __launch_bounds__(256) void k_flash_mfma(const unsigned short* __restrict__ Qg,
                                                    const unsigned short* __restrict__ Kg,
                                                    const unsigned short* __restrict__ Vg,
                                                    unsigned short* __restrict__ po,
                                                    float* __restrict__ pml) {
  const int h = blockIdx.y, z = blockIdx.z;
  const int tid = threadIdx.x;
  const int wave = tid >> 6, lane = tid & 63;
  const int lr = lane & 15, lg = lane >> 4;
  constexpr int NT2 = 16;            // 16 tiles x 64 keys = 1024 keys per slice

  __shared__ unsigned short Kf[2][64][40];
  __shared__ unsigned short VS[2][2048];

  const int q0 = blockIdx.x * 64 + wave * 16;
  const int kbase = z * 1024;

  const bf16x8 qfrag = *(const bf16x8*)(Qg + (size_t)(q0 + lr) * D + h * DH + lg * 8);

  f32x4 o0 = {0.f, 0.f, 0.f, 0.f}, o1 = {0.f, 0.f, 0.f, 0.f};
  float mrow = -INFINITY, lrow = 0.f;

  const unsigned vsbase0 =
      (unsigned)(unsigned long long)(const void*)&VS[0][0] + (unsigned)(lg * 128 + lr * 2);

  const int key = tid >> 2, c8 = (tid & 3) * 8;
  const int vidx = (c8 >> 4) * 1024 + (key >> 2) * 64 + (key & 3) * 16 + (c8 & 15);
  const unsigned short* kp = Kg + (size_t)(kbase + key) * D + h * DH + c8;
  const unsigned short* vp = Vg + (size_t)(kbase + key) * D + h * DH + c8;
  constexpr int KSTEP = 64 * D;

  {
    bf16x8 k0r = *(const bf16x8*)kp;
    bf16x8 v0r = *(const bf16x8*)vp;
    *(bf16x8*)&Kf[0][key][c8] = k0r;
    *(bf16x8*)&VS[0][vidx] = v0r;
  }
  __syncthreads();

  for (int kt = 0; kt < NT2; ++kt) {
    const int cur = kt & 1;
    const int ktn = (kt + 1 < NT2) ? kt + 1 : kt;
    bf16x8 kreg = *(const bf16x8*)(kp + (size_t)ktn * KSTEP);
    bf16x8 vreg = *(const bf16x8*)(vp + (size_t)ktn * KSTEP);

    // swapped QK^T: s[k16][r] = S[q=lr][key = k16*16 + lg*4 + r] (log2 units)
    f32x4 s[4];
    __builtin_amdgcn_s_setprio(1);
#pragma unroll
    for (int k16 = 0; k16 < 4; ++k16) {
      bf16x8 ka = *(const bf16x8*)&Kf[cur][k16 * 16 + lr][lg * 8];
      f32x4 zc = {0.f, 0.f, 0.f, 0.f};
      s[k16] = __builtin_amdgcn_mfma_f32_16x16x32_bf16(ka, qfrag, zc, 0, 0, 0);
    }
    __builtin_amdgcn_s_setprio(0);

    // issue V tr-reads early
    const unsigned vb = vsbase0 + (unsigned)(cur << 12);
    u32x2 tv000, tv001, tv010, tv011, tv100, tv101, tv110, tv111;
    asm volatile("ds_read_b64_tr_b16 %0, %1 offset:0"    : "=v"(tv000) : "v"(vb));
    asm volatile("ds_read_b64_tr_b16 %0, %1 offset:2048" : "=v"(tv001) : "v"(vb));
    asm volatile("ds_read_b64_tr_b16 %0, %1 offset:512"  : "=v"(tv010) : "v"(vb));
    asm volatile("ds_read_b64_tr_b16 %0, %1 offset:2560" : "=v"(tv011) : "v"(vb));
    asm volatile("ds_read_b64_tr_b16 %0, %1 offset:1024" : "=v"(tv100) : "v"(vb));
    asm volatile("ds_read_b64_tr_b16 %0, %1 offset:3072" : "=v"(tv101) : "v"(vb));
    asm volatile("ds_read_b64_tr_b16 %0, %1 offset:1536" : "=v"(tv110) : "v"(vb));
    asm volatile("ds_read_b64_tr_b16 %0, %1 offset:3584" : "=v"(tv111) : "v"(vb));

    // exp2-domain online softmax with defer-max (THR=11 log2-units ~ 8 nats)
    float tm = s[0][0];
#pragma unroll
    for (int k16 = 0; k16 < 4; ++k16)
#pragma unroll
      for (int r = 0; r < 4; ++r) tm = fmaxf(tm, s[k16][r]);
    const bool skip = __all(tm - mrow <= 11.f);
    if (!skip) {
      float tmm = fmaxf(tm, __shfl_xor(tm, 16));
      tmm = fmaxf(tmm, __shfl_xor(tmm, 32));
      const float nm = fmaxf(mrow, tmm);
      const float cfac = ex2(mrow - nm);
      mrow = nm;
      lrow *= cfac;
#pragma unroll
      for (int r = 0; r < 4; ++r) {
        const float cr = __shfl(cfac, lg * 4 + r);
        o0[r] *= cr; o1[r] *= cr;
      }
    }
    float ls = 0.f;
#pragma unroll
    for (int k16 = 0; k16 < 4; ++k16)
#pragma unroll
      for (int r = 0; r < 4; ++r) { s[k16][r] = ex2(s[k16][r] - mrow); ls += s[k16][r]; }
    ls += __shfl_xor(ls, 16);
    ls += __shfl_xor(ls, 32);
    lrow += ls;

    asm volatile("s_waitcnt lgkmcnt(0)" ::: "memory");
    __builtin_amdgcn_sched_barrier(0);

    // PV: a = lane-local P (packed via cvt_pk), b = tr-read V fragments
    union VB { u32x2 u2[2]; bf16x8 b; };
    __builtin_amdgcn_s_setprio(1);
#pragma unroll
    for (int kt2 = 0; kt2 < 2; ++kt2) {
      union { unsigned w[4]; bf16x8 v; } pu;
      pu.w[0] = pk2(s[2 * kt2][0], s[2 * kt2][1]);
      pu.w[1] = pk2(s[2 * kt2][2], s[2 * kt2][3]);
      pu.w[2] = pk2(s[2 * kt2 + 1][0], s[2 * kt2 + 1][1]);
      pu.w[3] = pk2(s[2 * kt2 + 1][2], s[2 * kt2 + 1][3]);
      VB v0f, v1f;
      if (kt2 == 0) { v0f.u2[0] = tv000; v0f.u2[1] = tv010; v1f.u2[0] = tv001; v1f.u2[1] = tv011; }
      else          { v0f.u2[0] = tv100; v0f.u2[1] = tv110; v1f.u2[0] = tv101; v1f.u2[1] = tv111; }
      o0 = __builtin_amdgcn_mfma_f32_16x16x32_bf16(pu.v, v0f.b, o0, 0, 0, 0);
      o1 = __builtin_amdgcn_mfma_f32_16x16x32_bf16(pu.v, v1f.b, o1, 0, 0, 0);
    }
    __builtin_amdgcn_s_setprio(0);

    if (kt + 1 < NT2) {
      *(bf16x8*)&Kf[cur ^ 1][key][c8] = kreg;
      *(bf16x8*)&VS[cur ^ 1][vidx] = vreg;
      __syncthreads();
    }
  }

  // partial outputs (unnormalized, bf16) + per-q (m [log2], l)
#pragma unroll
  for (int r = 0; r < 4; ++r) {
    unsigned short* op = po + (size_t)z * S * D + (size_t)(q0 + lg * 4 + r) * D + h * DH + lr;
    op[0]  = f2bf(o0[r]);
    op[16] = f2bf(o1[r]);
  }
  if (lane < 16) {
    float* mlp = pml + ((size_t)(z * NH + h) * S + q0 + lr) * 2;
    mlp[0] = mrow;
    mlp[1] = lrow;
  }
}

// merge the 4 KV slices: out bf16 t1b[q][d] (m in log2 domain)
__global__ __launch_bounds__(256) void k_fmerge(const unsigned short* __restrict__ po,
                                                const float* __restrict__ pml,
                                                unsigned short* __restrict__ t1b) {
  const int t = blockIdx.x, d = threadIdx.x;
  const int h = d >> 5;
  float m[4], l[4];
  float M = -INFINITY;
#pragma unroll
  for (int z = 0; z < 4; ++z) {
    const float* ml = pml + ((size_t)(z * NH + h) * S + t) * 2;
    m[z] = ml[0]; l[z] = ml[1];
    M = fmaxf(M, m[z]);
  }
  float L = 0.f, acc = 0.f;
#pragma unroll
  for (int z = 0; z < 4; ++z) {
    const float a = ex2(m[z] - M);
    L += l[z] * a;
    acc += bf2f(po[(size_t)z * S * D + (size_t)t * D + d]) * a;
  }
  t1b[(size_t)t * D + d] = f2bf(acc / L);
}

// ---------------------------------------------------------------------------
// Gate helpers
// ---------------------------------------------------------------------------
__global__ __launch_bounds__(256) void k_colmean(const float* __restrict__ xl,
                                                 const float* __restrict__ xg,
                                                 float* __restrict__ gbuf) {
  const int j = threadIdx.x;
  const int t0 = blockIdx.x * 64;
  float s = 0.f;
  for (int t = 0; t < 64; ++t) {
    size_t i = (size_t)(t0 + t) * D + j;
    s += xl[i] + xg[i];
  }
  atomicAdd(&gbuf[j], s * 0.5f);
}

__global__ __launch_bounds__(256) void k_gate(float* __restrict__ gbuf,
                                              const float* __restrict__ gw,
                                              const float* __restrict__ gb) {
  const int j = threadIdx.x;
  const float gm = gbuf[j] * (1.f / (float)S);
  float2 s = block_sum2(gm * gw[2 * j], gm * gw[2 * j + 1]);
  if (j == 0) {
    float g0 = s.x + gb[0], g1 = s.y + gb[1];
    float mx = fmaxf(g0, g1);
    float e0 = __expf(g0 - mx), e1 = __expf(g1 - mx);
    gbuf[256] = e0 / (e0 + e1);
    gbuf[257] = e1 / (e0 + e1);
  }
}

__global__ __launch_bounds__(256) void k_xf(const float* __restrict__ xl,
                                            const float* __restrict__ xg,
                                            const float* __restrict__ gbuf,
                                            float* __restrict__ xf,
                                            unsigned short* __restrict__ xfb) {
  const float alpha = gbuf[256], beta = gbuf[257];
  const size_t i = ((size_t)blockIdx.x * 256 + threadIdx.x) * 4;
  float4 a = *(const float4*)(xg + i);
  float4 b = *(const float4*)(xl + i);
  float4 r;
  r.x = alpha * a.x + beta * b.x;
  r.y = alpha * a.y + beta * b.y;
  r.z = alpha * a.z + beta * b.z;
  r.w = alpha * a.w + beta * b.w;
  *(float4*)(xf + i) = r;
  *(uint2*)(xfb + i) = make_uint2(pk2(r.x, r.y), pk2(r.z, r.w));
}

// ===========================================================================
extern "C" void kernel_launch(void* const* d_in, const int* in_sizes, int n_in,
                              void* d_out, int out_size, void* d_ws, size_t ws_size,
                              hipStream_t stream) {
  const float* x   = (const float*)d_in[0];
  const float* fw  = (const float*)d_in[2];
  const float* fb  = (const float*)d_in[3];
  const float* fg  = (const float*)d_in[4];
  const float* fbb = (const float*)d_in[5];
  const float* wq  = (const float*)d_in[6];
  const float* wk  = (const float*)d_in[7];
  const float* wv  = (const float*)d_in[8];
  const float* bq  = (const float*)d_in[9];
  const float* bk  = (const float*)d_in[10];
  const float* bv  = (const float*)d_in[11];
  const float* wo  = (const float*)d_in[12];
  const float* bo  = (const float*)d_in[13];
  const float* gw  = (const float*)d_in[14];
  const float* gb  = (const float*)d_in[15];
  const float* w1  = (const float*)d_in[16];
  const float* b1  = (const float*)d_in[17];
  const float* w2  = (const float*)d_in[18];
  const float* b2  = (const float*)d_in[19];
  const float* n1g = (const float*)d_in[20];
  const float* n1b = (const float*)d_in[21];
  const float* n2g = (const float*)d_in[22];
  const float* n2b = (const float*)d_in[23];
  const float* n3g = (const float*)d_in[24];
  const float* n3b = (const float*)d_in[25];
  float* out = (float*)d_out;

  // ---- workspace carve (bytes) ----
  char* base = (char*)d_ws;
  size_t off = 0;
  auto carve = [&](size_t bytes) { char* p = base + off; off += (bytes + 255) & ~(size_t)255; return p; };
  float* p0 = (float*)carve(961 * 256 * 4);
  float* p1 = (float*)carve(225 * 256 * 4);
  float* p2 = (float*)carve(49 * 256 * 4);
  unsigned short* fwT = (unsigned short*)carve(256 * 768 * 2);
  unsigned short* wqkvT = (unsigned short*)carve(3 * 256 * 256 * 2);  // q|k|v
  unsigned short* wqT = wqkvT;
  unsigned short* wkT = wqkvT + 256 * 256;
  unsigned short* wvT = wqkvT + 2 * 256 * 256;
  unsigned short* woT = (unsigned short*)carve(256 * 256 * 2);
  unsigned short* w1T = (unsigned short*)carve(1024 * 256 * 2);
  unsigned short* w2T = (unsigned short*)carve(256 * 1024 * 2);
  char* R = carve(8388608);   // catb(6.3MB) -> po(8MB bf16 x4) -> xg(4MB) -> hbuf(8MB)
  unsigned short* catb = (unsigned short*)R;
  unsigned short* po   = (unsigned short*)R;
  float* xg            = (float*)R;
  unsigned short* hbuf = (unsigned short*)R;
  float* pml = (float*)carve(4 * NH * (size_t)S * 2 * 4);
  unsigned short* qb = (unsigned short*)carve((size_t)S * D * 2);
  unsigned short* kb = (unsigned short*)carve((size_t)S * D * 2);
  unsigned short* vb = (unsigned short*)carve((size_t)S * D * 2);
  float* xf            = (float*)qb;             // qb+kb region, dead after flash
  unsigned short* xfb  = vb;                     // vb region, dead after flash
  float* t1  = (float*)carve((size_t)S * D * 4); // fuse out; later ffo
  float* ffo = t1;
  unsigned short* t1b = (unsigned short*)carve((size_t)S * D * 2);
  float* xl  = (float*)carve((size_t)S * D * 4);
  unsigned short* xlb = (unsigned short*)carve((size_t)S * D * 2);
  float* gbuf = (float*)carve(264 * 4);

  hipMemsetAsync(gbuf, 0, 264 * sizeof(float), stream);

  // weight pre-transpose (bf16 WT[N][K]; wq/wk/wv contiguous)
  k_wt<<<dim3(960), dim3(256), 0, stream>>>(fw, wq, wk, wv, wo, w1, w2,
                                            fwT, wqT, wkT, wvT, woT, w1T, w2T);
  // local multi-scale window attention -> pooled per window (MFMA)
  k_local_s<4, 64><<<dim3(961), dim3(64), 0, stream>>>(x, p0, 31);
  k_local_s<8, 256><<<dim3(225), dim3(256), 0, stream>>>(x, p1, 15);
  k_local16<<<dim3(49), dim3(256), 0, stream>>>(x, p2, 7);
  // scatter/avg -> catb[S][768] bf16
  k_combine<<<dim3(S), dim3(256), 0, stream>>>(p0, p1, p2, catb);
  // fuse GEMM + fused LN pair
  k_gemm_m<768, 0, 0><<<dim3(S / 32, 8), dim3(64), 0, stream>>>(catb, fwT, fb, t1, 256);
  k_ln_fuse<<<dim3(S), dim3(256), 0, stream>>>(t1, x, xl, xlb, fg, fbb, n1g, n1b);
  // global MHA (bf16 q/k/v; single QKV dispatch; q pre-scaled w/ log2e)
  k_gemm_qkv<<<dim3(S / 32, 24), dim3(64), 0, stream>>>(xlb, wqkvT, bq, bk, bv, qb, kb, vb);
  k_flash_mfma<<<dim3(S / 64, NH, 4), dim3(256), 0, stream>>>(qb, kb, vb, po, pml);
  k_fmerge<<<dim3(S), dim3(256), 0, stream>>>(po, pml, t1b);
  k_gemm_m<256, 0, 0><<<dim3(S / 32, 8), dim3(64), 0, stream>>>(t1b, woT, bo, xf, 256);
  k_ln<<<dim3(S), dim3(256), 0, stream>>>(xg, nullptr, xl, xf, n2g, n2b);
  // gate
  k_colmean<<<dim3(64), dim3(256), 0, stream>>>(xl, xg, gbuf);
  k_gate<<<dim3(1), dim3(256), 0, stream>>>(gbuf, gw, gb);
  k_xf<<<dim3(S * D / 1024), dim3(256), 0, stream>>>(xl, xg, gbuf, xf, xfb);
  // FFN + final LN
  k_gemm_m<256, 1, 1><<<dim3(S / 32, 32), dim3(64), 0, stream>>>(xfb, w1T, b1, hbuf, 1024);
  k_gemm_m<1024, 0, 0><<<dim3(S / 32, 8), dim3(64), 0, stream>>>(hbuf, w2T, b2, ffo, 256);
  k_ln<<<dim3(S), dim3(256), 0, stream>>>(out, nullptr, xf, ffo, n3g, n3b);
}

// Round 10
// 213.681 us; speedup vs baseline: 6.9906x; 1.0761x over previous
//
#include <hip/hip_runtime.h>
#include <hip/hip_bf16.h>
#include <cstdint>
#include <cstddef>

// ============================================================================
// HierarchicalTransformerBlock: B=1, S=4096 (64x64 grid), D=256, NH=8, dh=32,
// DFF=1024, local windows w = 4,8,16 (stride w/2).
// Round 10: flash deferred per-lane l-reduction (no per-iter shuffles);
// k_local16 split over 2 blocks/window (atomic pooled); GEMM unroll 8.
// ============================================================================

#define DEVFN __device__ __forceinline__

constexpr int S    = 4096;
constexpr int D    = 256;
constexpr int GRID = 64;
constexpr int NH   = 8;
constexpr int DH   = 32;

typedef __attribute__((ext_vector_type(8))) short bf16x8;
typedef __attribute__((ext_vector_type(4))) float f32x4;
typedef __attribute__((ext_vector_type(16))) float f32x16;
typedef __attribute__((ext_vector_type(2))) unsigned int u32x2;

DEVFN float asf(unsigned u) { return __uint_as_float(u); }

DEVFN unsigned short f2bf(float f) {  // round-to-nearest-even bf16
  unsigned u = __float_as_uint(f);
  u += 0x7fffu + ((u >> 16) & 1u);
  return (unsigned short)(u >> 16);
}
DEVFN float bf2f(unsigned short s) { return __uint_as_float(((unsigned)s) << 16); }

DEVFN unsigned pk2(float a, float b) {  // packed HW cvt (v_cvt_pk_bf16_f32)
  __hip_bfloat162 h = __float22bfloat162_rn(make_float2(a, b));
  return *(unsigned*)&h;
}

DEVFN bf16x8 pack8(float4 a, float4 b) {
  union { unsigned w[4]; bf16x8 v; } u;
  u.w[0] = pk2(a.x, a.y); u.w[1] = pk2(a.z, a.w);
  u.w[2] = pk2(b.x, b.y); u.w[3] = pk2(b.z, b.w);
  return u.v;
}

DEVFN float ex2(float x) {  // 2^x
#if __has_builtin(__builtin_amdgcn_exp2f)
  return __builtin_amdgcn_exp2f(x);
#else
  return __expf(x * 0.6931471805599453f);
#endif
}

DEVFN float gelu_t(float u) {  // tanh-form GELU (|err| <= ~3e-3 vs exact)
  const float y = 0.7978845608028654f * (u + 0.044715f * u * u * u);
  const float e = __expf(2.f * y);
  return 0.5f * u * (2.f - 2.f / (e + 1.f));
}

// ---------------------------------------------------------------------------
// Weight pre-transpose: fp32 W[K][N] -> bf16 WT[N][K]; 32x32 tiles via LDS.
// ---------------------------------------------------------------------------
__global__ __launch_bounds__(256) void k_wt(
    const float* fw, const float* wq, const float* wk, const float* wv,
    const float* wo, const float* w1, const float* w2,
    unsigned short* fwT, unsigned short* wqT, unsigned short* wkT,
    unsigned short* wvT, unsigned short* woT, unsigned short* w1T,
    unsigned short* w2T) {
  __shared__ unsigned short tile[32][36];
  const int bid = blockIdx.x;
  const float* src; unsigned short* dst; int K, N, t;
  if (bid < 192)      { src = fw; dst = fwT; K = 768;  N = 256;  t = bid; }
  else if (bid < 256) { src = wq; dst = wqT; K = 256;  N = 256;  t = bid - 192; }
  else if (bid < 320) { src = wk; dst = wkT; K = 256;  N = 256;  t = bid - 256; }
  else if (bid < 384) { src = wv; dst = wvT; K = 256;  N = 256;  t = bid - 320; }
  else if (bid < 448) { src = wo; dst = woT; K = 256;  N = 256;  t = bid - 384; }
  else if (bid < 704) { src = w1; dst = w1T; K = 256;  N = 1024; t = bid - 448; }
  else                { src = w2; dst = w2T; K = 1024; N = 256;  t = bid - 704; }
  const int nkt = K >> 5;
  const int k0 = (t % nkt) * 32, n0 = (t / nkt) * 32;
  const int i = threadIdx.x >> 3, j4 = threadIdx.x & 7;
  const float4 v = *(const float4*)(src + (size_t)(k0 + i) * N + n0 + j4 * 4);
  *(uint2*)&tile[i][j4 * 4] = make_uint2(pk2(v.x, v.y), pk2(v.z, v.w));
  __syncthreads();
  unsigned o0 = tile[j4 * 4 + 0][i], o1 = tile[j4 * 4 + 1][i];
  unsigned o2 = tile[j4 * 4 + 2][i], o3 = tile[j4 * 4 + 3][i];
  *(uint2*)(dst + (size_t)(n0 + i) * K + k0 + j4 * 4) =
      make_uint2(o0 | (o1 << 16), o2 | (o3 << 16));
}

// ---------------------------------------------------------------------------
// MFMA GEMM: C[M][N] = Ab[M][K](bf16) @ WT[N][K]^T(bf16) + bias.
// Dual accumulator, deep unroll (all loads issued early -> MLP).
// ---------------------------------------------------------------------------
template <int K, int OUTBF, int ACT>
__global__ __launch_bounds__(64) void k_gemm_m(const unsigned short* __restrict__ Ab,
                                               const unsigned short* __restrict__ WT,
                                               const float* __restrict__ bias,
                                               void* __restrict__ Cout, int N) {
  const int lane = threadIdx.x;
  const int lc = lane & 31, hi = lane >> 5;
  const int m0 = blockIdx.x * 32, n0 = blockIdx.y * 32;
  const unsigned short* ap = Ab + (size_t)(m0 + lc) * K + hi * 8;
  const unsigned short* bp = WT + (size_t)(n0 + lc) * K + hi * 8;
  f32x16 acc0 = {0.f,0.f,0.f,0.f,0.f,0.f,0.f,0.f,0.f,0.f,0.f,0.f,0.f,0.f,0.f,0.f};
  f32x16 acc1 = acc0;
#pragma unroll 8
  for (int k0 = 0; k0 < K; k0 += 32) {
    bf16x8 a0 = *(const bf16x8*)(ap + k0);
    bf16x8 b0 = *(const bf16x8*)(bp + k0);
    bf16x8 a1 = *(const bf16x8*)(ap + k0 + 16);
    bf16x8 b1 = *(const bf16x8*)(bp + k0 + 16);
    acc0 = __builtin_amdgcn_mfma_f32_32x32x16_bf16(a0, b0, acc0, 0, 0, 0);
    acc1 = __builtin_amdgcn_mfma_f32_32x32x16_bf16(a1, b1, acc1, 0, 0, 0);
  }
  const float bv = bias[n0 + lc];
#pragma unroll
  for (int r = 0; r < 16; ++r) {
    const int row = (r & 3) + 8 * (r >> 2) + 4 * hi;
    float v = acc0[r] + acc1[r] + bv;
    if (ACT == 1) v = gelu_t(v);
    if (OUTBF) ((unsigned short*)Cout)[(size_t)(m0 + row) * N + n0 + lc] = f2bf(v);
    else       ((float*)Cout)[(size_t)(m0 + row) * N + n0 + lc] = v;
  }
}

// QKV: grid (S/32, 24); sel = by>>3 picks {wq,bq,qb}/{wk,bk,kb}/{wv,bv,vb}.
// Q pre-scaled by log2(e)/sqrt(dh) (exp2-domain softmax downstream).
__global__ __launch_bounds__(64) void k_gemm_qkv(const unsigned short* __restrict__ Ab,
                                                 const unsigned short* __restrict__ wqkvT,
                                                 const float* __restrict__ bq,
                                                 const float* __restrict__ bk,
                                                 const float* __restrict__ bv,
                                                 unsigned short* __restrict__ qb,
                                                 unsigned short* __restrict__ kb,
                                                 unsigned short* __restrict__ vb) {
  const int lane = threadIdx.x;
  const int lc = lane & 31, hi = lane >> 5;
  const int m0 = blockIdx.x * 32;
  const int sel = blockIdx.y >> 3, n0 = (blockIdx.y & 7) * 32;
  const unsigned short* WT = wqkvT + (size_t)sel * 256 * 256;
  const float* bias = sel == 0 ? bq : sel == 1 ? bk : bv;
  unsigned short* out = sel == 0 ? qb : sel == 1 ? kb : vb;
  const float oscale = sel == 0 ? 0.25505889254f : 1.f;  // (1/sqrt(32))*log2(e)
  const unsigned short* ap = Ab + (size_t)(m0 + lc) * 256 + hi * 8;
  const unsigned short* bp = WT + (size_t)(n0 + lc) * 256 + hi * 8;
  f32x16 acc0 = {0.f,0.f,0.f,0.f,0.f,0.f,0.f,0.f,0.f,0.f,0.f,0.f,0.f,0.f,0.f,0.f};
  f32x16 acc1 = acc0;
#pragma unroll 8
  for (int k0 = 0; k0 < 256; k0 += 32) {
    bf16x8 a0 = *(const bf16x8*)(ap + k0);
    bf16x8 b0 = *(const bf16x8*)(bp + k0);
    bf16x8 a1 = *(const bf16x8*)(ap + k0 + 16);
    bf16x8 b1 = *(const bf16x8*)(bp + k0 + 16);
    acc0 = __builtin_amdgcn_mfma_f32_32x32x16_bf16(a0, b0, acc0, 0, 0, 0);
    acc1 = __builtin_amdgcn_mfma_f32_32x32x16_bf16(a1, b1, acc1, 0, 0, 0);
  }
  const float bvv = bias[n0 + lc];
#pragma unroll
  for (int r = 0; r < 16; ++r) {
    const int row = (r & 3) + 8 * (r >> 2) + 4 * hi;
    out[(size_t)(m0 + row) * 256 + n0 + lc] = f2bf((acc0[r] + acc1[r] + bvv) * oscale);
  }
}

// ---------------------------------------------------------------------------
// Local windowed attention, w=4/8 (16x16x32 MFMA), one window per block.
// ---------------------------------------------------------------------------
template <int W, int THREADS>
__global__ __launch_bounds__(THREADS) void k_local_s(const float* __restrict__ x,
                                                     float* __restrict__ pooled, int nS) {
  constexpr int NT  = W * W;
  constexpr int NCT = NT / 16;
  constexpr int LDE = 264;
  __shared__ unsigned short win[NT][LDE];
  __shared__ float a[NT];
  const int tid = threadIdx.x;
  const int wave = tid >> 6, lane = tid & 63;
  const int lr = lane & 15, lg = lane >> 4;
  const int l = blockIdx.x;
  const int row0 = (l / nS) * (W / 2), col0 = (l % nS) * (W / 2);

  for (int e8 = tid; e8 < NT * 32; e8 += THREADS) {
    const int t = e8 >> 5, c8 = (e8 & 31) * 8;
    const float* src = x + ((size_t)((row0 + t / W) * GRID + col0 + (t % W))) * D + c8;
    *(bf16x8*)&win[t][c8] = pack8(*(const float4*)src, *(const float4*)(src + 4));
  }
  if (tid < NT) a[tid] = 0.f;
  __syncthreads();

  bf16x8 af[8];
#pragma unroll
  for (int k2 = 0; k2 < 8; ++k2)
    af[k2] = *(const bf16x8*)&win[wave * 16 + lr][k2 * 32 + lg * 8];

  float m[4], Z[4], Zi[4];
#pragma unroll
  for (int r = 0; r < 4; ++r) { m[r] = -INFINITY; Z[r] = 0.f; }

  for (int ct = 0; ct < NCT; ++ct) {
    f32x4 Ca = {0.f, 0.f, 0.f, 0.f}, Cb = {0.f, 0.f, 0.f, 0.f};
#pragma unroll
    for (int k2 = 0; k2 < 8; k2 += 2) {
      bf16x8 b0 = *(const bf16x8*)&win[ct * 16 + lr][k2 * 32 + lg * 8];
      bf16x8 b1 = *(const bf16x8*)&win[ct * 16 + lr][(k2 + 1) * 32 + lg * 8];
      Ca = __builtin_amdgcn_mfma_f32_16x16x32_bf16(af[k2], b0, Ca, 0, 0, 0);
      Cb = __builtin_amdgcn_mfma_f32_16x16x32_bf16(af[k2 + 1], b1, Cb, 0, 0, 0);
    }
#pragma unroll
    for (int r = 0; r < 4; ++r) {
      const float sv = (Ca[r] + Cb[r]) * 0.0625f;
      const float nm = fmaxf(m[r], sv);
      Z[r] = Z[r] * __expf(m[r] - nm) + __expf(sv - nm);
      m[r] = nm;
    }
  }
#pragma unroll
  for (int r = 0; r < 4; ++r) {
#pragma unroll
    for (int msk = 1; msk <= 8; msk <<= 1) {
      const float om = __shfl_xor(m[r], msk), oz = __shfl_xor(Z[r], msk);
      const float nm = fmaxf(m[r], om);
      Z[r] = Z[r] * __expf(m[r] - nm) + oz * __expf(om - nm);
      m[r] = nm;
    }
    Zi[r] = 1.f / Z[r];
  }

  for (int ct = 0; ct < NCT; ++ct) {
    f32x4 Ca = {0.f, 0.f, 0.f, 0.f}, Cb = {0.f, 0.f, 0.f, 0.f};
#pragma unroll
    for (int k2 = 0; k2 < 8; k2 += 2) {
      bf16x8 b0 = *(const bf16x8*)&win[ct * 16 + lr][k2 * 32 + lg * 8];
      bf16x8 b1 = *(const bf16x8*)&win[ct * 16 + lr][(k2 + 1) * 32 + lg * 8];
      Ca = __builtin_amdgcn_mfma_f32_16x16x32_bf16(af[k2], b0, Ca, 0, 0, 0);
      Cb = __builtin_amdgcn_mfma_f32_16x16x32_bf16(af[k2 + 1], b1, Cb, 0, 0, 0);
    }
    float cs = 0.f;
#pragma unroll
    for (int r = 0; r < 4; ++r)
      cs += __expf((Ca[r] + Cb[r]) * 0.0625f - m[r]) * Zi[r];
    cs += __shfl_xor(cs, 16);
    cs += __shfl_xor(cs, 32);
    if (lg == 0) atomicAdd(&a[ct * 16 + lr], cs);
  }
  __syncthreads();

  for (int d = tid; d < D; d += THREADS) {
    float acc = 0.f;
#pragma unroll 8
    for (int k = 0; k < NT; ++k) acc += a[k] * bf2f(win[k][d]);
    pooled[(size_t)l * D + d] = acc * (1.f / NT);
  }
}

// ---------------------------------------------------------------------------
// Local windowed attention, w=16 (NT=256), 32x32x16 MFMA.
// Split: grid (49, 2); block z computes q-strips z*4+wave (4 of 8), partial
// column-sums a[k], partial pooled accumulated via global atomicAdd.
// ---------------------------------------------------------------------------
__global__ __launch_bounds__(256, 1) void k_local16(const float* __restrict__ x,
                                                    float* __restrict__ pooled, int nS) {
  constexpr int LDE = 264;
  __shared__ unsigned short win[256][LDE];
  __shared__ float a[256];
  const int tid = threadIdx.x;
  const int wave = tid >> 6, lane = tid & 63;
  const int lc = lane & 31, hi = lane >> 5;
  const int l = blockIdx.x, z = blockIdx.y;
  const int row0 = (l / nS) * 8, col0 = (l % nS) * 8;

  for (int e8 = tid; e8 < 256 * 32; e8 += 256) {
    const int t = e8 >> 5, c8 = (e8 & 31) * 8;
    const float* src = x + ((size_t)((row0 + (t >> 4)) * GRID + col0 + (t & 15))) * D + c8;
    *(bf16x8*)&win[t][c8] = pack8(*(const float4*)src, *(const float4*)(src + 4));
  }
  a[tid] = 0.f;
  __syncthreads();

  const int R0 = (z * 4 + wave) * 32;  // this wave's q-strip
  bf16x8 af[16];
#pragma unroll
  for (int k2 = 0; k2 < 16; ++k2)
    af[k2] = *(const bf16x8*)&win[R0 + lc][k2 * 16 + hi * 8];

  float m[16], Z[16], Zi[16];
#pragma unroll
  for (int r = 0; r < 16; ++r) { m[r] = -INFINITY; Z[r] = 0.f; }

  // pass A: stats
  for (int ct = 0; ct < 8; ++ct) {
    f32x16 Ca = {0.f,0.f,0.f,0.f,0.f,0.f,0.f,0.f,0.f,0.f,0.f,0.f,0.f,0.f,0.f,0.f};
    f32x16 Cb = Ca;
#pragma unroll
    for (int k2 = 0; k2 < 16; k2 += 2) {
      bf16x8 b0 = *(const bf16x8*)&win[ct * 32 + lc][k2 * 16 + hi * 8];
      bf16x8 b1 = *(const bf16x8*)&win[ct * 32 + lc][(k2 + 1) * 16 + hi * 8];
      Ca = __builtin_amdgcn_mfma_f32_32x32x16_bf16(af[k2], b0, Ca, 0, 0, 0);
      Cb = __builtin_amdgcn_mfma_f32_32x32x16_bf16(af[k2 + 1], b1, Cb, 0, 0, 0);
    }
#pragma unroll
    for (int r = 0; r < 16; ++r) {
      const float sv = (Ca[r] + Cb[r]) * 0.0625f;
      const float nm = fmaxf(m[r], sv);
      Z[r] = Z[r] * __expf(m[r] - nm) + __expf(sv - nm);
      m[r] = nm;
    }
  }
#pragma unroll
  for (int r = 0; r < 16; ++r) {
#pragma unroll
    for (int msk = 1; msk <= 16; msk <<= 1) {
      const float om = __shfl_xor(m[r], msk), oz = __shfl_xor(Z[r], msk);
      const float nm = fmaxf(m[r], om);
      Z[r] = Z[r] * __expf(m[r] - nm) + oz * __expf(om - nm);
      m[r] = nm;
    }
    Zi[r] = 1.f / Z[r];
  }

  // pass B: partial column sums (over this block's 128 q-rows)
  for (int ct = 0; ct < 8; ++ct) {
    f32x16 Ca = {0.f,0.f,0.f,0.f,0.f,0.f,0.f,0.f,0.f,0.f,0.f,0.f,0.f,0.f,0.f,0.f};
    f32x16 Cb = Ca;
#pragma unroll
    for (int k2 = 0; k2 < 16; k2 += 2) {
      bf16x8 b0 = *(const bf16x8*)&win[ct * 32 + lc][k2 * 16 + hi * 8];
      bf16x8 b1 = *(const bf16x8*)&win[ct * 32 + lc][(k2 + 1) * 16 + hi * 8];
      Ca = __builtin_amdgcn_mfma_f32_32x32x16_bf16(af[k2], b0, Ca, 0, 0, 0);
      Cb = __builtin_amdgcn_mfma_f32_32x32x16_bf16(af[k2 + 1], b1, Cb, 0, 0, 0);
    }
    float cs = 0.f;
#pragma unroll
    for (int r = 0; r < 16; ++r)
      cs += __expf((Ca[r] + Cb[r]) * 0.0625f - m[r]) * Zi[r];
    cs += __shfl_xor(cs, 32);
    if (hi == 0) atomicAdd(&a[ct * 32 + lc], cs);
  }
  __syncthreads();

  // partial pooled -> global atomic accumulate
  {
    const int d = tid;
    float acc = 0.f;
#pragma unroll 8
    for (int k = 0; k < 256; ++k) acc += a[k] * bf2f(win[k][d]);
    atomicAdd(&pooled[(size_t)l * D + d], acc * (1.f / 256.f));
  }
}

// ---------------------------------------------------------------------------
// Overlap-average scatter of pooled windows -> catb[t][768] (bf16)
// ---------------------------------------------------------------------------
DEVFN float gatherp(const float* __restrict__ pooled, int r, int c, int W, int s, int nS, int d) {
  int amin = max(0, (r - W + s) / s), amax = min(nS - 1, r / s);
  int bmin = max(0, (c - W + s) / s), bmax = min(nS - 1, c / s);
  float acc = 0.f;
  int cnt = 0;
  for (int a = amin; a <= amax; ++a)
    for (int b = bmin; b <= bmax; ++b) { acc += pooled[(size_t)(a * nS + b) * D + d]; ++cnt; }
  return acc / (float)cnt;
}

__global__ void k_combine(const float* __restrict__ p0, const float* __restrict__ p1,
                          const float* __restrict__ p2, unsigned short* __restrict__ catb) {
  const int t = blockIdx.x, d = threadIdx.x;
  const int r = t >> 6, c = t & 63;
  unsigned short* o = catb + (size_t)t * 768;
  o[d]       = f2bf(gatherp(p0, r, c, 4, 2, 31, d));
  o[256 + d] = f2bf(gatherp(p1, r, c, 8, 4, 15, d));
  o[512 + d] = f2bf(gatherp(p2, r, c, 16, 8, 7, d));
}

// ---------------------------------------------------------------------------
// Block-wide sum of (a, b) over 256 threads
// ---------------------------------------------------------------------------
DEVFN float2 block_sum2(float a, float b) {
  __shared__ float sb[8];
#pragma unroll
  for (int m = 32; m; m >>= 1) { a += __shfl_xor(a, m); b += __shfl_xor(b, m); }
  const int w = threadIdx.x >> 6;
  __syncthreads();
  if ((threadIdx.x & 63) == 0) { sb[w] = a; sb[4 + w] = b; }
  __syncthreads();
  return make_float2(sb[0] + sb[1] + sb[2] + sb[3], sb[4] + sb[5] + sb[6] + sb[7]);
}

// out = LN(a (+ b)); optional bf16 dual write. In-place safe (out==a).
__global__ __launch_bounds__(256) void k_ln(float* __restrict__ out, unsigned short* __restrict__ outb,
                                            const float* __restrict__ a, const float* __restrict__ b,
                                            const float* __restrict__ g, const float* __restrict__ be) {
  const size_t i = (size_t)blockIdx.x * D + threadIdx.x;
  float v = a[i] + (b ? b[i] : 0.f);
  float2 s = block_sum2(v, v * v);
  float mean = s.x * (1.f / D);
  float var = s.y * (1.f / D) - mean * mean;
  const float r = (v - mean) * rsqrtf(var + 1e-5f) * g[threadIdx.x] + be[threadIdx.x];
  out[i] = r;
  if (outb) outb[i] = f2bf(r);
}

// xl = LN2(x + LN1(t1)); writes fp32 + bf16 (fuses the two post-fuse LNs)
__global__ __launch_bounds__(256) void k_ln_fuse(const float* __restrict__ t1,
                                                 const float* __restrict__ x,
                                                 float* __restrict__ xl,
                                                 unsigned short* __restrict__ xlb,
                                                 const float* __restrict__ fg,
                                                 const float* __restrict__ fbb,
                                                 const float* __restrict__ n1g,
                                                 const float* __restrict__ n1b) {
  const size_t i = (size_t)blockIdx.x * D + threadIdx.x;
  const float v1 = t1[i];
  float2 s1 = block_sum2(v1, v1 * v1);
  const float mean1 = s1.x * (1.f / D);
  const float var1 = s1.y * (1.f / D) - mean1 * mean1;
  const float r1 = (v1 - mean1) * rsqrtf(var1 + 1e-5f) * fg[threadIdx.x] + fbb[threadIdx.x];
  const float v2 = x[i] + r1;
  float2 s2 = block_sum2(v2, v2 * v2);
  const float mean2 = s2.x * (1.f / D);
  const float var2 = s2.y * (1.f / D) - mean2 * mean2;
  const float r2 = (v2 - mean2) * rsqrtf(var2 + 1e-5f) * n1g[threadIdx.x] + n1b[threadIdx.x];
  xl[i] = r2;
  xlb[i] = f2bf(r2);
}

// ---------------------------------------------------------------------------
// MFMA flash attention, split-KV x4: grid (S/64, NH, 4); each block processes
// 1024 keys; exp2-domain softmax (Q pre-scaled by log2e/sqrt(dh)); bf16
// partial O + per-q (m,l). Ping-pong LDS, swapped QK^T, tr-read V, defer-max,
// deferred per-lane l-accumulation (single cross-lane reduce at the end).
// ---------------------------------------------------------------------------
__global__ __launch_bounds__(256) void k_flash_mfma(const unsigned short* __restrict__ Qg,
                                                    const unsigned short* __restrict__ Kg,
                                                    const unsigned short* __restrict__ Vg,
                                                    unsigned short* __restrict__ po,
                                                    float* __restrict__ pml) {
  const int h = blockIdx.y, z = blockIdx.z;
  const int tid = threadIdx.x;
  const int wave = tid >> 6, lane = tid & 63;
  const int lr = lane & 15, lg = lane >> 4;
  constexpr int NT2 = 16;            // 16 tiles x 64 keys = 1024 keys per slice

  __shared__ unsigned short Kf[2][64][40];
  __shared__ unsigned short VS[2][2048];

  const int q0 = blockIdx.x * 64 + wave * 16;
  const int kbase = z * 1024;

  const bf16x8 qfrag = *(const bf16x8*)(Qg + (size_t)(q0 + lr) * D + h * DH + lg * 8);

  f32x4 o0 = {0.f, 0.f, 0.f, 0.f}, o1 = {0.f, 0.f, 0.f, 0.f};
  float mrow = -INFINITY, lrow = 0.f;  // lrow = per-lane partial until epilogue

  const unsigned vsbase0 =
      (unsigned)(unsigned long long)(const void*)&VS[0][0] + (unsigned)(lg * 128 + lr * 2);

  const int key = tid >> 2, c8 = (tid & 3) * 8;
  const int vidx = (c8 >> 4) * 1024 + (key >> 2) * 64 + (key & 3) * 16 + (c8 & 15);
  const unsigned short* kp = Kg + (size_t)(kbase + key) * D + h * DH + c8;
  const unsigned short* vp = Vg + (size_t)(kbase + key) * D + h * DH + c8;
  constexpr int KSTEP = 64 * D;

  {
    bf16x8 k0r = *(const bf16x8*)kp;
    bf16x8 v0r = *(const bf16x8*)vp;
    *(bf16x8*)&Kf[0][key][c8] = k0r;
    *(bf16x8*)&VS[0][vidx] = v0r;
  }
  __syncthreads();

  for (int kt = 0; kt < NT2; ++kt) {
    const int cur = kt & 1;
    const int ktn = (kt + 1 < NT2) ? kt + 1 : kt;
    bf16x8 kreg = *(const bf16x8*)(kp + (size_t)ktn * KSTEP);
    bf16x8 vreg = *(const bf16x8*)(vp + (size_t)ktn * KSTEP);

    // swapped QK^T: s[k16][r] = S[q=lr][key = k16*16 + lg*4 + r] (log2 units)
    f32x4 s[4];
    __builtin_amdgcn_s_setprio(1);
#pragma unroll
    for (int k16 = 0; k16 < 4; ++k16) {
      bf16x8 ka = *(const bf16x8*)&Kf[cur][k16 * 16 + lr][lg * 8];
      f32x4 zc = {0.f, 0.f, 0.f, 0.f};
      s[k16] = __builtin_amdgcn_mfma_f32_16x16x32_bf16(ka, qfrag, zc, 0, 0, 0);
    }
    __builtin_amdgcn_s_setprio(0);

    // issue V tr-reads early
    const unsigned vb = vsbase0 + (unsigned)(cur << 12);
    u32x2 tv000, tv001, tv010, tv011, tv100, tv101, tv110, tv111;
    asm volatile("ds_read_b64_tr_b16 %0, %1 offset:0"    : "=v"(tv000) : "v"(vb));
    asm volatile("ds_read_b64_tr_b16 %0, %1 offset:2048" : "=v"(tv001) : "v"(vb));
    asm volatile("ds_read_b64_tr_b16 %0, %1 offset:512"  : "=v"(tv010) : "v"(vb));
    asm volatile("ds_read_b64_tr_b16 %0, %1 offset:2560" : "=v"(tv011) : "v"(vb));
    asm volatile("ds_read_b64_tr_b16 %0, %1 offset:1024" : "=v"(tv100) : "v"(vb));
    asm volatile("ds_read_b64_tr_b16 %0, %1 offset:3072" : "=v"(tv101) : "v"(vb));
    asm volatile("ds_read_b64_tr_b16 %0, %1 offset:1536" : "=v"(tv110) : "v"(vb));
    asm volatile("ds_read_b64_tr_b16 %0, %1 offset:3584" : "=v"(tv111) : "v"(vb));

    // exp2-domain online softmax with defer-max (THR=11 log2-units ~ 8 nats)
    float tm = fmaxf(fmaxf(fmaxf(s[0][0], s[0][1]), fmaxf(s[0][2], s[0][3])),
                     fmaxf(fmaxf(s[1][0], s[1][1]), fmaxf(s[1][2], s[1][3])));
    tm = fmaxf(tm, fmaxf(fmaxf(fmaxf(s[2][0], s[2][1]), fmaxf(s[2][2], s[2][3])),
                         fmaxf(fmaxf(s[3][0], s[3][1]), fmaxf(s[3][2], s[3][3]))));
    const bool skip = __all(tm - mrow <= 11.f);
    if (!skip) {
      float tmm = fmaxf(tm, __shfl_xor(tm, 16));
      tmm = fmaxf(tmm, __shfl_xor(tmm, 32));
      const float nm = fmaxf(mrow, tmm);
      const float cfac = ex2(mrow - nm);   // wave-uniform among same-lr lanes
      mrow = nm;
      lrow *= cfac;                        // per-lane partial scales identically
#pragma unroll
      for (int r = 0; r < 4; ++r) {
        const float cr = __shfl(cfac, lg * 4 + r);
        o0[r] *= cr; o1[r] *= cr;
      }
    }
#pragma unroll
    for (int k16 = 0; k16 < 4; ++k16)
#pragma unroll
      for (int r = 0; r < 4; ++r) { s[k16][r] = ex2(s[k16][r] - mrow); lrow += s[k16][r]; }

    asm volatile("s_waitcnt lgkmcnt(0)" ::: "memory");
    __builtin_amdgcn_sched_barrier(0);

    // PV: a = lane-local P (packed via cvt_pk), b = tr-read V fragments
    union VB { u32x2 u2[2]; bf16x8 b; };
    __builtin_amdgcn_s_setprio(1);
#pragma unroll
    for (int kt2 = 0; kt2 < 2; ++kt2) {
      union { unsigned w[4]; bf16x8 v; } pu;
      pu.w[0] = pk2(s[2 * kt2][0], s[2 * kt2][1]);
      pu.w[1] = pk2(s[2 * kt2][2], s[2 * kt2][3]);
      pu.w[2] = pk2(s[2 * kt2 + 1][0], s[2 * kt2 + 1][1]);
      pu.w[3] = pk2(s[2 * kt2 + 1][2], s[2 * kt2 + 1][3]);
      VB v0f, v1f;
      if (kt2 == 0) { v0f.u2[0] = tv000; v0f.u2[1] = tv010; v1f.u2[0] = tv001; v1f.u2[1] = tv011; }
      else          { v0f.u2[0] = tv100; v0f.u2[1] = tv110; v1f.u2[0] = tv101; v1f.u2[1] = tv111; }
      o0 = __builtin_amdgcn_mfma_f32_16x16x32_bf16(pu.v, v0f.b, o0, 0, 0, 0);
      o1 = __builtin_amdgcn_mfma_f32_16x16x32_bf16(pu.v, v1f.b, o1, 0, 0, 0);
    }
    __builtin_amdgcn_s_setprio(0);

    if (kt + 1 < NT2) {
      *(bf16x8*)&Kf[cur ^ 1][key][c8] = kreg;
      *(bf16x8*)&VS[cur ^ 1][vidx] = vreg;
      __syncthreads();
    }
  }

  // single cross-lane l reduction (deferred from the loop)
  lrow += __shfl_xor(lrow, 16);
  lrow += __shfl_xor(lrow, 32);

  // partial outputs (unnormalized, bf16) + per-q (m [log2], l)
#pragma unroll
  for (int r = 0; r < 4; ++r) {
    unsigned short* op = po + (size_t)z * S * D + (size_t)(q0 + lg * 4 + r) * D + h * DH + lr;
    op[0]  = f2bf(o0[r]);
    op[16] = f2bf(o1[r]);
  }
  if (lane < 16) {
    float* mlp = pml + ((size_t)(z * NH + h) * S + q0 + lr) * 2;
    mlp[0] = mrow;
    mlp[1] = lrow;
  }
}

// merge the 4 KV slices: out bf16 t1b[q][d] (m in log2 domain)
__global__ __launch_bounds__(256) void k_fmerge(const unsigned short* __restrict__ po,
                                                const float* __restrict__ pml,
                                                unsigned short* __restrict__ t1b) {
  const int t = blockIdx.x, d = threadIdx.x;
  const int h = d >> 5;
  float m[4], l[4];
  float M = -INFINITY;
#pragma unroll
  for (int z = 0; z < 4; ++z) {
    const float* ml = pml + ((size_t)(z * NH + h) * S + t) * 2;
    m[z] = ml[0]; l[z] = ml[1];
    M = fmaxf(M, m[z]);
  }
  float L = 0.f, acc = 0.f;
#pragma unroll
  for (int z = 0; z < 4; ++z) {
    const float a = ex2(m[z] - M);
    L += l[z] * a;
    acc += bf2f(po[(size_t)z * S * D + (size_t)t * D + d]) * a;
  }
  t1b[(size_t)t * D + d] = f2bf(acc / L);
}

// ---------------------------------------------------------------------------
// Gate helpers
// ---------------------------------------------------------------------------
__global__ __launch_bounds__(256) void k_colmean(const float* __restrict__ xl,
                                                 const float* __restrict__ xg,
                                                 float* __restrict__ gbuf) {
  const int j = threadIdx.x;
  const int t0 = blockIdx.x * 64;
  float s = 0.f;
  for (int t = 0; t < 64; ++t) {
    size_t i = (size_t)(t0 + t) * D + j;
    s += xl[i] + xg[i];
  }
  atomicAdd(&gbuf[j], s * 0.5f);
}

__global__ __launch_bounds__(256) void k_gate(float* __restrict__ gbuf,
                                              const float* __restrict__ gw,
                                              const float* __restrict__ gb) {
  const int j = threadIdx.x;
  const float gm = gbuf[j] * (1.f / (float)S);
  float2 s = block_sum2(gm * gw[2 * j], gm * gw[2 * j + 1]);
  if (j == 0) {
    float g0 = s.x + gb[0], g1 = s.y + gb[1];
    float mx = fmaxf(g0, g1);
    float e0 = __expf(g0 - mx), e1 = __expf(g1 - mx);
    gbuf[256] = e0 / (e0 + e1);
    gbuf[257] = e1 / (e0 + e1);
  }
}

__global__ __launch_bounds__(256) void k_xf(const float* __restrict__ xl,
                                            const float* __restrict__ xg,
                                            const float* __restrict__ gbuf,
                                            float* __restrict__ xf,
                                            unsigned short* __restrict__ xfb) {
  const float alpha = gbuf[256], beta = gbuf[257];
  const size_t i = ((size_t)blockIdx.x * 256 + threadIdx.x) * 4;
  float4 a = *(const float4*)(xg + i);
  float4 b = *(const float4*)(xl + i);
  float4 r;
  r.x = alpha * a.x + beta * b.x;
  r.y = alpha * a.y + beta * b.y;
  r.z = alpha * a.z + beta * b.z;
  r.w = alpha * a.w + beta * b.w;
  *(float4*)(xf + i) = r;
  *(uint2*)(xfb + i) = make_uint2(pk2(r.x, r.y), pk2(r.z, r.w));
}

// ===========================================================================
extern "C" void kernel_launch(void* const* d_in, const int* in_sizes, int n_in,
                              void* d_out, int out_size, void* d_ws, size_t ws_size,
                              hipStream_t stream) {
  const float* x   = (const float*)d_in[0];
  const float* fw  = (const float*)d_in[2];
  const float* fb  = (const float*)d_in[3];
  const float* fg  = (const float*)d_in[4];
  const float* fbb = (const float*)d_in[5];
  const float* wq  = (const float*)d_in[6];
  const float* wk  = (const float*)d_in[7];
  const float* wv  = (const float*)d_in[8];
  const float* bq  = (const float*)d_in[9];
  const float* bk  = (const float*)d_in[10];
  const float* bv  = (const float*)d_in[11];
  const float* wo  = (const float*)d_in[12];
  const float* bo  = (const float*)d_in[13];
  const float* gw  = (const float*)d_in[14];
  const float* gb  = (const float*)d_in[15];
  const float* w1  = (const float*)d_in[16];
  const float* b1  = (const float*)d_in[17];
  const float* w2  = (const float*)d_in[18];
  const float* b2  = (const float*)d_in[19];
  const float* n1g = (const float*)d_in[20];
  const float* n1b = (const float*)d_in[21];
  const float* n2g = (const float*)d_in[22];
  const float* n2b = (const float*)d_in[23];
  const float* n3g = (const float*)d_in[24];
  const float* n3b = (const float*)d_in[25];
  float* out = (float*)d_out;

  // ---- workspace carve (bytes) ----
  char* base = (char*)d_ws;
  size_t off = 0;
  auto carve = [&](size_t bytes) { char* p = base + off; off += (bytes + 255) & ~(size_t)255; return p; };
  float* p0 = (float*)carve(961 * 256 * 4);
  float* p1 = (float*)carve(225 * 256 * 4);
  float* p2 = (float*)carve(49 * 256 * 4);
  unsigned short* fwT = (unsigned short*)carve(256 * 768 * 2);
  unsigned short* wqkvT = (unsigned short*)carve(3 * 256 * 256 * 2);  // q|k|v
  unsigned short* wqT = wqkvT;
  unsigned short* wkT = wqkvT + 256 * 256;
  unsigned short* wvT = wqkvT + 2 * 256 * 256;
  unsigned short* woT = (unsigned short*)carve(256 * 256 * 2);
  unsigned short* w1T = (unsigned short*)carve(1024 * 256 * 2);
  unsigned short* w2T = (unsigned short*)carve(256 * 1024 * 2);
  char* R = carve(8388608);   // catb(6.3MB) -> po(8MB bf16 x4) -> xg(4MB) -> hbuf(8MB)
  unsigned short* catb = (unsigned short*)R;
  unsigned short* po   = (unsigned short*)R;
  float* xg            = (float*)R;
  unsigned short* hbuf = (unsigned short*)R;
  float* pml = (float*)carve(4 * NH * (size_t)S * 2 * 4);
  unsigned short* qb = (unsigned short*)carve((size_t)S * D * 2);
  unsigned short* kb = (unsigned short*)carve((size_t)S * D * 2);
  unsigned short* vb = (unsigned short*)carve((size_t)S * D * 2);
  float* xf            = (float*)qb;             // qb+kb region, dead after flash
  unsigned short* xfb  = vb;                     // vb region, dead after flash
  float* t1  = (float*)carve((size_t)S * D * 4); // fuse out; later ffo
  float* ffo = t1;
  unsigned short* t1b = (unsigned short*)carve((size_t)S * D * 2);
  float* xl  = (float*)carve((size_t)S * D * 4);
  unsigned short* xlb = (unsigned short*)carve((size_t)S * D * 2);
  float* gbuf = (float*)carve(264 * 4);

  hipMemsetAsync(gbuf, 0, 264 * sizeof(float), stream);
  hipMemsetAsync(p2, 0, 49 * 256 * sizeof(float), stream);

  // weight pre-transpose (bf16 WT[N][K]; wq/wk/wv contiguous)
  k_wt<<<dim3(960), dim3(256), 0, stream>>>(fw, wq, wk, wv, wo, w1, w2,
                                            fwT, wqT, wkT, wvT, woT, w1T, w2T);
  // local multi-scale window attention -> pooled per window (MFMA)
  k_local_s<4, 64><<<dim3(961), dim3(64), 0, stream>>>(x, p0, 31);
  k_local_s<8, 256><<<dim3(225), dim3(256), 0, stream>>>(x, p1, 15);
  k_local16<<<dim3(49, 2), dim3(256), 0, stream>>>(x, p2, 7);
  // scatter/avg -> catb[S][768] bf16
  k_combine<<<dim3(S), dim3(256), 0, stream>>>(p0, p1, p2, catb);
  // fuse GEMM + fused LN pair
  k_gemm_m<768, 0, 0><<<dim3(S / 32, 8), dim3(64), 0, stream>>>(catb, fwT, fb, t1, 256);
  k_ln_fuse<<<dim3(S), dim3(256), 0, stream>>>(t1, x, xl, xlb, fg, fbb, n1g, n1b);
  // global MHA (bf16 q/k/v; single QKV dispatch; q pre-scaled w/ log2e)
  k_gemm_qkv<<<dim3(S / 32, 24), dim3(64), 0, stream>>>(xlb, wqkvT, bq, bk, bv, qb, kb, vb);
  k_flash_mfma<<<dim3(S / 64, NH, 4), dim3(256), 0, stream>>>(qb, kb, vb, po, pml);
  k_fmerge<<<dim3(S), dim3(256), 0, stream>>>(po, pml, t1b);
  k_gemm_m<256, 0, 0><<<dim3(S / 32, 8), dim3(64), 0, stream>>>(t1b, woT, bo, xf, 256);
  k_ln<<<dim3(S), dim3(256), 0, stream>>>(xg, nullptr, xl, xf, n2g, n2b);
  // gate
  k_colmean<<<dim3(64), dim3(256), 0, stream>>>(xl, xg, gbuf);
  k_gate<<<dim3(1), dim3(256), 0, stream>>>(gbuf, gw, gb);
  k_xf<<<dim3(S * D / 1024), dim3(256), 0, stream>>>(xl, xg, gbuf, xf, xfb);
  // FFN + final LN
  k_gemm_m<256, 1, 1><<<dim3(S / 32, 32), dim3(64), 0, stream>>>(xfb, w1T, b1, hbuf, 1024);
  k_gemm_m<1024, 0, 0><<<dim3(S / 32, 8), dim3(64), 0, stream>>>(hbuf, w2T, b2, ffo, 256);
  k_ln<<<dim3(S), dim3(256), 0, stream>>>(out, nullptr, xf, ffo, n3g, n3b);
}